// Round 22
// baseline (251.277 us; speedup 1.0000x reference)
//
#include <hip/hip_runtime.h>

#define CHN    64
#define NATOMS 512
#define PDIM   1024
#define KSP    5
#define HO_    63
#define WO_    63
#define NPATCH 31752
#define MPAD   31872          // 249 * 128
#define HH     128
#define WW     128
#define MT     16
#define OUT_N  8388608
#define DELTA  6e-3f
#define QGUARD 2.5e-3f
#define FBLK   2048
#define RPB    (8 * HO_)      // 504 reconp blocks (one per (b,ho) patch row)

typedef _Float16 f16;
typedef _Float16 f16x8 __attribute__((ext_vector_type(8)));
typedef float    f32x4 __attribute__((ext_vector_type(4)));
typedef float    f32x2 __attribute__((ext_vector_type(2)));

static __device__ __forceinline__ void gload_lds16(const void* g, void* l) {
    __builtin_amdgcn_global_load_lds(
        (const __attribute__((address_space(1))) unsigned int*)g,
        (__attribute__((address_space(3))) unsigned int*)l, 16, 0, 0);
}

static __device__ inline f32x2 fma2(f32x2 a, f32x2 b, f32x2 c) {
#if __has_builtin(__builtin_elementwise_fma)
    return __builtin_elementwise_fma(a, b, c);
#else
    f32x2 r; r.x = fmaf(a.x, b.x, c.x); r.y = fmaf(a.y, b.y, c.y); return r;
#endif
}

// ---- u32 key: (abs>>11)<<11 | (1023-idx)<<1 | sign ----
static __device__ __forceinline__ unsigned mk_key32(float v, int idx) {
    unsigned vb = __float_as_uint(v);
    unsigned ab = vb & 0x7FFFFFFFu;
    return ((ab >> 11) << 11) | ((unsigned)(1023 - idx) << 1) | (vb >> 31);
}
static __device__ __forceinline__ int key32_idx(unsigned k) {
    return 1023 - (int)((k >> 1) & 1023u);
}

#define CEU(s, i, j) { unsigned _a = s[i], _b = s[j]; \
                       s[i] = _a > _b ? _a : _b; s[j] = _a > _b ? _b : _a; }

#define SORT8(s) \
    CEU(s,0,1) CEU(s,2,3) CEU(s,4,5) CEU(s,6,7) \
    CEU(s,0,2) CEU(s,1,3) CEU(s,4,6) CEU(s,5,7) \
    CEU(s,1,2) CEU(s,5,6) \
    CEU(s,0,4) CEU(s,1,5) CEU(s,2,6) CEU(s,3,7) \
    CEU(s,2,4) CEU(s,3,5) \
    CEU(s,1,2) CEU(s,3,4) CEU(s,5,6)

#define MERGE8(s, a, b) { \
    unsigned L[8]; \
    L[0] = a[0] > b[7] ? a[0] : b[7]; L[1] = a[1] > b[6] ? a[1] : b[6]; \
    L[2] = a[2] > b[5] ? a[2] : b[5]; L[3] = a[3] > b[4] ? a[3] : b[4]; \
    L[4] = a[4] > b[3] ? a[4] : b[3]; L[5] = a[5] > b[2] ? a[5] : b[2]; \
    L[6] = a[6] > b[1] ? a[6] : b[1]; L[7] = a[7] > b[0] ? a[7] : b[0]; \
    CEU(L,0,4) CEU(L,1,5) CEU(L,2,6) CEU(L,3,7) \
    CEU(L,0,2) CEU(L,1,3) CEU(L,4,6) CEU(L,5,7) \
    CEU(L,0,1) CEU(L,2,3) CEU(L,4,5) CEU(L,6,7) \
    for (int _i = 0; _i < 8; ++_i) s[_i] = L[_i]; }

// ---------------- gram = D^T D, 32x32 tiles, fp32 accumulate ----------------
__global__ __launch_bounds__(256) void gram_kernel(const float* __restrict__ D,
                                                   float* __restrict__ gram) {
    __shared__ float Ti[64][32];
    __shared__ float Tj[64][32];
    const int tid = threadIdx.x;
    const int i0 = blockIdx.x * 32, j0 = blockIdx.y * 32;
    const int ri  = tid >> 3;
    const int rj0 = (tid & 7) * 4;
    float acc[4] = {0.f, 0.f, 0.f, 0.f};
    for (int k0 = 0; k0 < PDIM; k0 += 64) {
        __syncthreads();
#pragma unroll
        for (int s = 0; s < 8; ++s) {
            int e = tid + 256 * s;
            int kk = e >> 5, col = e & 31;
            Ti[kk][col] = D[(size_t)(k0 + kk) * NATOMS + i0 + col];
            Tj[kk][col] = D[(size_t)(k0 + kk) * NATOMS + j0 + col];
        }
        __syncthreads();
#pragma unroll 4
        for (int kk = 0; kk < 64; ++kk) {
            float ti = Ti[kk][ri];
#pragma unroll
            for (int q = 0; q < 4; ++q)
                acc[q] = fmaf(ti, Tj[kk][rj0 + q], acc[q]);
        }
    }
#pragma unroll
    for (int q = 0; q < 4; ++q)
        gram[(size_t)(i0 + ri) * NATOMS + j0 + rj0 + q] = acc[q];
}

// ------------- patch extraction (coalesced): x -> Xh [MPAD][1024] f16 -------
__global__ __launch_bounds__(256) void extract_kernel(const float* __restrict__ x,
                                                      f16* __restrict__ Xh) {
    __shared__ float xs[16][4][129];
    const int bid = blockIdx.x;
    const int cg  = bid & 3;
    const int t   = bid >> 2;
    const int ho  = t % HO_;
    const int b   = t / HO_;

    for (int i = threadIdx.x; i < 64 * 32; i += 256) {
        int r = i >> 5;
        int q = i & 31;
        int c = r >> 2, pr = r & 3;
        float4 v = *(const float4*)(x + ((size_t)(b * CHN + cg * 16 + c) * HH
                                         + (2 * ho + pr)) * WW + q * 4);
        xs[c][pr][q * 4 + 0] = v.x;
        xs[c][pr][q * 4 + 1] = v.y;
        xs[c][pr][q * 4 + 2] = v.z;
        xs[c][pr][q * 4 + 3] = v.w;
    }
    __syncthreads();

    for (int p = threadIdx.x; p < WO_ * 16; p += 256) {
        int wo = p >> 4;
        int c  = p & 15;
        f16 h[16];
#pragma unroll
        for (int pr = 0; pr < 4; ++pr)
#pragma unroll
            for (int pc = 0; pc < 4; ++pc)
                h[pr * 4 + pc] = (f16)xs[c][pr][2 * wo + pc];
        int n = (b * HO_ + ho) * WO_ + wo;
        f16x8 v0, v1;
#pragma unroll
        for (int i2 = 0; i2 < 8; ++i2) { v0[i2] = h[i2]; v1[i2] = h[8 + i2]; }
        f16* dh = Xh + (size_t)n * PDIM + (cg * 16 + c) * 16;
        *(f16x8*)dh = v0; *(f16x8*)(dh + 8) = v1;
    }
}

// ------------- D -> Dt transpose via LDS tiles (coalesced both sides) -------
__global__ __launch_bounds__(256) void dtrans_kernel(const float* __restrict__ D,
                                                     f16* __restrict__ Dth,
                                                     f16* __restrict__ Dtl) {
    __shared__ float ts[64][65];
    const int k0 = blockIdx.x * 64;
    const int n0 = blockIdx.y * 64;

    for (int i = threadIdx.x; i < 64 * 16; i += 256) {
        int r = i >> 4;
        int q = i & 15;
        float4 v = *(const float4*)(D + (size_t)(k0 + r) * NATOMS + n0 + q * 4);
        ts[r][q * 4 + 0] = v.x;
        ts[r][q * 4 + 1] = v.y;
        ts[r][q * 4 + 2] = v.z;
        ts[r][q * 4 + 3] = v.w;
    }
    __syncthreads();

    {
        int i = threadIdx.x;
        int nn = i >> 2, q = i & 3;
        f16 h[16], l[16];
#pragma unroll
        for (int j = 0; j < 16; ++j) {
            float v = ts[q * 16 + j][nn];
            f16 hh = (f16)v;
            h[j] = hh;
            l[j] = (f16)(v - (float)hh);
        }
        f16x8 h0, h1, l0, l1;
#pragma unroll
        for (int j = 0; j < 8; ++j) { h0[j] = h[j]; h1[j] = h[8 + j]; l0[j] = l[j]; l1[j] = l[8 + j]; }
        f16* dh = Dth + (size_t)(n0 + nn) * PDIM + k0 + q * 16;
        f16* dl = Dtl + (size_t)(n0 + nn) * PDIM + k0 + q * 16;
        *(f16x8*)dh = h0; *(f16x8*)(dh + 8) = h1;
        *(f16x8*)dl = l0; *(f16x8*)(dl + 8) = l1;
    }
}

// ------------- MFMA GEMM: corr[MPAD][512] (f16) = Xh . Dth^T ----------------
__global__ __launch_bounds__(512) void gemm_kernel(const f16* __restrict__ Xh,
                                                   const f16* __restrict__ Dth,
                                                   f16* __restrict__ corr) {
    __shared__ char lds[98304];
    const int tid  = threadIdx.x;
    const int lane = tid & 63;
    const int wave = tid >> 6;
    const size_t arow0 = (size_t)blockIdx.x * 128;
    const int    brow0 = blockIdx.y * 256;
    const int wm = wave >> 2;
    const int wn = wave & 3;

    f32x4 acc[4][4];
#pragma unroll
    for (int m = 0; m < 4; ++m)
#pragma unroll
        for (int n = 0; n < 4; ++n) acc[m][n] = (f32x4){0.f, 0.f, 0.f, 0.f};

    const char* asrc[2]; int adst[2];
#pragma unroll
    for (int i = 0; i < 2; ++i) {
        int p = tid * 16 + i * 8192;
        int row = p >> 7, sc = ((p >> 4) & 7) ^ (row & 7);
        asrc[i] = (const char*)Xh + (arow0 + row) * 2048 + sc * 16;
        adst[i] = p;
    }
    const char* bsrc[4]; int bdst[4];
#pragma unroll
    for (int i = 0; i < 4; ++i) {
        int p = tid * 16 + i * 8192;
        int row = p >> 7, sc = ((p >> 4) & 7) ^ (row & 7);
        bsrc[i] = (const char*)Dth + (size_t)(brow0 + row) * 2048 + sc * 16;
        bdst[i] = 16384 + p;
    }

    int aoff[4][2], boff[4][2];
#pragma unroll
    for (int m = 0; m < 4; ++m)
#pragma unroll
        for (int ks = 0; ks < 2; ++ks) {
            int row = wm * 64 + m * 16 + (lane & 15);
            int ch  = (ks * 4 + (lane >> 4)) ^ (row & 7);
            aoff[m][ks] = row * 128 + ch * 16;
        }
#pragma unroll
    for (int n = 0; n < 4; ++n)
#pragma unroll
        for (int ks = 0; ks < 2; ++ks) {
            int row = wn * 64 + n * 16 + (lane & 15);
            int ch  = (ks * 4 + (lane >> 4)) ^ (row & 7);
            boff[n][ks] = 16384 + row * 128 + ch * 16;
        }

#pragma unroll
    for (int i = 0; i < 2; ++i) gload_lds16(asrc[i], lds + adst[i]);
#pragma unroll
    for (int i = 0; i < 4; ++i) gload_lds16(bsrc[i], lds + bdst[i]);
#pragma unroll
    for (int i = 0; i < 2; ++i) asrc[i] += 128;
#pragma unroll
    for (int i = 0; i < 4; ++i) bsrc[i] += 128;
    __syncthreads();

    int bufo = 0;
    for (int kt = 0; kt < 16; ++kt) {
        const int nbuf = bufo ^ 49152;
        if (kt + 1 < 16) {
#pragma unroll
            for (int i = 0; i < 2; ++i) { gload_lds16(asrc[i], lds + nbuf + adst[i]); asrc[i] += 128; }
#pragma unroll
            for (int i = 0; i < 4; ++i) { gload_lds16(bsrc[i], lds + nbuf + bdst[i]); bsrc[i] += 128; }
        }
#pragma unroll
        for (int ks = 0; ks < 2; ++ks) {
            f16x8 a[4], b[4];
#pragma unroll
            for (int m = 0; m < 4; ++m) a[m] = *(const f16x8*)(lds + bufo + aoff[m][ks]);
#pragma unroll
            for (int n = 0; n < 4; ++n) b[n] = *(const f16x8*)(lds + bufo + boff[n][ks]);
#pragma unroll
            for (int m = 0; m < 4; ++m)
#pragma unroll
                for (int n = 0; n < 4; ++n)
                    acc[m][n] = __builtin_amdgcn_mfma_f32_16x16x32_f16(a[m], b[n], acc[m][n], 0, 0, 0);
        }
        if (kt + 1 < 16) { __syncthreads(); bufo = nbuf; }
    }

#pragma unroll
    for (int m = 0; m < 4; ++m) {
        size_t row_b = arow0 + wm * 64 + m * 16 + (lane >> 4) * 4;
#pragma unroll
        for (int n = 0; n < 4; ++n) {
            int col = brow0 + wn * 64 + n * 16 + (lane & 15);
#pragma unroll
            for (int i = 0; i < 4; ++i)
                corr[(row_b + i) * NATOMS + col] = (f16)acc[m][n][i];
        }
    }
}

// ------- phase 1: sorted top-8 keys + values (f16 corr, cache-hot) ----------
__global__ __launch_bounds__(512) void topred_kernel(const f16* __restrict__ corr,
                                                     unsigned* __restrict__ topk) {
    const int tid = threadIdx.x;
    const int sl  = tid & 31;
    const int hw  = tid >> 5;                 // half-wave 0..15
    const int np  = blockIdx.x * 16 + hw;     // may run into pad rows (< MPAD)

    const f16* row = corr + (size_t)np * NATOMS;
    const f16* cr = row + sl * 16;
    f16x8 c0 = *(const f16x8*)cr;
    f16x8 c1 = *(const f16x8*)(cr + 8);
    unsigned k[16];
#pragma unroll
    for (int j = 0; j < 8; ++j) {
        k[j]     = mk_key32((float)c0[j], sl * 16 + j);
        k[8 + j] = mk_key32((float)c1[j], sl * 16 + 8 + j);
    }

    unsigned a[8], b8[8];
#pragma unroll
    for (int i = 0; i < 8; ++i) { a[i] = k[i]; b8[i] = k[8 + i]; }
    SORT8(a)
    SORT8(b8)
    unsigned s[8];
    MERGE8(s, a, b8)
#pragma unroll
    for (int off = 16; off; off >>= 1) {
        unsigned p[8];
#pragma unroll
        for (int i = 0; i < 8; ++i) p[i] = (unsigned)__shfl_xor((int)s[i], off);
        MERGE8(s, s, p)
    }

    if (sl == 0 && np < NPATCH) {
        float v0 = (float)row[key32_idx(s[0])], v1 = (float)row[key32_idx(s[1])];
        float v2 = (float)row[key32_idx(s[2])], v3 = (float)row[key32_idx(s[3])];
        float v4 = (float)row[key32_idx(s[4])], v5 = (float)row[key32_idx(s[5])];
        float v6 = (float)row[key32_idx(s[6])], v7 = (float)row[key32_idx(s[7])];
        uint4* dst = (uint4*)(topk + (size_t)np * 16);
        dst[0] = make_uint4(s[0], s[1], s[2], s[3]);
        dst[1] = make_uint4(s[4], s[5], s[6], s[7]);
        dst[2] = make_uint4(__float_as_uint(v0), __float_as_uint(v1),
                            __float_as_uint(v2), __float_as_uint(v3));
        dst[3] = make_uint4(__float_as_uint(v4), __float_as_uint(v5),
                            __float_as_uint(v6), __float_as_uint(v7));
    }
}

// ------- phase 2: 64-thr blocks; parallel gram gather; unrolled arbitration -
__global__ __launch_bounds__(64) void topfin_kernel(const unsigned* __restrict__ topk,
                                                    const f16* __restrict__ corr,
                                                    const float* __restrict__ x,
                                                    const float* __restrict__ D,
                                                    const float* __restrict__ gram,
                                                    int* __restrict__ sup_out,
                                                    float* __restrict__ val_out) {
    const int lane = threadIdx.x & 63;
    const int half = lane >> 5;
    const int sl   = lane & 31;
    const int hw   = threadIdx.x >> 5;        // 0..1
    const int np   = blockIdx.x * 2 + hw;     // grid*2 == NPATCH exactly

    unsigned s[8];
    float    tval[8];
    {
        const uint4* src = (const uint4*)(topk + (size_t)np * 16);
        uint4 s0 = src[0], s1 = src[1], v0 = src[2], v1 = src[3];
        s[0] = s0.x; s[1] = s0.y; s[2] = s0.z; s[3] = s0.w;
        s[4] = s1.x; s[5] = s1.y; s[6] = s1.z; s[7] = s1.w;
        tval[0] = __uint_as_float(v0.x); tval[1] = __uint_as_float(v0.y);
        tval[2] = __uint_as_float(v0.z); tval[3] = __uint_as_float(v0.w);
        tval[4] = __uint_as_float(v1.x); tval[5] = __uint_as_float(v1.y);
        tval[6] = __uint_as_float(v1.z); tval[7] = __uint_as_float(v1.w);
    }
    int tidx[8];
#pragma unroll
    for (int r = 0; r < 8; ++r) tidx[r] = key32_idx(s[r]);

    const float a5 = fabsf(tval[KSP - 1]);
    const float lo = fmaxf(a5 - DELTA, 0.0f);
    const float hi = a5 + DELTA;
    const unsigned lokey = (__float_as_uint(fmaxf(lo - QGUARD, 0.0f)) >> 11) << 11;

    int   nfinal = 0, fidx[KSP];
    float fval[KSP];
    int   nwin = 0, widx[8];
    float wvf[8];
#pragma unroll
    for (int r = 0; r < KSP; ++r) {
        if (fabsf(tval[r]) > hi) { fidx[nfinal] = tidx[r]; fval[nfinal] = tval[r]; ++nfinal; }
        else                     { widx[nwin] = tidx[r]; wvf[nwin] = tval[r]; ++nwin; }
    }
#pragma unroll
    for (int r = KSP; r < 8; ++r) {
        if (fabsf(tval[r]) >= lo && nwin < 8) { widx[nwin] = tidx[r]; wvf[nwin] = tval[r]; ++nwin; }
    }

    // rescan for extras beyond top-8 (only when the 8th key is inside window)
    if (s[7] >= lokey) {
        const f16* cr = corr + (size_t)np * NATOMS + sl * 16;
        f16x8 c0 = *(const f16x8*)cr;
        f16x8 c1 = *(const f16x8*)(cr + 8);
        unsigned k[16];
        float vbuf[16];
#pragma unroll
        for (int j = 0; j < 8; ++j) {
            vbuf[j]     = (float)c0[j];
            vbuf[8 + j] = (float)c1[j];
            k[j]        = mk_key32(vbuf[j], sl * 16 + j);
            k[8 + j]    = mk_key32(vbuf[8 + j], sl * 16 + 8 + j);
        }
#pragma unroll
        for (int i = 0; i < 16; ++i) {
            bool ex = (k[i] < s[7]) && (k[i] >= lokey);
            unsigned m = (unsigned)(__ballot(ex) >> (half * 32));
            while (m && nwin < 8) {
                int l = __ffs(m) - 1; m &= m - 1;
                unsigned kk = (unsigned)__shfl((int)k[i], l + half * 32);
                float vv2 = __shfl(vbuf[i], l + half * 32);
                if (fabsf(vv2) >= lo) { widx[nwin] = key32_idx(kk); wvf[nwin] = vv2; ++nwin; }
            }
        }
    }

    const int need = KSP - nfinal;
    if (nwin == need) {
        for (int w = 0; w < nwin; ++w) { fidx[nfinal] = widx[w]; fval[nfinal] = wvf[w]; ++nfinal; }
    } else {
        // fp64 arbitration of the boundary window (rare), 32-lane dot
        int bb_ = np / (HO_ * WO_);
        int rr  = np - bb_ * (HO_ * WO_);
        int ho2 = rr / WO_;
        int wo2 = rr - ho2 * WO_;
        const float* xb = x + (size_t)bb_ * CHN * HH * WW;
        double wv64[8];
        for (int w = 0; w < nwin; ++w) {
            int at = widx[w];
            double sd = 0.0;
#pragma unroll
            for (int t = 0; t < 32; ++t) {
                int kk = sl + (t << 5);
                int c  = kk >> 4, pr = (kk >> 2) & 3, pc = kk & 3;
                float xv = xb[((size_t)c * HH + (2 * ho2 + pr)) * WW + 2 * wo2 + pc];
                float dv = D[(size_t)kk * NATOMS + at];
                sd = fma((double)xv, (double)dv, sd);
            }
            for (int off = 16; off; off >>= 1) sd += __shfl_xor(sd, off);
            wv64[w] = sd;
        }
        unsigned taken = 0u;
        for (int scnt = 0; scnt < need; ++scnt) {
            int best = -1; double bbv = -1.0;
            for (int w = 0; w < nwin; ++w) {
                if ((taken >> w) & 1u) continue;
                double aw = fabs(wv64[w]);
                if (aw > bbv || (aw == bbv && best >= 0 && widx[w] < widx[best])) { bbv = aw; best = w; }
            }
            taken |= 1u << best;
            fidx[nfinal] = widx[best];
            fval[nfinal] = (float)wv64[best];
            ++nfinal;
        }
    }

    // ---- 5x5 solve (fp32); gram gathered in PARALLEL across lanes ----
    float A[KSP][KSP], bb[KSP];
    {
        float gv = 0.f;
        if (sl < 25) {
            int gi = sl / 5, gj = sl - 5 * gi;
            gv = gram[(size_t)fidx[gi] * NATOMS + fidx[gj]];
        }
#pragma unroll
        for (int i = 0; i < KSP; ++i)
#pragma unroll
            for (int j = 0; j < KSP; ++j)
                A[i][j] = __shfl(gv, i * 5 + j + half * 32);
    }
#pragma unroll
    for (int i = 0; i < KSP; ++i) bb[i] = fval[i];
#pragma unroll
    for (int c = 0; c < KSP; ++c) {
        float inv = 1.0f / A[c][c];
#pragma unroll
        for (int r = 0; r < KSP; ++r) {
            if (r > c) {
                float f = A[r][c] * inv;
#pragma unroll
                for (int cc = 0; cc < KSP; ++cc)
                    if (cc > c) A[r][cc] -= f * A[c][cc];
                bb[r] -= f * bb[c];
            }
        }
    }
#pragma unroll
    for (int r = KSP - 1; r >= 0; --r) {
        float t = bb[r];
#pragma unroll
        for (int cc = 0; cc < KSP; ++cc)
            if (cc > r) t -= A[r][cc] * bb[cc];
        bb[r] = t / A[r][r];
    }
    if (sl == 0) {
#pragma unroll
        for (int i = 0; i < KSP; ++i) {
            sup_out[(size_t)np * KSP + i] = fidx[i];
            val_out[(size_t)np * KSP + i] = bb[i];
        }
    }
}

// ------- fused reconstruction, row-complete blocks, float4 I/O --------------
// Block = one (b,ho) patch row (63 patches). Compute phase identical per
// patch (lane=channel); inner 2x2 staged in LDS planes; write phase emits
// the two complete image rows 2ho+1, 2ho+2 for all 64 channels as float4.
__global__ __launch_bounds__(256) void reconp_kernel(const float* __restrict__ x,
                                                     const f16* __restrict__ Dth,
                                                     const f16* __restrict__ Dtl,
                                                     const int* __restrict__ sup,
                                                     const float* __restrict__ val,
                                                     float* __restrict__ out,
                                                     double* __restrict__ rpart) {
    __shared__ float zplane[4][WO_][65];      // [pos][wo][c], pos=(pr-1)*2+(pc-1), pr,pc in {1,2}
    __shared__ double red[4];
    const int lane = threadIdx.x & 63;
    const int wave = threadIdx.x >> 6;
    const int ho = blockIdx.x % HO_;
    const int b  = blockIdx.x / HO_;
    const int nbase = (b * HO_ + ho) * WO_;

#pragma unroll
    for (int it = 0; it < 16; ++it) {
        const int wo = it * 4 + wave;
        if (wo < WO_) {
            const int n = nbase + wo;
            const int*   sp = sup + (size_t)n * KSP;
            const float* vp = val + (size_t)n * KSP;
            float z[16];
#pragma unroll
            for (int i = 0; i < 16; ++i) z[i] = 0.f;
#pragma unroll
            for (int t = 0; t < KSP; ++t) {
                int a = sp[t]; float v = vp[t];
                const f16* dh = Dth + (size_t)a * PDIM + lane * 16;
                const f16* dl = Dtl + (size_t)a * PDIM + lane * 16;
                f16x8 h0 = *(const f16x8*)dh, h1 = *(const f16x8*)(dh + 8);
                f16x8 l0 = *(const f16x8*)dl, l1 = *(const f16x8*)(dl + 8);
#pragma unroll
                for (int i = 0; i < 8; ++i) {
                    z[i]     = fmaf(v, (float)h0[i] + (float)l0[i], z[i]);
                    z[8 + i] = fmaf(v, (float)h1[i] + (float)l1[i], z[8 + i]);
                }
            }
            zplane[0][wo][lane] = z[5];       // (pr=1,pc=1)
            zplane[1][wo][lane] = z[6];       // (pr=1,pc=2)
            zplane[2][wo][lane] = z[9];       // (pr=2,pc=1)
            zplane[3][wo][lane] = z[10];      // (pr=2,pc=2)
        }
    }
    __syncthreads();

    double sq = 0.0;
#pragma unroll
    for (int k = 0; k < 16; ++k) {
        int f = threadIdx.x + 256 * k;        // 0..4095: q minor, then c, then r
        int q = f & 31;                        // float4 col group 0..31
        int c = (f >> 5) & 63;
        int r = f >> 11;                       // 0..1
        const int prof = r * 2;                // row 2ho+1 -> pr=1; row 2ho+2 -> pr=2
        float4 zv;
        zv.x = (q == 0)  ? 0.f : zplane[prof + 1][2 * q - 1][c];
        zv.y = zplane[prof][2 * q][c];
        zv.z = zplane[prof + 1][2 * q][c];
        zv.w = (q == 31) ? 0.f : zplane[prof][2 * q + 1][c];
        size_t base = ((size_t)(b * CHN + c) * HH + (2 * ho + 1 + r)) * WW + 4 * q;
        float4 xv = *(const float4*)(x + base);
        float4 ov;
        ov.x = xv.x + (zv.x - xv.x);
        ov.y = xv.y + (zv.y - xv.y);
        ov.z = xv.z + (zv.z - xv.z);
        ov.w = xv.w + (zv.w - xv.w);
        *(float4*)(out + base) = ov;
        float d0 = zv.x - xv.x, d1 = zv.y - xv.y, d2 = zv.z - xv.z, d3 = zv.w - xv.w;
        sq += (double)d0 * d0 + (double)d1 * d1 + (double)d2 * d2 + (double)d3 * d3;
    }

    for (int off = 32; off; off >>= 1) sq += __shfl_xor(sq, off);
    if (lane == 0) red[wave] = sq;
    __syncthreads();
    if (threadIdx.x == 0) rpart[blockIdx.x] = red[0] + red[1] + red[2] + red[3];
}

// ------- border rows 0 and 127: out = x + (0 - x), loss += x^2 (float4) -----
__global__ __launch_bounds__(64) void border_kernel(const float* __restrict__ x,
                                                    float* __restrict__ out,
                                                    double* __restrict__ bpart) {
    const int plane = blockIdx.x;             // b*CHN + c, 0..511
    const int t = threadIdx.x;                // 0..63: r = t>>5 (row 0/127), q = t&31
    const int r = (t >> 5) ? 127 : 0;
    const int q = t & 31;
    size_t base = (size_t)plane * HH * WW + (size_t)r * WW + 4 * q;
    float4 xv = *(const float4*)(x + base);
    float4 ov;
    ov.x = xv.x + (0.0f - xv.x);
    ov.y = xv.y + (0.0f - xv.y);
    ov.z = xv.z + (0.0f - xv.z);
    ov.w = xv.w + (0.0f - xv.w);
    *(float4*)(out + base) = ov;
    double sq = (double)xv.x * xv.x + (double)xv.y * xv.y
              + (double)xv.z * xv.z + (double)xv.w * xv.w;
    for (int off = 32; off; off >>= 1) sq += __shfl_xor(sq, off);
    if (threadIdx.x == 0) bpart[blockIdx.x] = sq;
}

// ------- loss finalize: sum reconp + border partials ------------------------
__global__ __launch_bounds__(256) void loss2_kernel(const double* __restrict__ rpart,
                                                    const double* __restrict__ bpart,
                                                    float* __restrict__ out) {
    double s = 0.0;
    for (int i = threadIdx.x; i < RPB; i += 256) s += rpart[i];
    for (int i = threadIdx.x; i < 512; i += 256) s += bpart[i];
    for (int off = 32; off; off >>= 1) s += __shfl_xor(s, off);
    __shared__ double red[4];
    const int lane = threadIdx.x & 63, wv = threadIdx.x >> 6;
    if (lane == 0) red[wv] = s;
    __syncthreads();
    if (threadIdx.x == 0) {
        double m = (red[0] + red[1] + red[2] + red[3]) / (double)OUT_N;
        out[OUT_N] = (float)(m + 0.25 * m);
    }
}

// ======================= FALLBACK PATH (small ws) ===========================
__global__ __launch_bounds__(256) void corr_kernel_fb(const float* __restrict__ x,
                                                      const float* __restrict__ D,
                                                      const float* __restrict__ gram,
                                                      int* __restrict__ sup_out,
                                                      float* __restrict__ val_out) {
    __shared__ float pt[256 * MT];
    __shared__ float corrbuf[MT][NATOMS];
    __shared__ int   sup_s[MT][KSP];
    __shared__ float rhs_s[MT][KSP];

    const int tid  = threadIdx.x;
    const int lane = tid & 63;
    const int wave = tid >> 6;
    const int n0   = blockIdx.x * MT;
    const int sp  = lane & 15;
    const int spr = lane >> 4;

    int n = n0 + sp;
    bool pvalid = (n < NPATCH);
    int b = 0, ho = 0, wo = 0;
    if (pvalid) {
        b = n / (HO_ * WO_);
        int r = n - b * (HO_ * WO_);
        ho = r / WO_;
        wo = r - ho * WO_;
    }

    f32x2 accP[2][8];
#pragma unroll
    for (int a = 0; a < 2; ++a)
#pragma unroll
        for (int g = 0; g < 8; ++g) accP[a][g] = (f32x2)(0.f);

    for (int chunk = 0; chunk < 4; ++chunk) {
        __syncthreads();
#pragma unroll
        for (int t = 0; t < 4; ++t) {
            int s = wave + 4 * t;
            int c = chunk * 16 + s;
            float2 va = make_float2(0.f, 0.f), vb = make_float2(0.f, 0.f);
            if (pvalid) {
                const float* px = x + (((size_t)b * CHN + c) * HH + (2 * ho + spr)) * WW + 2 * wo;
                va = *(const float2*)px;
                vb = *(const float2*)(px + 2);
            }
            int kl = (s * 16 + spr * 4) * MT + sp;
            pt[kl]          = va.x;
            pt[kl + MT]     = va.y;
            pt[kl + 2 * MT] = vb.x;
            pt[kl + 3 * MT] = vb.y;
        }
        __syncthreads();
        const float* Dp = D + (size_t)chunk * 256 * NATOMS + 2 * tid;
#pragma unroll 4
        for (int k = 0; k < 256; ++k) {
            float2 dv = *(const float2*)(Dp + (size_t)k * NATOMS);
            f32x2 d00 = {dv.x, dv.x}, d11 = {dv.y, dv.y};
#pragma unroll
            for (int q = 0; q < 4; ++q) {
                const float4 f = *(const float4*)&pt[k * MT + 4 * q];
                f32x2 flo = {f.x, f.y}, fhi = {f.z, f.w};
                accP[0][2 * q]     = fma2(flo, d00, accP[0][2 * q]);
                accP[1][2 * q]     = fma2(flo, d11, accP[1][2 * q]);
                accP[0][2 * q + 1] = fma2(fhi, d00, accP[0][2 * q + 1]);
                accP[1][2 * q + 1] = fma2(fhi, d11, accP[1][2 * q + 1]);
            }
        }
    }
#pragma unroll
    for (int g = 0; g < 8; ++g) {
        *(float2*)&corrbuf[2 * g][2 * tid]     = make_float2(accP[0][g].x, accP[1][g].x);
        *(float2*)&corrbuf[2 * g + 1][2 * tid] = make_float2(accP[0][g].y, accP[1][g].y);
    }
    __syncthreads();

    for (int pi = 0; pi < 4; ++pi) {
        int p  = wave * 4 + pi;
        int np = n0 + p;
        if (np >= NPATCH) continue;
        float v[8], av[8];
#pragma unroll
        for (int i = 0; i < 8; ++i) {
            v[i]  = corrbuf[p][lane + 64 * i];
            av[i] = fabsf(v[i]);
        }
        unsigned usedm = 0u;
        int   top_i[KSP];
        float top_v[KSP];
#pragma unroll
        for (int r = 0; r < KSP; ++r) {
            float ba = -1.0f, bv = 0.0f;
            int   bi = 0x7FFFFFFF;
#pragma unroll
            for (int i = 0; i < 8; ++i) {
                if (!((usedm >> i) & 1u)) {
                    int idx = lane + 64 * i;
                    if (av[i] > ba || (av[i] == ba && idx < bi)) { ba = av[i]; bi = idx; bv = v[i]; }
                }
            }
            for (int off = 32; off; off >>= 1) {
                float oa = __shfl_xor(ba, off);
                int   oi = __shfl_xor(bi, off);
                float ov = __shfl_xor(bv, off);
                if (oa > ba || (oa == ba && oi < bi)) { ba = oa; bi = oi; bv = ov; }
            }
            top_i[r] = bi; top_v[r] = bv;
            if (lane == (bi & 63)) usedm |= (1u << (bi >> 6));
        }
        const float a5 = fabsf(top_v[KSP - 1]);
        const float lo = a5 - DELTA, hi = a5 + DELTA;
        int   nfinal = 0, fidx[KSP];
        float fval[KSP];
        int   nwin = 0, widx[8];
        float wvf[8];
#pragma unroll
        for (int r = 0; r < KSP; ++r) {
            if (fabsf(top_v[r]) > hi) { fidx[nfinal] = top_i[r]; fval[nfinal] = top_v[r]; ++nfinal; }
            else if (nwin < 8)        { widx[nwin] = top_i[r]; wvf[nwin] = top_v[r]; ++nwin; }
        }
#pragma unroll
        for (int i = 0; i < 8; ++i) {
            bool ex = (((usedm >> i) & 1u) == 0u) && (av[i] >= lo);
            unsigned long long m = __ballot(ex);
            while (m && nwin < 8) {
                int l = __ffsll(m) - 1; m &= m - 1;
                widx[nwin] = l + 64 * i;
                wvf[nwin]  = __shfl(v[i], l);
                ++nwin;
            }
        }
        const int need = KSP - nfinal;
        if (nwin == need) {
            for (int w = 0; w < nwin; ++w) { fidx[nfinal] = widx[w]; fval[nfinal] = wvf[w]; ++nfinal; }
        } else {
            int bb_ = np / (HO_ * WO_);
            int rr  = np - bb_ * (HO_ * WO_);
            int ho2 = rr / WO_;
            int wo2 = rr - ho2 * WO_;
            const float* xb = x + (size_t)bb_ * CHN * HH * WW;
            double wv64[8];
            for (int w = 0; w < nwin; ++w) {
                int a = widx[w];
                double s = 0.0;
                for (int t = 0; t < 16; ++t) {
                    int k  = lane + (t << 6);
                    int c  = k >> 4, pr = (k >> 2) & 3, pc = k & 3;
                    float xv = xb[((size_t)c * HH + (2 * ho2 + pr)) * WW + 2 * wo2 + pc];
                    float dv = D[(size_t)k * NATOMS + a];
                    s = fma((double)xv, (double)dv, s);
                }
                for (int off = 32; off; off >>= 1) s += __shfl_xor(s, off);
                wv64[w] = s;
            }
            unsigned taken = 0u;
            for (int scnt = 0; scnt < need; ++scnt) {
                int best = -1; double bbv = -1.0;
                for (int w = 0; w < nwin; ++w) {
                    if ((taken >> w) & 1u) continue;
                    double aw = fabs(wv64[w]);
                    if (aw > bbv || (aw == bbv && best >= 0 && widx[w] < widx[best])) { bbv = aw; best = w; }
                }
                taken |= 1u << best;
                fidx[nfinal] = widx[best];
                fval[nfinal] = (float)wv64[best];
                ++nfinal;
            }
        }
        if (lane == 0) {
#pragma unroll
            for (int r = 0; r < KSP; ++r) { sup_s[p][r] = fidx[r]; rhs_s[p][r] = fval[r]; }
        }
    }
    __syncthreads();

    if (tid < MT) {
        int p = tid, np = n0 + p;
        if (np < NPATCH) {
            int s[KSP];
            double A[KSP][KSP], bb[KSP];
#pragma unroll
            for (int i = 0; i < KSP; ++i) { s[i] = sup_s[p][i]; bb[i] = (double)rhs_s[p][i]; }
#pragma unroll
            for (int i = 0; i < KSP; ++i)
#pragma unroll
                for (int j = 0; j < KSP; ++j)
                    A[i][j] = (double)gram[(size_t)s[i] * NATOMS + s[j]] + (i == j ? 1e-10 : 0.0);
#pragma unroll
            for (int c = 0; c < KSP; ++c) {
                double inv = 1.0 / A[c][c];
#pragma unroll
                for (int r = 0; r < KSP; ++r) {
                    if (r > c) {
                        double f = A[r][c] * inv;
#pragma unroll
                        for (int cc = 0; cc < KSP; ++cc)
                            if (cc > c) A[r][cc] -= f * A[c][cc];
                        bb[r] -= f * bb[c];
                    }
                }
            }
#pragma unroll
            for (int r = KSP - 1; r >= 0; --r) {
                double t = bb[r];
#pragma unroll
                for (int cc = 0; cc < KSP; ++cc)
                    if (cc > r) t -= A[r][cc] * bb[cc];
                bb[r] = t / A[r][r];
            }
#pragma unroll
            for (int i = 0; i < KSP; ++i) {
                sup_out[(size_t)np * KSP + i] = s[i];
                val_out[(size_t)np * KSP + i] = (float)bb[i];
            }
        }
    }
}

__global__ __launch_bounds__(256) void recon_kernel_fb(const float* __restrict__ x,
                                                       const float* __restrict__ D,
                                                       const int* __restrict__ sup,
                                                       const float* __restrict__ val,
                                                       float* __restrict__ out,
                                                       double* __restrict__ partials) {
    double sqacc = 0.0;
    for (size_t o = (size_t)blockIdx.x * 256 + threadIdx.x; o < OUT_N; o += (size_t)FBLK * 256) {
        const int j = (int)(o & 127);
        const int i = (int)((o >> 7) & 127);
        const int c = (int)((o >> 14) & 63);
        const int b = (int)(o >> 20);
        const float xv = x[o];
        float z = 0.0f;
        const int pr = (i & 1) ? 1 : 2;
        const int pc = (j & 1) ? 1 : 2;
        const int ho = (i - pr) >> 1;
        const int wo = (j - pc) >> 1;
        if (ho >= 0 && ho < HO_ && wo >= 0 && wo < WO_) {
            const int n = (b * HO_ + ho) * WO_ + wo;
            const int k = c * 16 + pr * 4 + pc;
            const int*   sp5 = sup + (size_t)n * KSP;
            const float* vp5 = val + (size_t)n * KSP;
            float s = 0.0f;
#pragma unroll
            for (int t = 0; t < KSP; ++t)
                s = fmaf(vp5[t], D[(size_t)k * NATOMS + sp5[t]], s);
            z = s;
        }
        out[o] = xv + (z - xv);
        const float d = z - xv;
        sqacc += (double)d * (double)d;
    }
    for (int off = 32; off; off >>= 1) sqacc += __shfl_xor(sqacc, off);
    __shared__ double red[4];
    const int lane = threadIdx.x & 63, wv = threadIdx.x >> 6;
    if (lane == 0) red[wv] = sqacc;
    __syncthreads();
    if (threadIdx.x == 0) partials[blockIdx.x] = red[0] + red[1] + red[2] + red[3];
}

__global__ __launch_bounds__(256) void loss_kernel(const double* __restrict__ partials,
                                                   float* __restrict__ out) {
    double s = 0.0;
    for (int i = threadIdx.x; i < FBLK; i += 256) s += partials[i];
    for (int off = 32; off; off >>= 1) s += __shfl_xor(s, off);
    __shared__ double red[4];
    const int lane = threadIdx.x & 63, wv = threadIdx.x >> 6;
    if (lane == 0) red[wv] = s;
    __syncthreads();
    if (threadIdx.x == 0) {
        double m = (red[0] + red[1] + red[2] + red[3]) / (double)OUT_N;
        out[OUT_N] = (float)(m + 0.25 * m);
    }
}

// ---------------------------------------------------------------------------
extern "C" void kernel_launch(void* const* d_in, const int* in_sizes, int n_in,
                              void* d_out, int out_size, void* d_ws, size_t ws_size,
                              hipStream_t stream) {
    const float* x = (const float*)d_in[0];
    const float* D = (const float*)d_in[1];
    float* out = (float*)d_out;
    char* ws = (char*)d_ws;

    size_t off = 0;
    auto take = [&](size_t bytes) { char* p = ws + off; off += (bytes + 255) & ~(size_t)255; return p; };
    float*    gram     = (float*)take((size_t)NATOMS * NATOMS * 4);
    int*      sup      = (int*)take((size_t)NPATCH * KSP * 4);
    float*    val      = (float*)take((size_t)NPATCH * KSP * 4);
    double*   partials = (double*)take((size_t)FBLK * 8);
    double*   rpart    = (double*)take((size_t)RPB * 8);
    double*   bpart    = (double*)take((size_t)512 * 8);
    unsigned* topk     = (unsigned*)take((size_t)NPATCH * 16 * 4);
    f16*   Dth  = (f16*)take((size_t)NATOMS * PDIM * 2);
    f16*   Dtl  = (f16*)take((size_t)NATOMS * PDIM * 2);
    f16*   Xh   = (f16*)take((size_t)MPAD * PDIM * 2);
    f16*   corr = (f16*)take((size_t)MPAD * NATOMS * 2);
    const bool big = (off <= ws_size);

    if (big) {
        hipMemsetAsync(Xh + (size_t)NPATCH * PDIM, 0,
                       (size_t)(MPAD - NPATCH) * PDIM * sizeof(f16), stream);
        extract_kernel<<<8 * HO_ * 4, 256, 0, stream>>>(x, Xh);
        dtrans_kernel<<<dim3(16, 8), 256, 0, stream>>>(D, Dth, Dtl);
        gram_kernel<<<dim3(16, 16), 256, 0, stream>>>(D, gram);
        border_kernel<<<512, 64, 0, stream>>>(x, out, bpart);
        gemm_kernel<<<dim3(MPAD / 128, NATOMS / 256), 512, 0, stream>>>(Xh, Dth, corr);
        topred_kernel<<<(NPATCH + 15) / 16, 512, 0, stream>>>(corr, topk);
        topfin_kernel<<<NPATCH / 2, 64, 0, stream>>>(topk, corr, x, D, gram, sup, val);
        reconp_kernel<<<RPB, 256, 0, stream>>>(x, Dth, Dtl, sup, val, out, rpart);
        loss2_kernel<<<1, 256, 0, stream>>>(rpart, bpart, out);
    } else {
        gram_kernel<<<dim3(16, 16), 256, 0, stream>>>(D, gram);
        corr_kernel_fb<<<(NPATCH + MT - 1) / MT, 256, 0, stream>>>(x, D, gram, sup, val);
        recon_kernel_fb<<<FBLK, 256, 0, stream>>>(x, D, sup, val, out, partials);
        loss_kernel<<<1, 256, 0, stream>>>(partials, out);
    }
}

// Round 23
// 248.604 us; speedup vs baseline: 1.0108x; 1.0108x over previous
//
#include <hip/hip_runtime.h>

#define CHN    64
#define NATOMS 512
#define PDIM   1024
#define KSP    5
#define HO_    63
#define WO_    63
#define NPATCH 31752
#define MPAD   31872          // 249 * 128
#define HH     128
#define WW     128
#define MT     16
#define OUT_N  8388608
#define DELTA  6e-3f
#define QGUARD 2.5e-3f
#define FBLK   2048
#define RPB    (8 * HO_ * 4)  // 2016 reconp blocks: (b, ho, channel-group)

typedef _Float16 f16;
typedef _Float16 f16x8 __attribute__((ext_vector_type(8)));
typedef float    f32x4 __attribute__((ext_vector_type(4)));
typedef float    f32x2 __attribute__((ext_vector_type(2)));

static __device__ __forceinline__ void gload_lds16(const void* g, void* l) {
    __builtin_amdgcn_global_load_lds(
        (const __attribute__((address_space(1))) unsigned int*)g,
        (__attribute__((address_space(3))) unsigned int*)l, 16, 0, 0);
}

static __device__ inline f32x2 fma2(f32x2 a, f32x2 b, f32x2 c) {
#if __has_builtin(__builtin_elementwise_fma)
    return __builtin_elementwise_fma(a, b, c);
#else
    f32x2 r; r.x = fmaf(a.x, b.x, c.x); r.y = fmaf(a.y, b.y, c.y); return r;
#endif
}

// ---- u32 key: (abs>>11)<<11 | (1023-idx)<<1 | sign ----
static __device__ __forceinline__ unsigned mk_key32(float v, int idx) {
    unsigned vb = __float_as_uint(v);
    unsigned ab = vb & 0x7FFFFFFFu;
    return ((ab >> 11) << 11) | ((unsigned)(1023 - idx) << 1) | (vb >> 31);
}
static __device__ __forceinline__ int key32_idx(unsigned k) {
    return 1023 - (int)((k >> 1) & 1023u);
}

#define CEU(s, i, j) { unsigned _a = s[i], _b = s[j]; \
                       s[i] = _a > _b ? _a : _b; s[j] = _a > _b ? _b : _a; }

#define SORT8(s) \
    CEU(s,0,1) CEU(s,2,3) CEU(s,4,5) CEU(s,6,7) \
    CEU(s,0,2) CEU(s,1,3) CEU(s,4,6) CEU(s,5,7) \
    CEU(s,1,2) CEU(s,5,6) \
    CEU(s,0,4) CEU(s,1,5) CEU(s,2,6) CEU(s,3,7) \
    CEU(s,2,4) CEU(s,3,5) \
    CEU(s,1,2) CEU(s,3,4) CEU(s,5,6)

#define MERGE8(s, a, b) { \
    unsigned L[8]; \
    L[0] = a[0] > b[7] ? a[0] : b[7]; L[1] = a[1] > b[6] ? a[1] : b[6]; \
    L[2] = a[2] > b[5] ? a[2] : b[5]; L[3] = a[3] > b[4] ? a[3] : b[4]; \
    L[4] = a[4] > b[3] ? a[4] : b[3]; L[5] = a[5] > b[2] ? a[5] : b[2]; \
    L[6] = a[6] > b[1] ? a[6] : b[1]; L[7] = a[7] > b[0] ? a[7] : b[0]; \
    CEU(L,0,4) CEU(L,1,5) CEU(L,2,6) CEU(L,3,7) \
    CEU(L,0,2) CEU(L,1,3) CEU(L,4,6) CEU(L,5,7) \
    CEU(L,0,1) CEU(L,2,3) CEU(L,4,5) CEU(L,6,7) \
    for (int _i = 0; _i < 8; ++_i) s[_i] = L[_i]; }

// ---------------- gram = D^T D, 32x32 tiles, fp32 accumulate ----------------
__global__ __launch_bounds__(256) void gram_kernel(const float* __restrict__ D,
                                                   float* __restrict__ gram) {
    __shared__ float Ti[64][32];
    __shared__ float Tj[64][32];
    const int tid = threadIdx.x;
    const int i0 = blockIdx.x * 32, j0 = blockIdx.y * 32;
    const int ri  = tid >> 3;
    const int rj0 = (tid & 7) * 4;
    float acc[4] = {0.f, 0.f, 0.f, 0.f};
    for (int k0 = 0; k0 < PDIM; k0 += 64) {
        __syncthreads();
#pragma unroll
        for (int s = 0; s < 8; ++s) {
            int e = tid + 256 * s;
            int kk = e >> 5, col = e & 31;
            Ti[kk][col] = D[(size_t)(k0 + kk) * NATOMS + i0 + col];
            Tj[kk][col] = D[(size_t)(k0 + kk) * NATOMS + j0 + col];
        }
        __syncthreads();
#pragma unroll 4
        for (int kk = 0; kk < 64; ++kk) {
            float ti = Ti[kk][ri];
#pragma unroll
            for (int q = 0; q < 4; ++q)
                acc[q] = fmaf(ti, Tj[kk][rj0 + q], acc[q]);
        }
    }
#pragma unroll
    for (int q = 0; q < 4; ++q)
        gram[(size_t)(i0 + ri) * NATOMS + j0 + rj0 + q] = acc[q];
}

// ------------- patch extraction (coalesced): x -> Xh [MPAD][1024] f16 -------
__global__ __launch_bounds__(256) void extract_kernel(const float* __restrict__ x,
                                                      f16* __restrict__ Xh) {
    __shared__ float xs[16][4][129];
    const int bid = blockIdx.x;
    const int cg  = bid & 3;
    const int t   = bid >> 2;
    const int ho  = t % HO_;
    const int b   = t / HO_;

    for (int i = threadIdx.x; i < 64 * 32; i += 256) {
        int r = i >> 5;
        int q = i & 31;
        int c = r >> 2, pr = r & 3;
        float4 v = *(const float4*)(x + ((size_t)(b * CHN + cg * 16 + c) * HH
                                         + (2 * ho + pr)) * WW + q * 4);
        xs[c][pr][q * 4 + 0] = v.x;
        xs[c][pr][q * 4 + 1] = v.y;
        xs[c][pr][q * 4 + 2] = v.z;
        xs[c][pr][q * 4 + 3] = v.w;
    }
    __syncthreads();

    for (int p = threadIdx.x; p < WO_ * 16; p += 256) {
        int wo = p >> 4;
        int c  = p & 15;
        f16 h[16];
#pragma unroll
        for (int pr = 0; pr < 4; ++pr)
#pragma unroll
            for (int pc = 0; pc < 4; ++pc)
                h[pr * 4 + pc] = (f16)xs[c][pr][2 * wo + pc];
        int n = (b * HO_ + ho) * WO_ + wo;
        f16x8 v0, v1;
#pragma unroll
        for (int i2 = 0; i2 < 8; ++i2) { v0[i2] = h[i2]; v1[i2] = h[8 + i2]; }
        f16* dh = Xh + (size_t)n * PDIM + (cg * 16 + c) * 16;
        *(f16x8*)dh = v0; *(f16x8*)(dh + 8) = v1;
    }
}

// ------------- D -> Dt transpose via LDS tiles (coalesced both sides) -------
__global__ __launch_bounds__(256) void dtrans_kernel(const float* __restrict__ D,
                                                     f16* __restrict__ Dth,
                                                     f16* __restrict__ Dtl) {
    __shared__ float ts[64][65];
    const int k0 = blockIdx.x * 64;
    const int n0 = blockIdx.y * 64;

    for (int i = threadIdx.x; i < 64 * 16; i += 256) {
        int r = i >> 4;
        int q = i & 15;
        float4 v = *(const float4*)(D + (size_t)(k0 + r) * NATOMS + n0 + q * 4);
        ts[r][q * 4 + 0] = v.x;
        ts[r][q * 4 + 1] = v.y;
        ts[r][q * 4 + 2] = v.z;
        ts[r][q * 4 + 3] = v.w;
    }
    __syncthreads();

    {
        int i = threadIdx.x;
        int nn = i >> 2, q = i & 3;
        f16 h[16], l[16];
#pragma unroll
        for (int j = 0; j < 16; ++j) {
            float v = ts[q * 16 + j][nn];
            f16 hh = (f16)v;
            h[j] = hh;
            l[j] = (f16)(v - (float)hh);
        }
        f16x8 h0, h1, l0, l1;
#pragma unroll
        for (int j = 0; j < 8; ++j) { h0[j] = h[j]; h1[j] = h[8 + j]; l0[j] = l[j]; l1[j] = l[8 + j]; }
        f16* dh = Dth + (size_t)(n0 + nn) * PDIM + k0 + q * 16;
        f16* dl = Dtl + (size_t)(n0 + nn) * PDIM + k0 + q * 16;
        *(f16x8*)dh = h0; *(f16x8*)(dh + 8) = h1;
        *(f16x8*)dl = l0; *(f16x8*)(dl + 8) = l1;
    }
}

// ------------- MFMA GEMM: corr[MPAD][512] (f16) = Xh . Dth^T ----------------
__global__ __launch_bounds__(512) void gemm_kernel(const f16* __restrict__ Xh,
                                                   const f16* __restrict__ Dth,
                                                   f16* __restrict__ corr) {
    __shared__ char lds[98304];
    const int tid  = threadIdx.x;
    const int lane = tid & 63;
    const int wave = tid >> 6;
    const size_t arow0 = (size_t)blockIdx.x * 128;
    const int    brow0 = blockIdx.y * 256;
    const int wm = wave >> 2;
    const int wn = wave & 3;

    f32x4 acc[4][4];
#pragma unroll
    for (int m = 0; m < 4; ++m)
#pragma unroll
        for (int n = 0; n < 4; ++n) acc[m][n] = (f32x4){0.f, 0.f, 0.f, 0.f};

    const char* asrc[2]; int adst[2];
#pragma unroll
    for (int i = 0; i < 2; ++i) {
        int p = tid * 16 + i * 8192;
        int row = p >> 7, sc = ((p >> 4) & 7) ^ (row & 7);
        asrc[i] = (const char*)Xh + (arow0 + row) * 2048 + sc * 16;
        adst[i] = p;
    }
    const char* bsrc[4]; int bdst[4];
#pragma unroll
    for (int i = 0; i < 4; ++i) {
        int p = tid * 16 + i * 8192;
        int row = p >> 7, sc = ((p >> 4) & 7) ^ (row & 7);
        bsrc[i] = (const char*)Dth + (size_t)(brow0 + row) * 2048 + sc * 16;
        bdst[i] = 16384 + p;
    }

    int aoff[4][2], boff[4][2];
#pragma unroll
    for (int m = 0; m < 4; ++m)
#pragma unroll
        for (int ks = 0; ks < 2; ++ks) {
            int row = wm * 64 + m * 16 + (lane & 15);
            int ch  = (ks * 4 + (lane >> 4)) ^ (row & 7);
            aoff[m][ks] = row * 128 + ch * 16;
        }
#pragma unroll
    for (int n = 0; n < 4; ++n)
#pragma unroll
        for (int ks = 0; ks < 2; ++ks) {
            int row = wn * 64 + n * 16 + (lane & 15);
            int ch  = (ks * 4 + (lane >> 4)) ^ (row & 7);
            boff[n][ks] = 16384 + row * 128 + ch * 16;
        }

#pragma unroll
    for (int i = 0; i < 2; ++i) gload_lds16(asrc[i], lds + adst[i]);
#pragma unroll
    for (int i = 0; i < 4; ++i) gload_lds16(bsrc[i], lds + bdst[i]);
#pragma unroll
    for (int i = 0; i < 2; ++i) asrc[i] += 128;
#pragma unroll
    for (int i = 0; i < 4; ++i) bsrc[i] += 128;
    __syncthreads();

    int bufo = 0;
    for (int kt = 0; kt < 16; ++kt) {
        const int nbuf = bufo ^ 49152;
        if (kt + 1 < 16) {
#pragma unroll
            for (int i = 0; i < 2; ++i) { gload_lds16(asrc[i], lds + nbuf + adst[i]); asrc[i] += 128; }
#pragma unroll
            for (int i = 0; i < 4; ++i) { gload_lds16(bsrc[i], lds + nbuf + bdst[i]); bsrc[i] += 128; }
        }
#pragma unroll
        for (int ks = 0; ks < 2; ++ks) {
            f16x8 a[4], b[4];
#pragma unroll
            for (int m = 0; m < 4; ++m) a[m] = *(const f16x8*)(lds + bufo + aoff[m][ks]);
#pragma unroll
            for (int n = 0; n < 4; ++n) b[n] = *(const f16x8*)(lds + bufo + boff[n][ks]);
#pragma unroll
            for (int m = 0; m < 4; ++m)
#pragma unroll
                for (int n = 0; n < 4; ++n)
                    acc[m][n] = __builtin_amdgcn_mfma_f32_16x16x32_f16(a[m], b[n], acc[m][n], 0, 0, 0);
        }
        if (kt + 1 < 16) { __syncthreads(); bufo = nbuf; }
    }

#pragma unroll
    for (int m = 0; m < 4; ++m) {
        size_t row_b = arow0 + wm * 64 + m * 16 + (lane >> 4) * 4;
#pragma unroll
        for (int n = 0; n < 4; ++n) {
            int col = brow0 + wn * 64 + n * 16 + (lane & 15);
#pragma unroll
            for (int i = 0; i < 4; ++i)
                corr[(row_b + i) * NATOMS + col] = (f16)acc[m][n][i];
        }
    }
}

// ------- phase 1: sorted top-8 keys + values (f16 corr, cache-hot) ----------
__global__ __launch_bounds__(512) void topred_kernel(const f16* __restrict__ corr,
                                                     unsigned* __restrict__ topk) {
    const int tid = threadIdx.x;
    const int sl  = tid & 31;
    const int hw  = tid >> 5;                 // half-wave 0..15
    const int np  = blockIdx.x * 16 + hw;     // may run into pad rows (< MPAD)

    const f16* row = corr + (size_t)np * NATOMS;
    const f16* cr = row + sl * 16;
    f16x8 c0 = *(const f16x8*)cr;
    f16x8 c1 = *(const f16x8*)(cr + 8);
    unsigned k[16];
#pragma unroll
    for (int j = 0; j < 8; ++j) {
        k[j]     = mk_key32((float)c0[j], sl * 16 + j);
        k[8 + j] = mk_key32((float)c1[j], sl * 16 + 8 + j);
    }

    unsigned a[8], b8[8];
#pragma unroll
    for (int i = 0; i < 8; ++i) { a[i] = k[i]; b8[i] = k[8 + i]; }
    SORT8(a)
    SORT8(b8)
    unsigned s[8];
    MERGE8(s, a, b8)
#pragma unroll
    for (int off = 16; off; off >>= 1) {
        unsigned p[8];
#pragma unroll
        for (int i = 0; i < 8; ++i) p[i] = (unsigned)__shfl_xor((int)s[i], off);
        MERGE8(s, s, p)
    }

    if (sl == 0 && np < NPATCH) {
        float v0 = (float)row[key32_idx(s[0])], v1 = (float)row[key32_idx(s[1])];
        float v2 = (float)row[key32_idx(s[2])], v3 = (float)row[key32_idx(s[3])];
        float v4 = (float)row[key32_idx(s[4])], v5 = (float)row[key32_idx(s[5])];
        float v6 = (float)row[key32_idx(s[6])], v7 = (float)row[key32_idx(s[7])];
        uint4* dst = (uint4*)(topk + (size_t)np * 16);
        dst[0] = make_uint4(s[0], s[1], s[2], s[3]);
        dst[1] = make_uint4(s[4], s[5], s[6], s[7]);
        dst[2] = make_uint4(__float_as_uint(v0), __float_as_uint(v1),
                            __float_as_uint(v2), __float_as_uint(v3));
        dst[3] = make_uint4(__float_as_uint(v4), __float_as_uint(v5),
                            __float_as_uint(v6), __float_as_uint(v7));
    }
}

// ------- phase 2: 64-thr blocks; parallel gram gather; unrolled arbitration -
__global__ __launch_bounds__(64) void topfin_kernel(const unsigned* __restrict__ topk,
                                                    const f16* __restrict__ corr,
                                                    const float* __restrict__ x,
                                                    const float* __restrict__ D,
                                                    const float* __restrict__ gram,
                                                    int* __restrict__ sup_out,
                                                    float* __restrict__ val_out) {
    const int lane = threadIdx.x & 63;
    const int half = lane >> 5;
    const int sl   = lane & 31;
    const int hw   = threadIdx.x >> 5;        // 0..1
    const int np   = blockIdx.x * 2 + hw;     // grid*2 == NPATCH exactly

    unsigned s[8];
    float    tval[8];
    {
        const uint4* src = (const uint4*)(topk + (size_t)np * 16);
        uint4 s0 = src[0], s1 = src[1], v0 = src[2], v1 = src[3];
        s[0] = s0.x; s[1] = s0.y; s[2] = s0.z; s[3] = s0.w;
        s[4] = s1.x; s[5] = s1.y; s[6] = s1.z; s[7] = s1.w;
        tval[0] = __uint_as_float(v0.x); tval[1] = __uint_as_float(v0.y);
        tval[2] = __uint_as_float(v0.z); tval[3] = __uint_as_float(v0.w);
        tval[4] = __uint_as_float(v1.x); tval[5] = __uint_as_float(v1.y);
        tval[6] = __uint_as_float(v1.z); tval[7] = __uint_as_float(v1.w);
    }
    int tidx[8];
#pragma unroll
    for (int r = 0; r < 8; ++r) tidx[r] = key32_idx(s[r]);

    const float a5 = fabsf(tval[KSP - 1]);
    const float lo = fmaxf(a5 - DELTA, 0.0f);
    const float hi = a5 + DELTA;
    const unsigned lokey = (__float_as_uint(fmaxf(lo - QGUARD, 0.0f)) >> 11) << 11;

    int   nfinal = 0, fidx[KSP];
    float fval[KSP];
    int   nwin = 0, widx[8];
    float wvf[8];
#pragma unroll
    for (int r = 0; r < KSP; ++r) {
        if (fabsf(tval[r]) > hi) { fidx[nfinal] = tidx[r]; fval[nfinal] = tval[r]; ++nfinal; }
        else                     { widx[nwin] = tidx[r]; wvf[nwin] = tval[r]; ++nwin; }
    }
#pragma unroll
    for (int r = KSP; r < 8; ++r) {
        if (fabsf(tval[r]) >= lo && nwin < 8) { widx[nwin] = tidx[r]; wvf[nwin] = tval[r]; ++nwin; }
    }

    // rescan for extras beyond top-8 (only when the 8th key is inside window)
    if (s[7] >= lokey) {
        const f16* cr = corr + (size_t)np * NATOMS + sl * 16;
        f16x8 c0 = *(const f16x8*)cr;
        f16x8 c1 = *(const f16x8*)(cr + 8);
        unsigned k[16];
        float vbuf[16];
#pragma unroll
        for (int j = 0; j < 8; ++j) {
            vbuf[j]     = (float)c0[j];
            vbuf[8 + j] = (float)c1[j];
            k[j]        = mk_key32(vbuf[j], sl * 16 + j);
            k[8 + j]    = mk_key32(vbuf[8 + j], sl * 16 + 8 + j);
        }
#pragma unroll
        for (int i = 0; i < 16; ++i) {
            bool ex = (k[i] < s[7]) && (k[i] >= lokey);
            unsigned m = (unsigned)(__ballot(ex) >> (half * 32));
            while (m && nwin < 8) {
                int l = __ffs(m) - 1; m &= m - 1;
                unsigned kk = (unsigned)__shfl((int)k[i], l + half * 32);
                float vv2 = __shfl(vbuf[i], l + half * 32);
                if (fabsf(vv2) >= lo) { widx[nwin] = key32_idx(kk); wvf[nwin] = vv2; ++nwin; }
            }
        }
    }

    const int need = KSP - nfinal;
    if (nwin == need) {
        for (int w = 0; w < nwin; ++w) { fidx[nfinal] = widx[w]; fval[nfinal] = wvf[w]; ++nfinal; }
    } else {
        // fp64 arbitration of the boundary window (rare), 32-lane dot
        int bb_ = np / (HO_ * WO_);
        int rr  = np - bb_ * (HO_ * WO_);
        int ho2 = rr / WO_;
        int wo2 = rr - ho2 * WO_;
        const float* xb = x + (size_t)bb_ * CHN * HH * WW;
        double wv64[8];
        for (int w = 0; w < nwin; ++w) {
            int at = widx[w];
            double sd = 0.0;
#pragma unroll
            for (int t = 0; t < 32; ++t) {
                int kk = sl + (t << 5);
                int c  = kk >> 4, pr = (kk >> 2) & 3, pc = kk & 3;
                float xv = xb[((size_t)c * HH + (2 * ho2 + pr)) * WW + 2 * wo2 + pc];
                float dv = D[(size_t)kk * NATOMS + at];
                sd = fma((double)xv, (double)dv, sd);
            }
            for (int off = 16; off; off >>= 1) sd += __shfl_xor(sd, off);
            wv64[w] = sd;
        }
        unsigned taken = 0u;
        for (int scnt = 0; scnt < need; ++scnt) {
            int best = -1; double bbv = -1.0;
            for (int w = 0; w < nwin; ++w) {
                if ((taken >> w) & 1u) continue;
                double aw = fabs(wv64[w]);
                if (aw > bbv || (aw == bbv && best >= 0 && widx[w] < widx[best])) { bbv = aw; best = w; }
            }
            taken |= 1u << best;
            fidx[nfinal] = widx[best];
            fval[nfinal] = (float)wv64[best];
            ++nfinal;
        }
    }

    // ---- 5x5 solve (fp32); gram gathered in PARALLEL across lanes ----
    float A[KSP][KSP], bb[KSP];
    {
        float gv = 0.f;
        if (sl < 25) {
            int gi = sl / 5, gj = sl - 5 * gi;
            gv = gram[(size_t)fidx[gi] * NATOMS + fidx[gj]];
        }
#pragma unroll
        for (int i = 0; i < KSP; ++i)
#pragma unroll
            for (int j = 0; j < KSP; ++j)
                A[i][j] = __shfl(gv, i * 5 + j + half * 32);
    }
#pragma unroll
    for (int i = 0; i < KSP; ++i) bb[i] = fval[i];
#pragma unroll
    for (int c = 0; c < KSP; ++c) {
        float inv = 1.0f / A[c][c];
#pragma unroll
        for (int r = 0; r < KSP; ++r) {
            if (r > c) {
                float f = A[r][c] * inv;
#pragma unroll
                for (int cc = 0; cc < KSP; ++cc)
                    if (cc > c) A[r][cc] -= f * A[c][cc];
                bb[r] -= f * bb[c];
            }
        }
    }
#pragma unroll
    for (int r = KSP - 1; r >= 0; --r) {
        float t = bb[r];
#pragma unroll
        for (int cc = 0; cc < KSP; ++cc)
            if (cc > r) t -= A[r][cc] * bb[cc];
        bb[r] = t / A[r][r];
    }
    if (sl == 0) {
#pragma unroll
        for (int i = 0; i < KSP; ++i) {
            sup_out[(size_t)np * KSP + i] = fidx[i];
            val_out[(size_t)np * KSP + i] = bb[i];
        }
    }
}

// ------- fused reconstruction: (b, ho, 16-channel group) blocks, float4 IO --
// Thread = (patch p_local, channel c_local). Same per-(patch,channel) FMA
// chain as all passing versions; write phase = round-22's verified float4
// mapping, restricted to this block's 16 channels.
__global__ __launch_bounds__(256) void reconp_kernel(const float* __restrict__ x,
                                                     const f16* __restrict__ Dth,
                                                     const f16* __restrict__ Dtl,
                                                     const int* __restrict__ sup,
                                                     const float* __restrict__ val,
                                                     float* __restrict__ out,
                                                     double* __restrict__ rpart) {
    __shared__ float zplane[4][WO_][17];      // [pos][wo][c_local], 17 KB
    __shared__ double red[4];
    const int tid  = threadIdx.x;
    const int lane = tid & 63;
    const int wave = tid >> 6;
    const int cg = blockIdx.x & 3;
    const int t2 = blockIdx.x >> 2;
    const int ho = t2 % HO_;
    const int b  = t2 / HO_;
    const int nbase = (b * HO_ + ho) * WO_;
    const int p_local = tid >> 4;             // 0..15
    const int c_local = tid & 15;
    const int c = cg * 16 + c_local;

#pragma unroll
    for (int it = 0; it < 4; ++it) {
        const int wo = it * 16 + p_local;
        if (wo < WO_) {
            const int n = nbase + wo;
            const int*   sp = sup + (size_t)n * KSP;
            const float* vp = val + (size_t)n * KSP;
            float z[16];
#pragma unroll
            for (int i = 0; i < 16; ++i) z[i] = 0.f;
#pragma unroll
            for (int t = 0; t < KSP; ++t) {
                int a = sp[t]; float v = vp[t];
                const f16* dh = Dth + (size_t)a * PDIM + c * 16;
                const f16* dl = Dtl + (size_t)a * PDIM + c * 16;
                f16x8 h0 = *(const f16x8*)dh, h1 = *(const f16x8*)(dh + 8);
                f16x8 l0 = *(const f16x8*)dl, l1 = *(const f16x8*)(dl + 8);
#pragma unroll
                for (int i = 0; i < 8; ++i) {
                    z[i]     = fmaf(v, (float)h0[i] + (float)l0[i], z[i]);
                    z[8 + i] = fmaf(v, (float)h1[i] + (float)l1[i], z[8 + i]);
                }
            }
            zplane[0][wo][c_local] = z[5];    // (pr=1,pc=1)
            zplane[1][wo][c_local] = z[6];    // (pr=1,pc=2)
            zplane[2][wo][c_local] = z[9];    // (pr=2,pc=1)
            zplane[3][wo][c_local] = z[10];   // (pr=2,pc=2)
        }
    }
    __syncthreads();

    double sq = 0.0;
#pragma unroll
    for (int k = 0; k < 4; ++k) {
        int f  = tid + 256 * k;               // 0..1023
        int q  = f & 31;                       // float4 col group 0..31
        int cl = (f >> 5) & 15;
        int r  = f >> 9;                       // 0..1
        const int prof = r * 2;                // row 2ho+1 -> pr=1; 2ho+2 -> pr=2
        float4 zv;
        zv.x = (q == 0)  ? 0.f : zplane[prof + 1][2 * q - 1][cl];
        zv.y = zplane[prof][2 * q][cl];
        zv.z = zplane[prof + 1][2 * q][cl];
        zv.w = (q == 31) ? 0.f : zplane[prof][2 * q + 1][cl];
        size_t base = ((size_t)(b * CHN + cg * 16 + cl) * HH + (2 * ho + 1 + r)) * WW + 4 * q;
        float4 xv = *(const float4*)(x + base);
        float4 ov;
        ov.x = xv.x + (zv.x - xv.x);
        ov.y = xv.y + (zv.y - xv.y);
        ov.z = xv.z + (zv.z - xv.z);
        ov.w = xv.w + (zv.w - xv.w);
        *(float4*)(out + base) = ov;
        float d0 = zv.x - xv.x, d1 = zv.y - xv.y, d2 = zv.z - xv.z, d3 = zv.w - xv.w;
        sq += (double)d0 * d0 + (double)d1 * d1 + (double)d2 * d2 + (double)d3 * d3;
    }

    for (int off = 32; off; off >>= 1) sq += __shfl_xor(sq, off);
    if (lane == 0) red[wave] = sq;
    __syncthreads();
    if (threadIdx.x == 0) rpart[blockIdx.x] = red[0] + red[1] + red[2] + red[3];
}

// ------- border rows 0 and 127: out = x + (0 - x), loss += x^2 (float4) -----
__global__ __launch_bounds__(64) void border_kernel(const float* __restrict__ x,
                                                    float* __restrict__ out,
                                                    double* __restrict__ bpart) {
    const int plane = blockIdx.x;             // b*CHN + c, 0..511
    const int t = threadIdx.x;                // 0..63: r = t>>5 (row 0/127), q = t&31
    const int r = (t >> 5) ? 127 : 0;
    const int q = t & 31;
    size_t base = (size_t)plane * HH * WW + (size_t)r * WW + 4 * q;
    float4 xv = *(const float4*)(x + base);
    float4 ov;
    ov.x = xv.x + (0.0f - xv.x);
    ov.y = xv.y + (0.0f - xv.y);
    ov.z = xv.z + (0.0f - xv.z);
    ov.w = xv.w + (0.0f - xv.w);
    *(float4*)(out + base) = ov;
    double sq = (double)xv.x * xv.x + (double)xv.y * xv.y
              + (double)xv.z * xv.z + (double)xv.w * xv.w;
    for (int off = 32; off; off >>= 1) sq += __shfl_xor(sq, off);
    if (threadIdx.x == 0) bpart[blockIdx.x] = sq;
}

// ------- loss finalize: sum reconp + border partials ------------------------
__global__ __launch_bounds__(256) void loss2_kernel(const double* __restrict__ rpart,
                                                    const double* __restrict__ bpart,
                                                    float* __restrict__ out) {
    double s = 0.0;
    for (int i = threadIdx.x; i < RPB; i += 256) s += rpart[i];
    for (int i = threadIdx.x; i < 512; i += 256) s += bpart[i];
    for (int off = 32; off; off >>= 1) s += __shfl_xor(s, off);
    __shared__ double red[4];
    const int lane = threadIdx.x & 63, wv = threadIdx.x >> 6;
    if (lane == 0) red[wv] = s;
    __syncthreads();
    if (threadIdx.x == 0) {
        double m = (red[0] + red[1] + red[2] + red[3]) / (double)OUT_N;
        out[OUT_N] = (float)(m + 0.25 * m);
    }
}

// ======================= FALLBACK PATH (small ws) ===========================
__global__ __launch_bounds__(256) void corr_kernel_fb(const float* __restrict__ x,
                                                      const float* __restrict__ D,
                                                      const float* __restrict__ gram,
                                                      int* __restrict__ sup_out,
                                                      float* __restrict__ val_out) {
    __shared__ float pt[256 * MT];
    __shared__ float corrbuf[MT][NATOMS];
    __shared__ int   sup_s[MT][KSP];
    __shared__ float rhs_s[MT][KSP];

    const int tid  = threadIdx.x;
    const int lane = tid & 63;
    const int wave = tid >> 6;
    const int n0   = blockIdx.x * MT;
    const int sp  = lane & 15;
    const int spr = lane >> 4;

    int n = n0 + sp;
    bool pvalid = (n < NPATCH);
    int b = 0, ho = 0, wo = 0;
    if (pvalid) {
        b = n / (HO_ * WO_);
        int r = n - b * (HO_ * WO_);
        ho = r / WO_;
        wo = r - ho * WO_;
    }

    f32x2 accP[2][8];
#pragma unroll
    for (int a = 0; a < 2; ++a)
#pragma unroll
        for (int g = 0; g < 8; ++g) accP[a][g] = (f32x2)(0.f);

    for (int chunk = 0; chunk < 4; ++chunk) {
        __syncthreads();
#pragma unroll
        for (int t = 0; t < 4; ++t) {
            int s = wave + 4 * t;
            int c = chunk * 16 + s;
            float2 va = make_float2(0.f, 0.f), vb = make_float2(0.f, 0.f);
            if (pvalid) {
                const float* px = x + (((size_t)b * CHN + c) * HH + (2 * ho + spr)) * WW + 2 * wo;
                va = *(const float2*)px;
                vb = *(const float2*)(px + 2);
            }
            int kl = (s * 16 + spr * 4) * MT + sp;
            pt[kl]          = va.x;
            pt[kl + MT]     = va.y;
            pt[kl + 2 * MT] = vb.x;
            pt[kl + 3 * MT] = vb.y;
        }
        __syncthreads();
        const float* Dp = D + (size_t)chunk * 256 * NATOMS + 2 * tid;
#pragma unroll 4
        for (int k = 0; k < 256; ++k) {
            float2 dv = *(const float2*)(Dp + (size_t)k * NATOMS);
            f32x2 d00 = {dv.x, dv.x}, d11 = {dv.y, dv.y};
#pragma unroll
            for (int q = 0; q < 4; ++q) {
                const float4 f = *(const float4*)&pt[k * MT + 4 * q];
                f32x2 flo = {f.x, f.y}, fhi = {f.z, f.w};
                accP[0][2 * q]     = fma2(flo, d00, accP[0][2 * q]);
                accP[1][2 * q]     = fma2(flo, d11, accP[1][2 * q]);
                accP[0][2 * q + 1] = fma2(fhi, d00, accP[0][2 * q + 1]);
                accP[1][2 * q + 1] = fma2(fhi, d11, accP[1][2 * q + 1]);
            }
        }
    }
#pragma unroll
    for (int g = 0; g < 8; ++g) {
        *(float2*)&corrbuf[2 * g][2 * tid]     = make_float2(accP[0][g].x, accP[1][g].x);
        *(float2*)&corrbuf[2 * g + 1][2 * tid] = make_float2(accP[0][g].y, accP[1][g].y);
    }
    __syncthreads();

    for (int pi = 0; pi < 4; ++pi) {
        int p  = wave * 4 + pi;
        int np = n0 + p;
        if (np >= NPATCH) continue;
        float v[8], av[8];
#pragma unroll
        for (int i = 0; i < 8; ++i) {
            v[i]  = corrbuf[p][lane + 64 * i];
            av[i] = fabsf(v[i]);
        }
        unsigned usedm = 0u;
        int   top_i[KSP];
        float top_v[KSP];
#pragma unroll
        for (int r = 0; r < KSP; ++r) {
            float ba = -1.0f, bv = 0.0f;
            int   bi = 0x7FFFFFFF;
#pragma unroll
            for (int i = 0; i < 8; ++i) {
                if (!((usedm >> i) & 1u)) {
                    int idx = lane + 64 * i;
                    if (av[i] > ba || (av[i] == ba && idx < bi)) { ba = av[i]; bi = idx; bv = v[i]; }
                }
            }
            for (int off = 32; off; off >>= 1) {
                float oa = __shfl_xor(ba, off);
                int   oi = __shfl_xor(bi, off);
                float ov = __shfl_xor(bv, off);
                if (oa > ba || (oa == ba && oi < bi)) { ba = oa; bi = oi; bv = ov; }
            }
            top_i[r] = bi; top_v[r] = bv;
            if (lane == (bi & 63)) usedm |= (1u << (bi >> 6));
        }
        const float a5 = fabsf(top_v[KSP - 1]);
        const float lo = a5 - DELTA, hi = a5 + DELTA;
        int   nfinal = 0, fidx[KSP];
        float fval[KSP];
        int   nwin = 0, widx[8];
        float wvf[8];
#pragma unroll
        for (int r = 0; r < KSP; ++r) {
            if (fabsf(top_v[r]) > hi) { fidx[nfinal] = top_i[r]; fval[nfinal] = top_v[r]; ++nfinal; }
            else if (nwin < 8)        { widx[nwin] = top_i[r]; wvf[nwin] = top_v[r]; ++nwin; }
        }
#pragma unroll
        for (int i = 0; i < 8; ++i) {
            bool ex = (((usedm >> i) & 1u) == 0u) && (av[i] >= lo);
            unsigned long long m = __ballot(ex);
            while (m && nwin < 8) {
                int l = __ffsll(m) - 1; m &= m - 1;
                widx[nwin] = l + 64 * i;
                wvf[nwin]  = __shfl(v[i], l);
                ++nwin;
            }
        }
        const int need = KSP - nfinal;
        if (nwin == need) {
            for (int w = 0; w < nwin; ++w) { fidx[nfinal] = widx[w]; fval[nfinal] = wvf[w]; ++nfinal; }
        } else {
            int bb_ = np / (HO_ * WO_);
            int rr  = np - bb_ * (HO_ * WO_);
            int ho2 = rr / WO_;
            int wo2 = rr - ho2 * WO_;
            const float* xb = x + (size_t)bb_ * CHN * HH * WW;
            double wv64[8];
            for (int w = 0; w < nwin; ++w) {
                int a = widx[w];
                double s = 0.0;
                for (int t = 0; t < 16; ++t) {
                    int k  = lane + (t << 6);
                    int c  = k >> 4, pr = (k >> 2) & 3, pc = k & 3;
                    float xv = xb[((size_t)c * HH + (2 * ho2 + pr)) * WW + 2 * wo2 + pc];
                    float dv = D[(size_t)k * NATOMS + a];
                    s = fma((double)xv, (double)dv, s);
                }
                for (int off = 32; off; off >>= 1) s += __shfl_xor(s, off);
                wv64[w] = s;
            }
            unsigned taken = 0u;
            for (int scnt = 0; scnt < need; ++scnt) {
                int best = -1; double bbv = -1.0;
                for (int w = 0; w < nwin; ++w) {
                    if ((taken >> w) & 1u) continue;
                    double aw = fabs(wv64[w]);
                    if (aw > bbv || (aw == bbv && best >= 0 && widx[w] < widx[best])) { bbv = aw; best = w; }
                }
                taken |= 1u << best;
                fidx[nfinal] = widx[best];
                fval[nfinal] = (float)wv64[best];
                ++nfinal;
            }
        }
        if (lane == 0) {
#pragma unroll
            for (int r = 0; r < KSP; ++r) { sup_s[p][r] = fidx[r]; rhs_s[p][r] = fval[r]; }
        }
    }
    __syncthreads();

    if (tid < MT) {
        int p = tid, np = n0 + p;
        if (np < NPATCH) {
            int s[KSP];
            double A[KSP][KSP], bb[KSP];
#pragma unroll
            for (int i = 0; i < KSP; ++i) { s[i] = sup_s[p][i]; bb[i] = (double)rhs_s[p][i]; }
#pragma unroll
            for (int i = 0; i < KSP; ++i)
#pragma unroll
                for (int j = 0; j < KSP; ++j)
                    A[i][j] = (double)gram[(size_t)s[i] * NATOMS + s[j]] + (i == j ? 1e-10 : 0.0);
#pragma unroll
            for (int c = 0; c < KSP; ++c) {
                double inv = 1.0 / A[c][c];
#pragma unroll
                for (int r = 0; r < KSP; ++r) {
                    if (r > c) {
                        double f = A[r][c] * inv;
#pragma unroll
                        for (int cc = 0; cc < KSP; ++cc)
                            if (cc > c) A[r][cc] -= f * A[c][cc];
                        bb[r] -= f * bb[c];
                    }
                }
            }
#pragma unroll
            for (int r = KSP - 1; r >= 0; --r) {
                double t = bb[r];
#pragma unroll
                for (int cc = 0; cc < KSP; ++cc)
                    if (cc > r) t -= A[r][cc] * bb[cc];
                bb[r] = t / A[r][r];
            }
#pragma unroll
            for (int i = 0; i < KSP; ++i) {
                sup_out[(size_t)np * KSP + i] = s[i];
                val_out[(size_t)np * KSP + i] = (float)bb[i];
            }
        }
    }
}

__global__ __launch_bounds__(256) void recon_kernel_fb(const float* __restrict__ x,
                                                       const float* __restrict__ D,
                                                       const int* __restrict__ sup,
                                                       const float* __restrict__ val,
                                                       float* __restrict__ out,
                                                       double* __restrict__ partials) {
    double sqacc = 0.0;
    for (size_t o = (size_t)blockIdx.x * 256 + threadIdx.x; o < OUT_N; o += (size_t)FBLK * 256) {
        const int j = (int)(o & 127);
        const int i = (int)((o >> 7) & 127);
        const int c = (int)((o >> 14) & 63);
        const int b = (int)(o >> 20);
        const float xv = x[o];
        float z = 0.0f;
        const int pr = (i & 1) ? 1 : 2;
        const int pc = (j & 1) ? 1 : 2;
        const int ho = (i - pr) >> 1;
        const int wo = (j - pc) >> 1;
        if (ho >= 0 && ho < HO_ && wo >= 0 && wo < WO_) {
            const int n = (b * HO_ + ho) * WO_ + wo;
            const int k = c * 16 + pr * 4 + pc;
            const int*   sp5 = sup + (size_t)n * KSP;
            const float* vp5 = val + (size_t)n * KSP;
            float s = 0.0f;
#pragma unroll
            for (int t = 0; t < KSP; ++t)
                s = fmaf(vp5[t], D[(size_t)k * NATOMS + sp5[t]], s);
            z = s;
        }
        out[o] = xv + (z - xv);
        const float d = z - xv;
        sqacc += (double)d * (double)d;
    }
    for (int off = 32; off; off >>= 1) sqacc += __shfl_xor(sqacc, off);
    __shared__ double red[4];
    const int lane = threadIdx.x & 63, wv = threadIdx.x >> 6;
    if (lane == 0) red[wv] = sqacc;
    __syncthreads();
    if (threadIdx.x == 0) partials[blockIdx.x] = red[0] + red[1] + red[2] + red[3];
}

__global__ __launch_bounds__(256) void loss_kernel(const double* __restrict__ partials,
                                                   float* __restrict__ out) {
    double s = 0.0;
    for (int i = threadIdx.x; i < FBLK; i += 256) s += partials[i];
    for (int off = 32; off; off >>= 1) s += __shfl_xor(s, off);
    __shared__ double red[4];
    const int lane = threadIdx.x & 63, wv = threadIdx.x >> 6;
    if (lane == 0) red[wv] = s;
    __syncthreads();
    if (threadIdx.x == 0) {
        double m = (red[0] + red[1] + red[2] + red[3]) / (double)OUT_N;
        out[OUT_N] = (float)(m + 0.25 * m);
    }
}

// ---------------------------------------------------------------------------
extern "C" void kernel_launch(void* const* d_in, const int* in_sizes, int n_in,
                              void* d_out, int out_size, void* d_ws, size_t ws_size,
                              hipStream_t stream) {
    const float* x = (const float*)d_in[0];
    const float* D = (const float*)d_in[1];
    float* out = (float*)d_out;
    char* ws = (char*)d_ws;

    size_t off = 0;
    auto take = [&](size_t bytes) { char* p = ws + off; off += (bytes + 255) & ~(size_t)255; return p; };
    float*    gram     = (float*)take((size_t)NATOMS * NATOMS * 4);
    int*      sup      = (int*)take((size_t)NPATCH * KSP * 4);
    float*    val      = (float*)take((size_t)NPATCH * KSP * 4);
    double*   partials = (double*)take((size_t)FBLK * 8);
    double*   rpart    = (double*)take((size_t)RPB * 8);
    double*   bpart    = (double*)take((size_t)512 * 8);
    unsigned* topk     = (unsigned*)take((size_t)NPATCH * 16 * 4);
    f16*   Dth  = (f16*)take((size_t)NATOMS * PDIM * 2);
    f16*   Dtl  = (f16*)take((size_t)NATOMS * PDIM * 2);
    f16*   Xh   = (f16*)take((size_t)MPAD * PDIM * 2);
    f16*   corr = (f16*)take((size_t)MPAD * NATOMS * 2);
    const bool big = (off <= ws_size);

    if (big) {
        hipMemsetAsync(Xh + (size_t)NPATCH * PDIM, 0,
                       (size_t)(MPAD - NPATCH) * PDIM * sizeof(f16), stream);
        extract_kernel<<<8 * HO_ * 4, 256, 0, stream>>>(x, Xh);
        dtrans_kernel<<<dim3(16, 8), 256, 0, stream>>>(D, Dth, Dtl);
        gram_kernel<<<dim3(16, 16), 256, 0, stream>>>(D, gram);
        border_kernel<<<512, 64, 0, stream>>>(x, out, bpart);
        gemm_kernel<<<dim3(MPAD / 128, NATOMS / 256), 512, 0, stream>>>(Xh, Dth, corr);
        topred_kernel<<<(NPATCH + 15) / 16, 512, 0, stream>>>(corr, topk);
        topfin_kernel<<<NPATCH / 2, 64, 0, stream>>>(topk, corr, x, D, gram, sup, val);
        reconp_kernel<<<RPB, 256, 0, stream>>>(x, Dth, Dtl, sup, val, out, rpart);
        loss2_kernel<<<1, 256, 0, stream>>>(rpart, bpart, out);
    } else {
        gram_kernel<<<dim3(16, 16), 256, 0, stream>>>(D, gram);
        corr_kernel_fb<<<(NPATCH + MT - 1) / MT, 256, 0, stream>>>(x, D, gram, sup, val);
        recon_kernel_fb<<<FBLK, 256, 0, stream>>>(x, D, sup, val, out, partials);
        loss_kernel<<<1, 256, 0, stream>>>(partials, out);
    }
}

// Round 24
// 226.957 us; speedup vs baseline: 1.1072x; 1.0954x over previous
//
#include <hip/hip_runtime.h>

#define CHN    64
#define NATOMS 512
#define PDIM   1024
#define KSP    5
#define HO_    63
#define WO_    63
#define NPATCH 31752
#define MPAD   31872          // 249 * 128
#define HH     128
#define WW     128
#define MT     16
#define OUT_N  8388608
#define DELTA  6e-3f
#define QGUARD 2.5e-3f
#define FBLK   2048
#define RPB    ((NPATCH + 15) / 16)   // 1985 reconp blocks

typedef _Float16 f16;
typedef _Float16 f16x8 __attribute__((ext_vector_type(8)));
typedef float    f32x4 __attribute__((ext_vector_type(4)));
typedef float    f32x2 __attribute__((ext_vector_type(2)));

static __device__ __forceinline__ void gload_lds16(const void* g, void* l) {
    __builtin_amdgcn_global_load_lds(
        (const __attribute__((address_space(1))) unsigned int*)g,
        (__attribute__((address_space(3))) unsigned int*)l, 16, 0, 0);
}

static __device__ inline f32x2 fma2(f32x2 a, f32x2 b, f32x2 c) {
#if __has_builtin(__builtin_elementwise_fma)
    return __builtin_elementwise_fma(a, b, c);
#else
    f32x2 r; r.x = fmaf(a.x, b.x, c.x); r.y = fmaf(a.y, b.y, c.y); return r;
#endif
}

// ---- u32 key: (abs>>11)<<11 | (1023-idx)<<1 | sign ----
static __device__ __forceinline__ unsigned mk_key32(float v, int idx) {
    unsigned vb = __float_as_uint(v);
    unsigned ab = vb & 0x7FFFFFFFu;
    return ((ab >> 11) << 11) | ((unsigned)(1023 - idx) << 1) | (vb >> 31);
}
static __device__ __forceinline__ int key32_idx(unsigned k) {
    return 1023 - (int)((k >> 1) & 1023u);
}

#define CEU(s, i, j) { unsigned _a = s[i], _b = s[j]; \
                       s[i] = _a > _b ? _a : _b; s[j] = _a > _b ? _b : _a; }

#define SORT8(s) \
    CEU(s,0,1) CEU(s,2,3) CEU(s,4,5) CEU(s,6,7) \
    CEU(s,0,2) CEU(s,1,3) CEU(s,4,6) CEU(s,5,7) \
    CEU(s,1,2) CEU(s,5,6) \
    CEU(s,0,4) CEU(s,1,5) CEU(s,2,6) CEU(s,3,7) \
    CEU(s,2,4) CEU(s,3,5) \
    CEU(s,1,2) CEU(s,3,4) CEU(s,5,6)

#define MERGE8(s, a, b) { \
    unsigned L[8]; \
    L[0] = a[0] > b[7] ? a[0] : b[7]; L[1] = a[1] > b[6] ? a[1] : b[6]; \
    L[2] = a[2] > b[5] ? a[2] : b[5]; L[3] = a[3] > b[4] ? a[3] : b[4]; \
    L[4] = a[4] > b[3] ? a[4] : b[3]; L[5] = a[5] > b[2] ? a[5] : b[2]; \
    L[6] = a[6] > b[1] ? a[6] : b[1]; L[7] = a[7] > b[0] ? a[7] : b[0]; \
    CEU(L,0,4) CEU(L,1,5) CEU(L,2,6) CEU(L,3,7) \
    CEU(L,0,2) CEU(L,1,3) CEU(L,4,6) CEU(L,5,7) \
    CEU(L,0,1) CEU(L,2,3) CEU(L,4,5) CEU(L,6,7) \
    for (int _i = 0; _i < 8; ++_i) s[_i] = L[_i]; }

// ---------------- gram = D^T D, 32x32 tiles, fp32 accumulate ----------------
__global__ __launch_bounds__(256) void gram_kernel(const float* __restrict__ D,
                                                   float* __restrict__ gram) {
    __shared__ float Ti[64][32];
    __shared__ float Tj[64][32];
    const int tid = threadIdx.x;
    const int i0 = blockIdx.x * 32, j0 = blockIdx.y * 32;
    const int ri  = tid >> 3;
    const int rj0 = (tid & 7) * 4;
    float acc[4] = {0.f, 0.f, 0.f, 0.f};
    for (int k0 = 0; k0 < PDIM; k0 += 64) {
        __syncthreads();
#pragma unroll
        for (int s = 0; s < 8; ++s) {
            int e = tid + 256 * s;
            int kk = e >> 5, col = e & 31;
            Ti[kk][col] = D[(size_t)(k0 + kk) * NATOMS + i0 + col];
            Tj[kk][col] = D[(size_t)(k0 + kk) * NATOMS + j0 + col];
        }
        __syncthreads();
#pragma unroll 4
        for (int kk = 0; kk < 64; ++kk) {
            float ti = Ti[kk][ri];
#pragma unroll
            for (int q = 0; q < 4; ++q)
                acc[q] = fmaf(ti, Tj[kk][rj0 + q], acc[q]);
        }
    }
#pragma unroll
    for (int q = 0; q < 4; ++q)
        gram[(size_t)(i0 + ri) * NATOMS + j0 + rj0 + q] = acc[q];
}

// ------------- patch extraction (coalesced): x -> Xh [MPAD][1024] f16 -------
__global__ __launch_bounds__(256) void extract_kernel(const float* __restrict__ x,
                                                      f16* __restrict__ Xh) {
    __shared__ float xs[16][4][129];
    const int bid = blockIdx.x;
    const int cg  = bid & 3;
    const int t   = bid >> 2;
    const int ho  = t % HO_;
    const int b   = t / HO_;

    for (int i = threadIdx.x; i < 64 * 32; i += 256) {
        int r = i >> 5;
        int q = i & 31;
        int c = r >> 2, pr = r & 3;
        float4 v = *(const float4*)(x + ((size_t)(b * CHN + cg * 16 + c) * HH
                                         + (2 * ho + pr)) * WW + q * 4);
        xs[c][pr][q * 4 + 0] = v.x;
        xs[c][pr][q * 4 + 1] = v.y;
        xs[c][pr][q * 4 + 2] = v.z;
        xs[c][pr][q * 4 + 3] = v.w;
    }
    __syncthreads();

    for (int p = threadIdx.x; p < WO_ * 16; p += 256) {
        int wo = p >> 4;
        int c  = p & 15;
        f16 h[16];
#pragma unroll
        for (int pr = 0; pr < 4; ++pr)
#pragma unroll
            for (int pc = 0; pc < 4; ++pc)
                h[pr * 4 + pc] = (f16)xs[c][pr][2 * wo + pc];
        int n = (b * HO_ + ho) * WO_ + wo;
        f16x8 v0, v1;
#pragma unroll
        for (int i2 = 0; i2 < 8; ++i2) { v0[i2] = h[i2]; v1[i2] = h[8 + i2]; }
        f16* dh = Xh + (size_t)n * PDIM + (cg * 16 + c) * 16;
        *(f16x8*)dh = v0; *(f16x8*)(dh + 8) = v1;
    }
}

// ------------- D -> Dt transpose via LDS tiles (coalesced both sides) -------
__global__ __launch_bounds__(256) void dtrans_kernel(const float* __restrict__ D,
                                                     f16* __restrict__ Dth,
                                                     f16* __restrict__ Dtl) {
    __shared__ float ts[64][65];
    const int k0 = blockIdx.x * 64;
    const int n0 = blockIdx.y * 64;

    for (int i = threadIdx.x; i < 64 * 16; i += 256) {
        int r = i >> 4;
        int q = i & 15;
        float4 v = *(const float4*)(D + (size_t)(k0 + r) * NATOMS + n0 + q * 4);
        ts[r][q * 4 + 0] = v.x;
        ts[r][q * 4 + 1] = v.y;
        ts[r][q * 4 + 2] = v.z;
        ts[r][q * 4 + 3] = v.w;
    }
    __syncthreads();

    {
        int i = threadIdx.x;
        int nn = i >> 2, q = i & 3;
        f16 h[16], l[16];
#pragma unroll
        for (int j = 0; j < 16; ++j) {
            float v = ts[q * 16 + j][nn];
            f16 hh = (f16)v;
            h[j] = hh;
            l[j] = (f16)(v - (float)hh);
        }
        f16x8 h0, h1, l0, l1;
#pragma unroll
        for (int j = 0; j < 8; ++j) { h0[j] = h[j]; h1[j] = h[8 + j]; l0[j] = l[j]; l1[j] = l[8 + j]; }
        f16* dh = Dth + (size_t)(n0 + nn) * PDIM + k0 + q * 16;
        f16* dl = Dtl + (size_t)(n0 + nn) * PDIM + k0 + q * 16;
        *(f16x8*)dh = h0; *(f16x8*)(dh + 8) = h1;
        *(f16x8*)dl = l0; *(f16x8*)(dl + 8) = l1;
    }
}

// ------------- MFMA GEMM: corr[MPAD][512] (f16) = Xh . Dth^T ----------------
__global__ __launch_bounds__(512) void gemm_kernel(const f16* __restrict__ Xh,
                                                   const f16* __restrict__ Dth,
                                                   f16* __restrict__ corr) {
    __shared__ char lds[98304];
    const int tid  = threadIdx.x;
    const int lane = tid & 63;
    const int wave = tid >> 6;
    const size_t arow0 = (size_t)blockIdx.x * 128;
    const int    brow0 = blockIdx.y * 256;
    const int wm = wave >> 2;
    const int wn = wave & 3;

    f32x4 acc[4][4];
#pragma unroll
    for (int m = 0; m < 4; ++m)
#pragma unroll
        for (int n = 0; n < 4; ++n) acc[m][n] = (f32x4){0.f, 0.f, 0.f, 0.f};

    const char* asrc[2]; int adst[2];
#pragma unroll
    for (int i = 0; i < 2; ++i) {
        int p = tid * 16 + i * 8192;
        int row = p >> 7, sc = ((p >> 4) & 7) ^ (row & 7);
        asrc[i] = (const char*)Xh + (arow0 + row) * 2048 + sc * 16;
        adst[i] = p;
    }
    const char* bsrc[4]; int bdst[4];
#pragma unroll
    for (int i = 0; i < 4; ++i) {
        int p = tid * 16 + i * 8192;
        int row = p >> 7, sc = ((p >> 4) & 7) ^ (row & 7);
        bsrc[i] = (const char*)Dth + (size_t)(brow0 + row) * 2048 + sc * 16;
        bdst[i] = 16384 + p;
    }

    int aoff[4][2], boff[4][2];
#pragma unroll
    for (int m = 0; m < 4; ++m)
#pragma unroll
        for (int ks = 0; ks < 2; ++ks) {
            int row = wm * 64 + m * 16 + (lane & 15);
            int ch  = (ks * 4 + (lane >> 4)) ^ (row & 7);
            aoff[m][ks] = row * 128 + ch * 16;
        }
#pragma unroll
    for (int n = 0; n < 4; ++n)
#pragma unroll
        for (int ks = 0; ks < 2; ++ks) {
            int row = wn * 64 + n * 16 + (lane & 15);
            int ch  = (ks * 4 + (lane >> 4)) ^ (row & 7);
            boff[n][ks] = 16384 + row * 128 + ch * 16;
        }

#pragma unroll
    for (int i = 0; i < 2; ++i) gload_lds16(asrc[i], lds + adst[i]);
#pragma unroll
    for (int i = 0; i < 4; ++i) gload_lds16(bsrc[i], lds + bdst[i]);
#pragma unroll
    for (int i = 0; i < 2; ++i) asrc[i] += 128;
#pragma unroll
    for (int i = 0; i < 4; ++i) bsrc[i] += 128;
    __syncthreads();

    int bufo = 0;
    for (int kt = 0; kt < 16; ++kt) {
        const int nbuf = bufo ^ 49152;
        if (kt + 1 < 16) {
#pragma unroll
            for (int i = 0; i < 2; ++i) { gload_lds16(asrc[i], lds + nbuf + adst[i]); asrc[i] += 128; }
#pragma unroll
            for (int i = 0; i < 4; ++i) { gload_lds16(bsrc[i], lds + nbuf + bdst[i]); bsrc[i] += 128; }
        }
#pragma unroll
        for (int ks = 0; ks < 2; ++ks) {
            f16x8 a[4], b[4];
#pragma unroll
            for (int m = 0; m < 4; ++m) a[m] = *(const f16x8*)(lds + bufo + aoff[m][ks]);
#pragma unroll
            for (int n = 0; n < 4; ++n) b[n] = *(const f16x8*)(lds + bufo + boff[n][ks]);
#pragma unroll
            for (int m = 0; m < 4; ++m)
#pragma unroll
                for (int n = 0; n < 4; ++n)
                    acc[m][n] = __builtin_amdgcn_mfma_f32_16x16x32_f16(a[m], b[n], acc[m][n], 0, 0, 0);
        }
        if (kt + 1 < 16) { __syncthreads(); bufo = nbuf; }
    }

#pragma unroll
    for (int m = 0; m < 4; ++m) {
        size_t row_b = arow0 + wm * 64 + m * 16 + (lane >> 4) * 4;
#pragma unroll
        for (int n = 0; n < 4; ++n) {
            int col = brow0 + wn * 64 + n * 16 + (lane & 15);
#pragma unroll
            for (int i = 0; i < 4; ++i)
                corr[(row_b + i) * NATOMS + col] = (f16)acc[m][n][i];
        }
    }
}

// ------- phase 1: sorted top-8 keys + values (f16 corr, cache-hot) ----------
__global__ __launch_bounds__(512) void topred_kernel(const f16* __restrict__ corr,
                                                     unsigned* __restrict__ topk) {
    const int tid = threadIdx.x;
    const int sl  = tid & 31;
    const int hw  = tid >> 5;                 // half-wave 0..15
    const int np  = blockIdx.x * 16 + hw;     // may run into pad rows (< MPAD)

    const f16* row = corr + (size_t)np * NATOMS;
    const f16* cr = row + sl * 16;
    f16x8 c0 = *(const f16x8*)cr;
    f16x8 c1 = *(const f16x8*)(cr + 8);
    unsigned k[16];
#pragma unroll
    for (int j = 0; j < 8; ++j) {
        k[j]     = mk_key32((float)c0[j], sl * 16 + j);
        k[8 + j] = mk_key32((float)c1[j], sl * 16 + 8 + j);
    }

    unsigned a[8], b8[8];
#pragma unroll
    for (int i = 0; i < 8; ++i) { a[i] = k[i]; b8[i] = k[8 + i]; }
    SORT8(a)
    SORT8(b8)
    unsigned s[8];
    MERGE8(s, a, b8)
#pragma unroll
    for (int off = 16; off; off >>= 1) {
        unsigned p[8];
#pragma unroll
        for (int i = 0; i < 8; ++i) p[i] = (unsigned)__shfl_xor((int)s[i], off);
        MERGE8(s, s, p)
    }

    if (sl == 0 && np < NPATCH) {
        float v0 = (float)row[key32_idx(s[0])], v1 = (float)row[key32_idx(s[1])];
        float v2 = (float)row[key32_idx(s[2])], v3 = (float)row[key32_idx(s[3])];
        float v4 = (float)row[key32_idx(s[4])], v5 = (float)row[key32_idx(s[5])];
        float v6 = (float)row[key32_idx(s[6])], v7 = (float)row[key32_idx(s[7])];
        uint4* dst = (uint4*)(topk + (size_t)np * 16);
        dst[0] = make_uint4(s[0], s[1], s[2], s[3]);
        dst[1] = make_uint4(s[4], s[5], s[6], s[7]);
        dst[2] = make_uint4(__float_as_uint(v0), __float_as_uint(v1),
                            __float_as_uint(v2), __float_as_uint(v3));
        dst[3] = make_uint4(__float_as_uint(v4), __float_as_uint(v5),
                            __float_as_uint(v6), __float_as_uint(v7));
    }
}

// ------- phase 2: 64-thr blocks; parallel gram gather; unrolled arbitration -
__global__ __launch_bounds__(64) void topfin_kernel(const unsigned* __restrict__ topk,
                                                    const f16* __restrict__ corr,
                                                    const float* __restrict__ x,
                                                    const float* __restrict__ D,
                                                    const float* __restrict__ gram,
                                                    int* __restrict__ sup_out,
                                                    float* __restrict__ val_out) {
    const int lane = threadIdx.x & 63;
    const int half = lane >> 5;
    const int sl   = lane & 31;
    const int hw   = threadIdx.x >> 5;        // 0..1
    const int np   = blockIdx.x * 2 + hw;     // grid*2 == NPATCH exactly

    unsigned s[8];
    float    tval[8];
    {
        const uint4* src = (const uint4*)(topk + (size_t)np * 16);
        uint4 s0 = src[0], s1 = src[1], v0 = src[2], v1 = src[3];
        s[0] = s0.x; s[1] = s0.y; s[2] = s0.z; s[3] = s0.w;
        s[4] = s1.x; s[5] = s1.y; s[6] = s1.z; s[7] = s1.w;
        tval[0] = __uint_as_float(v0.x); tval[1] = __uint_as_float(v0.y);
        tval[2] = __uint_as_float(v0.z); tval[3] = __uint_as_float(v0.w);
        tval[4] = __uint_as_float(v1.x); tval[5] = __uint_as_float(v1.y);
        tval[6] = __uint_as_float(v1.z); tval[7] = __uint_as_float(v1.w);
    }
    int tidx[8];
#pragma unroll
    for (int r = 0; r < 8; ++r) tidx[r] = key32_idx(s[r]);

    const float a5 = fabsf(tval[KSP - 1]);
    const float lo = fmaxf(a5 - DELTA, 0.0f);
    const float hi = a5 + DELTA;
    const unsigned lokey = (__float_as_uint(fmaxf(lo - QGUARD, 0.0f)) >> 11) << 11;

    int   nfinal = 0, fidx[KSP];
    float fval[KSP];
    int   nwin = 0, widx[8];
    float wvf[8];
#pragma unroll
    for (int r = 0; r < KSP; ++r) {
        if (fabsf(tval[r]) > hi) { fidx[nfinal] = tidx[r]; fval[nfinal] = tval[r]; ++nfinal; }
        else                     { widx[nwin] = tidx[r]; wvf[nwin] = tval[r]; ++nwin; }
    }
#pragma unroll
    for (int r = KSP; r < 8; ++r) {
        if (fabsf(tval[r]) >= lo && nwin < 8) { widx[nwin] = tidx[r]; wvf[nwin] = tval[r]; ++nwin; }
    }

    // rescan for extras beyond top-8 (only when the 8th key is inside window)
    if (s[7] >= lokey) {
        const f16* cr = corr + (size_t)np * NATOMS + sl * 16;
        f16x8 c0 = *(const f16x8*)cr;
        f16x8 c1 = *(const f16x8*)(cr + 8);
        unsigned k[16];
        float vbuf[16];
#pragma unroll
        for (int j = 0; j < 8; ++j) {
            vbuf[j]     = (float)c0[j];
            vbuf[8 + j] = (float)c1[j];
            k[j]        = mk_key32(vbuf[j], sl * 16 + j);
            k[8 + j]    = mk_key32(vbuf[8 + j], sl * 16 + 8 + j);
        }
#pragma unroll
        for (int i = 0; i < 16; ++i) {
            bool ex = (k[i] < s[7]) && (k[i] >= lokey);
            unsigned m = (unsigned)(__ballot(ex) >> (half * 32));
            while (m && nwin < 8) {
                int l = __ffs(m) - 1; m &= m - 1;
                unsigned kk = (unsigned)__shfl((int)k[i], l + half * 32);
                float vv2 = __shfl(vbuf[i], l + half * 32);
                if (fabsf(vv2) >= lo) { widx[nwin] = key32_idx(kk); wvf[nwin] = vv2; ++nwin; }
            }
        }
    }

    const int need = KSP - nfinal;
    if (nwin == need) {
        for (int w = 0; w < nwin; ++w) { fidx[nfinal] = widx[w]; fval[nfinal] = wvf[w]; ++nfinal; }
    } else {
        // fp64 arbitration of the boundary window (rare), 32-lane dot
        int bb_ = np / (HO_ * WO_);
        int rr  = np - bb_ * (HO_ * WO_);
        int ho2 = rr / WO_;
        int wo2 = rr - ho2 * WO_;
        const float* xb = x + (size_t)bb_ * CHN * HH * WW;
        double wv64[8];
        for (int w = 0; w < nwin; ++w) {
            int at = widx[w];
            double sd = 0.0;
#pragma unroll
            for (int t = 0; t < 32; ++t) {
                int kk = sl + (t << 5);
                int c  = kk >> 4, pr = (kk >> 2) & 3, pc = kk & 3;
                float xv = xb[((size_t)c * HH + (2 * ho2 + pr)) * WW + 2 * wo2 + pc];
                float dv = D[(size_t)kk * NATOMS + at];
                sd = fma((double)xv, (double)dv, sd);
            }
            for (int off = 16; off; off >>= 1) sd += __shfl_xor(sd, off);
            wv64[w] = sd;
        }
        unsigned taken = 0u;
        for (int scnt = 0; scnt < need; ++scnt) {
            int best = -1; double bbv = -1.0;
            for (int w = 0; w < nwin; ++w) {
                if ((taken >> w) & 1u) continue;
                double aw = fabs(wv64[w]);
                if (aw > bbv || (aw == bbv && best >= 0 && widx[w] < widx[best])) { bbv = aw; best = w; }
            }
            taken |= 1u << best;
            fidx[nfinal] = widx[best];
            fval[nfinal] = (float)wv64[best];
            ++nfinal;
        }
    }

    // ---- 5x5 solve (fp32); gram gathered in PARALLEL across lanes ----
    float A[KSP][KSP], bb[KSP];
    {
        float gv = 0.f;
        if (sl < 25) {
            int gi = sl / 5, gj = sl - 5 * gi;
            gv = gram[(size_t)fidx[gi] * NATOMS + fidx[gj]];
        }
#pragma unroll
        for (int i = 0; i < KSP; ++i)
#pragma unroll
            for (int j = 0; j < KSP; ++j)
                A[i][j] = __shfl(gv, i * 5 + j + half * 32);
    }
#pragma unroll
    for (int i = 0; i < KSP; ++i) bb[i] = fval[i];
#pragma unroll
    for (int c = 0; c < KSP; ++c) {
        float inv = 1.0f / A[c][c];
#pragma unroll
        for (int r = 0; r < KSP; ++r) {
            if (r > c) {
                float f = A[r][c] * inv;
#pragma unroll
                for (int cc = 0; cc < KSP; ++cc)
                    if (cc > c) A[r][cc] -= f * A[c][cc];
                bb[r] -= f * bb[c];
            }
        }
    }
#pragma unroll
    for (int r = KSP - 1; r >= 0; --r) {
        float t = bb[r];
#pragma unroll
        for (int cc = 0; cc < KSP; ++cc)
            if (cc > r) t -= A[r][cc] * bb[cc];
        bb[r] = t / A[r][r];
    }
    if (sl == 0) {
#pragma unroll
        for (int i = 0; i < KSP; ++i) {
            sup_out[(size_t)np * KSP + i] = fidx[i];
            val_out[(size_t)np * KSP + i] = bb[i];
        }
    }
}

// ------- fused reconstruction: LDS transpose + direct out write -------------
// Block = 16 consecutive patches. Compute phase (lane=channel) identical to
// all passing versions; per-patch inner-2x2 staged in LDS; write phase maps
// threads to (c, nl) and writes out = x + (z - x) at the 4 covered pixels,
// accumulating the fp64 loss partial. (Round-21 configuration, 226.7 us.)
__global__ __launch_bounds__(256) void reconp_kernel(const float* __restrict__ x,
                                                     const f16* __restrict__ Dth,
                                                     const f16* __restrict__ Dtl,
                                                     const int* __restrict__ sup,
                                                     const float* __restrict__ val,
                                                     float* __restrict__ out,
                                                     double* __restrict__ rpart) {
    __shared__ f32x4 zbuf[16][65];
    __shared__ double red[4];
    const int lane = threadIdx.x & 63;
    const int wave = threadIdx.x >> 6;
    const int n0   = blockIdx.x * 16;

#pragma unroll
    for (int it = 0; it < 4; ++it) {
        const int nl = it * 4 + wave;
        const int n  = n0 + nl;
        if (n < NPATCH) {
            const int*   sp = sup + (size_t)n * KSP;
            const float* vp = val + (size_t)n * KSP;
            float z[16];
#pragma unroll
            for (int i = 0; i < 16; ++i) z[i] = 0.f;
#pragma unroll
            for (int t = 0; t < KSP; ++t) {
                int a = sp[t]; float v = vp[t];
                const f16* dh = Dth + (size_t)a * PDIM + lane * 16;
                const f16* dl = Dtl + (size_t)a * PDIM + lane * 16;
                f16x8 h0 = *(const f16x8*)dh, h1 = *(const f16x8*)(dh + 8);
                f16x8 l0 = *(const f16x8*)dl, l1 = *(const f16x8*)(dl + 8);
#pragma unroll
                for (int i = 0; i < 8; ++i) {
                    z[i]     = fmaf(v, (float)h0[i] + (float)l0[i], z[i]);
                    z[8 + i] = fmaf(v, (float)h1[i] + (float)l1[i], z[8 + i]);
                }
            }
            zbuf[nl][lane] = (f32x4){ z[5], z[6], z[9], z[10] };
        }
    }
    __syncthreads();

    double sq = 0.0;
#pragma unroll
    for (int k = 0; k < 4; ++k) {
        int f  = threadIdx.x + 256 * k;       // 0..1023, nl minor -> coalesced
        int c  = f >> 4;
        int nl = f & 15;
        int n  = n0 + nl;
        if (n < NPATCH) {
            int b  = n / (HO_ * WO_);
            int r  = n - b * (HO_ * WO_);
            int ho = r / WO_, wo = r - ho * WO_;
            f32x4 zv = zbuf[nl][c];
            size_t base = ((size_t)(b * CHN + c) * HH + (2 * ho + 1)) * WW + (2 * wo + 1);
            float x0 = x[base],      x1 = x[base + 1];
            float x2 = x[base + WW], x3 = x[base + WW + 1];
            out[base]          = x0 + (zv.x - x0);
            out[base + 1]      = x1 + (zv.y - x1);
            out[base + WW]     = x2 + (zv.z - x2);
            out[base + WW + 1] = x3 + (zv.w - x3);
            float d0 = zv.x - x0, d1 = zv.y - x1, d2 = zv.z - x2, d3 = zv.w - x3;
            sq += (double)d0 * d0 + (double)d1 * d1 + (double)d2 * d2 + (double)d3 * d3;
        }
    }

    for (int off = 32; off; off >>= 1) sq += __shfl_xor(sq, off);
    if (lane == 0) red[wave] = sq;
    __syncthreads();
    if (threadIdx.x == 0) rpart[blockIdx.x] = red[0] + red[1] + red[2] + red[3];
}

// ------- border pixels: z_q = 0 -> out = x + (0 - x), loss += x^2 -----------
__global__ __launch_bounds__(256) void border_kernel(const float* __restrict__ x,
                                                     float* __restrict__ out,
                                                     double* __restrict__ bpart) {
    const int plane = blockIdx.x;             // b*CHN + c, 0..511
    const float* xp = x + (size_t)plane * HH * WW;
    float* op = out + (size_t)plane * HH * WW;
    double sq = 0.0;
    for (int idx = threadIdx.x; idx < 508; idx += 256) {
        int i, j;
        if (idx < 128)      { i = 0;         j = idx;       }
        else if (idx < 256) { i = 127;       j = idx - 128; }
        else if (idx < 382) { i = idx - 255; j = 0;         }   // i = 1..126
        else                { i = idx - 381; j = 127;       }   // i = 1..126
        float xv = xp[i * WW + j];
        op[i * WW + j] = xv + (0.0f - xv);
        sq += (double)xv * xv;
    }
    for (int off = 32; off; off >>= 1) sq += __shfl_xor(sq, off);
    __shared__ double red[4];
    const int lane = threadIdx.x & 63, wv = threadIdx.x >> 6;
    if (lane == 0) red[wv] = sq;
    __syncthreads();
    if (threadIdx.x == 0) bpart[blockIdx.x] = red[0] + red[1] + red[2] + red[3];
}

// ------- loss finalize: sum reconp + border partials ------------------------
__global__ __launch_bounds__(256) void loss2_kernel(const double* __restrict__ rpart,
                                                    const double* __restrict__ bpart,
                                                    float* __restrict__ out) {
    double s = 0.0;
    for (int i = threadIdx.x; i < RPB; i += 256) s += rpart[i];
    for (int i = threadIdx.x; i < 512; i += 256) s += bpart[i];
    for (int off = 32; off; off >>= 1) s += __shfl_xor(s, off);
    __shared__ double red[4];
    const int lane = threadIdx.x & 63, wv = threadIdx.x >> 6;
    if (lane == 0) red[wv] = s;
    __syncthreads();
    if (threadIdx.x == 0) {
        double m = (red[0] + red[1] + red[2] + red[3]) / (double)OUT_N;
        out[OUT_N] = (float)(m + 0.25 * m);
    }
}

// ======================= FALLBACK PATH (small ws) ===========================
__global__ __launch_bounds__(256) void corr_kernel_fb(const float* __restrict__ x,
                                                      const float* __restrict__ D,
                                                      const float* __restrict__ gram,
                                                      int* __restrict__ sup_out,
                                                      float* __restrict__ val_out) {
    __shared__ float pt[256 * MT];
    __shared__ float corrbuf[MT][NATOMS];
    __shared__ int   sup_s[MT][KSP];
    __shared__ float rhs_s[MT][KSP];

    const int tid  = threadIdx.x;
    const int lane = tid & 63;
    const int wave = tid >> 6;
    const int n0   = blockIdx.x * MT;
    const int sp  = lane & 15;
    const int spr = lane >> 4;

    int n = n0 + sp;
    bool pvalid = (n < NPATCH);
    int b = 0, ho = 0, wo = 0;
    if (pvalid) {
        b = n / (HO_ * WO_);
        int r = n - b * (HO_ * WO_);
        ho = r / WO_;
        wo = r - ho * WO_;
    }

    f32x2 accP[2][8];
#pragma unroll
    for (int a = 0; a < 2; ++a)
#pragma unroll
        for (int g = 0; g < 8; ++g) accP[a][g] = (f32x2)(0.f);

    for (int chunk = 0; chunk < 4; ++chunk) {
        __syncthreads();
#pragma unroll
        for (int t = 0; t < 4; ++t) {
            int s = wave + 4 * t;
            int c = chunk * 16 + s;
            float2 va = make_float2(0.f, 0.f), vb = make_float2(0.f, 0.f);
            if (pvalid) {
                const float* px = x + (((size_t)b * CHN + c) * HH + (2 * ho + spr)) * WW + 2 * wo;
                va = *(const float2*)px;
                vb = *(const float2*)(px + 2);
            }
            int kl = (s * 16 + spr * 4) * MT + sp;
            pt[kl]          = va.x;
            pt[kl + MT]     = va.y;
            pt[kl + 2 * MT] = vb.x;
            pt[kl + 3 * MT] = vb.y;
        }
        __syncthreads();
        const float* Dp = D + (size_t)chunk * 256 * NATOMS + 2 * tid;
#pragma unroll 4
        for (int k = 0; k < 256; ++k) {
            float2 dv = *(const float2*)(Dp + (size_t)k * NATOMS);
            f32x2 d00 = {dv.x, dv.x}, d11 = {dv.y, dv.y};
#pragma unroll
            for (int q = 0; q < 4; ++q) {
                const float4 f = *(const float4*)&pt[k * MT + 4 * q];
                f32x2 flo = {f.x, f.y}, fhi = {f.z, f.w};
                accP[0][2 * q]     = fma2(flo, d00, accP[0][2 * q]);
                accP[1][2 * q]     = fma2(flo, d11, accP[1][2 * q]);
                accP[0][2 * q + 1] = fma2(fhi, d00, accP[0][2 * q + 1]);
                accP[1][2 * q + 1] = fma2(fhi, d11, accP[1][2 * q + 1]);
            }
        }
    }
#pragma unroll
    for (int g = 0; g < 8; ++g) {
        *(float2*)&corrbuf[2 * g][2 * tid]     = make_float2(accP[0][g].x, accP[1][g].x);
        *(float2*)&corrbuf[2 * g + 1][2 * tid] = make_float2(accP[0][g].y, accP[1][g].y);
    }
    __syncthreads();

    for (int pi = 0; pi < 4; ++pi) {
        int p  = wave * 4 + pi;
        int np = n0 + p;
        if (np >= NPATCH) continue;
        float v[8], av[8];
#pragma unroll
        for (int i = 0; i < 8; ++i) {
            v[i]  = corrbuf[p][lane + 64 * i];
            av[i] = fabsf(v[i]);
        }
        unsigned usedm = 0u;
        int   top_i[KSP];
        float top_v[KSP];
#pragma unroll
        for (int r = 0; r < KSP; ++r) {
            float ba = -1.0f, bv = 0.0f;
            int   bi = 0x7FFFFFFF;
#pragma unroll
            for (int i = 0; i < 8; ++i) {
                if (!((usedm >> i) & 1u)) {
                    int idx = lane + 64 * i;
                    if (av[i] > ba || (av[i] == ba && idx < bi)) { ba = av[i]; bi = idx; bv = v[i]; }
                }
            }
            for (int off = 32; off; off >>= 1) {
                float oa = __shfl_xor(ba, off);
                int   oi = __shfl_xor(bi, off);
                float ov = __shfl_xor(bv, off);
                if (oa > ba || (oa == ba && oi < bi)) { ba = oa; bi = oi; bv = ov; }
            }
            top_i[r] = bi; top_v[r] = bv;
            if (lane == (bi & 63)) usedm |= (1u << (bi >> 6));
        }
        const float a5 = fabsf(top_v[KSP - 1]);
        const float lo = a5 - DELTA, hi = a5 + DELTA;
        int   nfinal = 0, fidx[KSP];
        float fval[KSP];
        int   nwin = 0, widx[8];
        float wvf[8];
#pragma unroll
        for (int r = 0; r < KSP; ++r) {
            if (fabsf(top_v[r]) > hi) { fidx[nfinal] = top_i[r]; fval[nfinal] = top_v[r]; ++nfinal; }
            else if (nwin < 8)        { widx[nwin] = top_i[r]; wvf[nwin] = top_v[r]; ++nwin; }
        }
#pragma unroll
        for (int i = 0; i < 8; ++i) {
            bool ex = (((usedm >> i) & 1u) == 0u) && (av[i] >= lo);
            unsigned long long m = __ballot(ex);
            while (m && nwin < 8) {
                int l = __ffsll(m) - 1; m &= m - 1;
                widx[nwin] = l + 64 * i;
                wvf[nwin]  = __shfl(v[i], l);
                ++nwin;
            }
        }
        const int need = KSP - nfinal;
        if (nwin == need) {
            for (int w = 0; w < nwin; ++w) { fidx[nfinal] = widx[w]; fval[nfinal] = wvf[w]; ++nfinal; }
        } else {
            int bb_ = np / (HO_ * WO_);
            int rr  = np - bb_ * (HO_ * WO_);
            int ho2 = rr / WO_;
            int wo2 = rr - ho2 * WO_;
            const float* xb = x + (size_t)bb_ * CHN * HH * WW;
            double wv64[8];
            for (int w = 0; w < nwin; ++w) {
                int a = widx[w];
                double s = 0.0;
                for (int t = 0; t < 16; ++t) {
                    int k  = lane + (t << 6);
                    int c  = k >> 4, pr = (k >> 2) & 3, pc = k & 3;
                    float xv = xb[((size_t)c * HH + (2 * ho2 + pr)) * WW + 2 * wo2 + pc];
                    float dv = D[(size_t)k * NATOMS + a];
                    s = fma((double)xv, (double)dv, s);
                }
                for (int off = 32; off; off >>= 1) s += __shfl_xor(s, off);
                wv64[w] = s;
            }
            unsigned taken = 0u;
            for (int scnt = 0; scnt < need; ++scnt) {
                int best = -1; double bbv = -1.0;
                for (int w = 0; w < nwin; ++w) {
                    if ((taken >> w) & 1u) continue;
                    double aw = fabs(wv64[w]);
                    if (aw > bbv || (aw == bbv && best >= 0 && widx[w] < widx[best])) { bbv = aw; best = w; }
                }
                taken |= 1u << best;
                fidx[nfinal] = widx[best];
                fval[nfinal] = (float)wv64[best];
                ++nfinal;
            }
        }
        if (lane == 0) {
#pragma unroll
            for (int r = 0; r < KSP; ++r) { sup_s[p][r] = fidx[r]; rhs_s[p][r] = fval[r]; }
        }
    }
    __syncthreads();

    if (tid < MT) {
        int p = tid, np = n0 + p;
        if (np < NPATCH) {
            int s[KSP];
            double A[KSP][KSP], bb[KSP];
#pragma unroll
            for (int i = 0; i < KSP; ++i) { s[i] = sup_s[p][i]; bb[i] = (double)rhs_s[p][i]; }
#pragma unroll
            for (int i = 0; i < KSP; ++i)
#pragma unroll
                for (int j = 0; j < KSP; ++j)
                    A[i][j] = (double)gram[(size_t)s[i] * NATOMS + s[j]] + (i == j ? 1e-10 : 0.0);
#pragma unroll
            for (int c = 0; c < KSP; ++c) {
                double inv = 1.0 / A[c][c];
#pragma unroll
                for (int r = 0; r < KSP; ++r) {
                    if (r > c) {
                        double f = A[r][c] * inv;
#pragma unroll
                        for (int cc = 0; cc < KSP; ++cc)
                            if (cc > c) A[r][cc] -= f * A[c][cc];
                        bb[r] -= f * bb[c];
                    }
                }
            }
#pragma unroll
            for (int r = KSP - 1; r >= 0; --r) {
                double t = bb[r];
#pragma unroll
                for (int cc = 0; cc < KSP; ++cc)
                    if (cc > r) t -= A[r][cc] * bb[cc];
                bb[r] = t / A[r][r];
            }
#pragma unroll
            for (int i = 0; i < KSP; ++i) {
                sup_out[(size_t)np * KSP + i] = s[i];
                val_out[(size_t)np * KSP + i] = (float)bb[i];
            }
        }
    }
}

__global__ __launch_bounds__(256) void recon_kernel_fb(const float* __restrict__ x,
                                                       const float* __restrict__ D,
                                                       const int* __restrict__ sup,
                                                       const float* __restrict__ val,
                                                       float* __restrict__ out,
                                                       double* __restrict__ partials) {
    double sqacc = 0.0;
    for (size_t o = (size_t)blockIdx.x * 256 + threadIdx.x; o < OUT_N; o += (size_t)FBLK * 256) {
        const int j = (int)(o & 127);
        const int i = (int)((o >> 7) & 127);
        const int c = (int)((o >> 14) & 63);
        const int b = (int)(o >> 20);
        const float xv = x[o];
        float z = 0.0f;
        const int pr = (i & 1) ? 1 : 2;
        const int pc = (j & 1) ? 1 : 2;
        const int ho = (i - pr) >> 1;
        const int wo = (j - pc) >> 1;
        if (ho >= 0 && ho < HO_ && wo >= 0 && wo < WO_) {
            const int n = (b * HO_ + ho) * WO_ + wo;
            const int k = c * 16 + pr * 4 + pc;
            const int*   sp5 = sup + (size_t)n * KSP;
            const float* vp5 = val + (size_t)n * KSP;
            float s = 0.0f;
#pragma unroll
            for (int t = 0; t < KSP; ++t)
                s = fmaf(vp5[t], D[(size_t)k * NATOMS + sp5[t]], s);
            z = s;
        }
        out[o] = xv + (z - xv);
        const float d = z - xv;
        sqacc += (double)d * (double)d;
    }
    for (int off = 32; off; off >>= 1) sqacc += __shfl_xor(sqacc, off);
    __shared__ double red[4];
    const int lane = threadIdx.x & 63, wv = threadIdx.x >> 6;
    if (lane == 0) red[wv] = sqacc;
    __syncthreads();
    if (threadIdx.x == 0) partials[blockIdx.x] = red[0] + red[1] + red[2] + red[3];
}

__global__ __launch_bounds__(256) void loss_kernel(const double* __restrict__ partials,
                                                   float* __restrict__ out) {
    double s = 0.0;
    for (int i = threadIdx.x; i < FBLK; i += 256) s += partials[i];
    for (int off = 32; off; off >>= 1) s += __shfl_xor(s, off);
    __shared__ double red[4];
    const int lane = threadIdx.x & 63, wv = threadIdx.x >> 6;
    if (lane == 0) red[wv] = s;
    __syncthreads();
    if (threadIdx.x == 0) {
        double m = (red[0] + red[1] + red[2] + red[3]) / (double)OUT_N;
        out[OUT_N] = (float)(m + 0.25 * m);
    }
}

// ---------------------------------------------------------------------------
extern "C" void kernel_launch(void* const* d_in, const int* in_sizes, int n_in,
                              void* d_out, int out_size, void* d_ws, size_t ws_size,
                              hipStream_t stream) {
    const float* x = (const float*)d_in[0];
    const float* D = (const float*)d_in[1];
    float* out = (float*)d_out;
    char* ws = (char*)d_ws;

    size_t off = 0;
    auto take = [&](size_t bytes) { char* p = ws + off; off += (bytes + 255) & ~(size_t)255; return p; };
    float*    gram     = (float*)take((size_t)NATOMS * NATOMS * 4);
    int*      sup      = (int*)take((size_t)NPATCH * KSP * 4);
    float*    val      = (float*)take((size_t)NPATCH * KSP * 4);
    double*   partials = (double*)take((size_t)FBLK * 8);
    double*   rpart    = (double*)take((size_t)RPB * 8);
    double*   bpart    = (double*)take((size_t)512 * 8);
    unsigned* topk     = (unsigned*)take((size_t)NPATCH * 16 * 4);
    f16*   Dth  = (f16*)take((size_t)NATOMS * PDIM * 2);
    f16*   Dtl  = (f16*)take((size_t)NATOMS * PDIM * 2);
    f16*   Xh   = (f16*)take((size_t)MPAD * PDIM * 2);
    f16*   corr = (f16*)take((size_t)MPAD * NATOMS * 2);
    const bool big = (off <= ws_size);

    if (big) {
        hipMemsetAsync(Xh + (size_t)NPATCH * PDIM, 0,
                       (size_t)(MPAD - NPATCH) * PDIM * sizeof(f16), stream);
        extract_kernel<<<8 * HO_ * 4, 256, 0, stream>>>(x, Xh);
        dtrans_kernel<<<dim3(16, 8), 256, 0, stream>>>(D, Dth, Dtl);
        gram_kernel<<<dim3(16, 16), 256, 0, stream>>>(D, gram);
        border_kernel<<<512, 256, 0, stream>>>(x, out, bpart);
        gemm_kernel<<<dim3(MPAD / 128, NATOMS / 256), 512, 0, stream>>>(Xh, Dth, corr);
        topred_kernel<<<(NPATCH + 15) / 16, 512, 0, stream>>>(corr, topk);
        topfin_kernel<<<NPATCH / 2, 64, 0, stream>>>(topk, corr, x, D, gram, sup, val);
        reconp_kernel<<<RPB, 256, 0, stream>>>(x, Dth, Dtl, sup, val, out, rpart);
        loss2_kernel<<<1, 256, 0, stream>>>(rpart, bpart, out);
    } else {
        gram_kernel<<<dim3(16, 16), 256, 0, stream>>>(D, gram);
        corr_kernel_fb<<<(NPATCH + MT - 1) / MT, 256, 0, stream>>>(x, D, gram, sup, val);
        recon_kernel_fb<<<FBLK, 256, 0, stream>>>(x, D, sup, val, out, partials);
        loss_kernel<<<1, 256, 0, stream>>>(partials, out);
    }
}

// Round 25
// 201.666 us; speedup vs baseline: 1.2460x; 1.1254x over previous
//
#include <hip/hip_runtime.h>

#define CHN    64
#define NATOMS 512
#define PDIM   1024
#define KSP    5
#define HO_    63
#define WO_    63
#define NPATCH 31752
#define MPAD   31872          // 249 * 128
#define HH     128
#define WW     128
#define MT     16
#define OUT_N  8388608
#define DELTA  6e-3f
#define QGUARD 2.5e-3f
#define FBLK   2048
#define RPB    ((NPATCH + 15) / 16)   // 1985 reconp blocks

typedef _Float16 f16;
typedef _Float16 f16x8 __attribute__((ext_vector_type(8)));
typedef _Float16 f16x4 __attribute__((ext_vector_type(4)));
typedef float    f32x4 __attribute__((ext_vector_type(4)));
typedef float    f32x2 __attribute__((ext_vector_type(2)));

static __device__ __forceinline__ void gload_lds16(const void* g, void* l) {
    __builtin_amdgcn_global_load_lds(
        (const __attribute__((address_space(1))) unsigned int*)g,
        (__attribute__((address_space(3))) unsigned int*)l, 16, 0, 0);
}

static __device__ inline f32x2 fma2(f32x2 a, f32x2 b, f32x2 c) {
#if __has_builtin(__builtin_elementwise_fma)
    return __builtin_elementwise_fma(a, b, c);
#else
    f32x2 r; r.x = fmaf(a.x, b.x, c.x); r.y = fmaf(a.y, b.y, c.y); return r;
#endif
}

// ---- u32 key: (abs>>11)<<11 | (1023-idx)<<1 | sign ----
static __device__ __forceinline__ unsigned mk_key32(float v, int idx) {
    unsigned vb = __float_as_uint(v);
    unsigned ab = vb & 0x7FFFFFFFu;
    return ((ab >> 11) << 11) | ((unsigned)(1023 - idx) << 1) | (vb >> 31);
}
static __device__ __forceinline__ int key32_idx(unsigned k) {
    return 1023 - (int)((k >> 1) & 1023u);
}

#define CEU(s, i, j) { unsigned _a = s[i], _b = s[j]; \
                       s[i] = _a > _b ? _a : _b; s[j] = _a > _b ? _b : _a; }

#define SORT8(s) \
    CEU(s,0,1) CEU(s,2,3) CEU(s,4,5) CEU(s,6,7) \
    CEU(s,0,2) CEU(s,1,3) CEU(s,4,6) CEU(s,5,7) \
    CEU(s,1,2) CEU(s,5,6) \
    CEU(s,0,4) CEU(s,1,5) CEU(s,2,6) CEU(s,3,7) \
    CEU(s,2,4) CEU(s,3,5) \
    CEU(s,1,2) CEU(s,3,4) CEU(s,5,6)

#define MERGE8(s, a, b) { \
    unsigned L[8]; \
    L[0] = a[0] > b[7] ? a[0] : b[7]; L[1] = a[1] > b[6] ? a[1] : b[6]; \
    L[2] = a[2] > b[5] ? a[2] : b[5]; L[3] = a[3] > b[4] ? a[3] : b[4]; \
    L[4] = a[4] > b[3] ? a[4] : b[3]; L[5] = a[5] > b[2] ? a[5] : b[2]; \
    L[6] = a[6] > b[1] ? a[6] : b[1]; L[7] = a[7] > b[0] ? a[7] : b[0]; \
    CEU(L,0,4) CEU(L,1,5) CEU(L,2,6) CEU(L,3,7) \
    CEU(L,0,2) CEU(L,1,3) CEU(L,4,6) CEU(L,5,7) \
    CEU(L,0,1) CEU(L,2,3) CEU(L,4,5) CEU(L,6,7) \
    for (int _i = 0; _i < 8; ++_i) s[_i] = L[_i]; }

// ---------------- gram = D^T D, 32x32 tiles, fp32 accumulate ----------------
__global__ __launch_bounds__(256) void gram_kernel(const float* __restrict__ D,
                                                   float* __restrict__ gram) {
    __shared__ float Ti[64][32];
    __shared__ float Tj[64][32];
    const int tid = threadIdx.x;
    const int i0 = blockIdx.x * 32, j0 = blockIdx.y * 32;
    const int ri  = tid >> 3;
    const int rj0 = (tid & 7) * 4;
    float acc[4] = {0.f, 0.f, 0.f, 0.f};
    for (int k0 = 0; k0 < PDIM; k0 += 64) {
        __syncthreads();
#pragma unroll
        for (int s = 0; s < 8; ++s) {
            int e = tid + 256 * s;
            int kk = e >> 5, col = e & 31;
            Ti[kk][col] = D[(size_t)(k0 + kk) * NATOMS + i0 + col];
            Tj[kk][col] = D[(size_t)(k0 + kk) * NATOMS + j0 + col];
        }
        __syncthreads();
#pragma unroll 4
        for (int kk = 0; kk < 64; ++kk) {
            float ti = Ti[kk][ri];
#pragma unroll
            for (int q = 0; q < 4; ++q)
                acc[q] = fmaf(ti, Tj[kk][rj0 + q], acc[q]);
        }
    }
#pragma unroll
    for (int q = 0; q < 4; ++q)
        gram[(size_t)(i0 + ri) * NATOMS + j0 + rj0 + q] = acc[q];
}

// ------------- patch extraction (coalesced): x -> Xh [MPAD][1024] f16 -------
__global__ __launch_bounds__(256) void extract_kernel(const float* __restrict__ x,
                                                      f16* __restrict__ Xh) {
    __shared__ float xs[16][4][129];
    const int bid = blockIdx.x;
    const int cg  = bid & 3;
    const int t   = bid >> 2;
    const int ho  = t % HO_;
    const int b   = t / HO_;

    for (int i = threadIdx.x; i < 64 * 32; i += 256) {
        int r = i >> 5;
        int q = i & 31;
        int c = r >> 2, pr = r & 3;
        float4 v = *(const float4*)(x + ((size_t)(b * CHN + cg * 16 + c) * HH
                                         + (2 * ho + pr)) * WW + q * 4);
        xs[c][pr][q * 4 + 0] = v.x;
        xs[c][pr][q * 4 + 1] = v.y;
        xs[c][pr][q * 4 + 2] = v.z;
        xs[c][pr][q * 4 + 3] = v.w;
    }
    __syncthreads();

    for (int p = threadIdx.x; p < WO_ * 16; p += 256) {
        int wo = p >> 4;
        int c  = p & 15;
        f16 h[16];
#pragma unroll
        for (int pr = 0; pr < 4; ++pr)
#pragma unroll
            for (int pc = 0; pc < 4; ++pc)
                h[pr * 4 + pc] = (f16)xs[c][pr][2 * wo + pc];
        int n = (b * HO_ + ho) * WO_ + wo;
        f16x8 v0, v1;
#pragma unroll
        for (int i2 = 0; i2 < 8; ++i2) { v0[i2] = h[i2]; v1[i2] = h[8 + i2]; }
        f16* dh = Xh + (size_t)n * PDIM + (cg * 16 + c) * 16;
        *(f16x8*)dh = v0; *(f16x8*)(dh + 8) = v1;
    }
}

// ------------- D -> Dt transpose via LDS tiles (coalesced both sides) -------
// Also emits the compact inner-2x2 dictionary Dq/Dql[atom][c][4] f16
// (elements {5,6,9,10} of each (atom, channel) block) for reconp.
__global__ __launch_bounds__(256) void dtrans_kernel(const float* __restrict__ D,
                                                     f16* __restrict__ Dth,
                                                     f16* __restrict__ Dtl,
                                                     f16* __restrict__ Dq,
                                                     f16* __restrict__ Dql) {
    __shared__ float ts[64][65];
    const int k0 = blockIdx.x * 64;
    const int n0 = blockIdx.y * 64;

    for (int i = threadIdx.x; i < 64 * 16; i += 256) {
        int r = i >> 4;
        int q = i & 15;
        float4 v = *(const float4*)(D + (size_t)(k0 + r) * NATOMS + n0 + q * 4);
        ts[r][q * 4 + 0] = v.x;
        ts[r][q * 4 + 1] = v.y;
        ts[r][q * 4 + 2] = v.z;
        ts[r][q * 4 + 3] = v.w;
    }
    __syncthreads();

    {
        int i = threadIdx.x;
        int nn = i >> 2, q = i & 3;
        f16 h[16], l[16];
#pragma unroll
        for (int j = 0; j < 16; ++j) {
            float v = ts[q * 16 + j][nn];
            f16 hh = (f16)v;
            h[j] = hh;
            l[j] = (f16)(v - (float)hh);
        }
        f16x8 h0, h1, l0, l1;
#pragma unroll
        for (int j = 0; j < 8; ++j) { h0[j] = h[j]; h1[j] = h[8 + j]; l0[j] = l[j]; l1[j] = l[8 + j]; }
        f16* dh = Dth + (size_t)(n0 + nn) * PDIM + k0 + q * 16;
        f16* dl = Dtl + (size_t)(n0 + nn) * PDIM + k0 + q * 16;
        *(f16x8*)dh = h0; *(f16x8*)(dh + 8) = h1;
        *(f16x8*)dl = l0; *(f16x8*)(dl + 8) = l1;

        // compact inner-2x2: channel c = k0/16 + q
        const int c = (k0 >> 4) + q;
        f16x4 qh = { h[5], h[6], h[9], h[10] };
        f16x4 qv = { l[5], l[6], l[9], l[10] };
        *(f16x4*)(Dq  + ((size_t)(n0 + nn) * CHN + c) * 4) = qh;
        *(f16x4*)(Dql + ((size_t)(n0 + nn) * CHN + c) * 4) = qv;
    }
}

// ------------- MFMA GEMM: corr[MPAD][512] (f16) = Xh . Dth^T ----------------
__global__ __launch_bounds__(512) void gemm_kernel(const f16* __restrict__ Xh,
                                                   const f16* __restrict__ Dth,
                                                   f16* __restrict__ corr) {
    __shared__ char lds[98304];
    const int tid  = threadIdx.x;
    const int lane = tid & 63;
    const int wave = tid >> 6;
    const size_t arow0 = (size_t)blockIdx.x * 128;
    const int    brow0 = blockIdx.y * 256;
    const int wm = wave >> 2;
    const int wn = wave & 3;

    f32x4 acc[4][4];
#pragma unroll
    for (int m = 0; m < 4; ++m)
#pragma unroll
        for (int n = 0; n < 4; ++n) acc[m][n] = (f32x4){0.f, 0.f, 0.f, 0.f};

    const char* asrc[2]; int adst[2];
#pragma unroll
    for (int i = 0; i < 2; ++i) {
        int p = tid * 16 + i * 8192;
        int row = p >> 7, sc = ((p >> 4) & 7) ^ (row & 7);
        asrc[i] = (const char*)Xh + (arow0 + row) * 2048 + sc * 16;
        adst[i] = p;
    }
    const char* bsrc[4]; int bdst[4];
#pragma unroll
    for (int i = 0; i < 4; ++i) {
        int p = tid * 16 + i * 8192;
        int row = p >> 7, sc = ((p >> 4) & 7) ^ (row & 7);
        bsrc[i] = (const char*)Dth + (size_t)(brow0 + row) * 2048 + sc * 16;
        bdst[i] = 16384 + p;
    }

    int aoff[4][2], boff[4][2];
#pragma unroll
    for (int m = 0; m < 4; ++m)
#pragma unroll
        for (int ks = 0; ks < 2; ++ks) {
            int row = wm * 64 + m * 16 + (lane & 15);
            int ch  = (ks * 4 + (lane >> 4)) ^ (row & 7);
            aoff[m][ks] = row * 128 + ch * 16;
        }
#pragma unroll
    for (int n = 0; n < 4; ++n)
#pragma unroll
        for (int ks = 0; ks < 2; ++ks) {
            int row = wn * 64 + n * 16 + (lane & 15);
            int ch  = (ks * 4 + (lane >> 4)) ^ (row & 7);
            boff[n][ks] = 16384 + row * 128 + ch * 16;
        }

#pragma unroll
    for (int i = 0; i < 2; ++i) gload_lds16(asrc[i], lds + adst[i]);
#pragma unroll
    for (int i = 0; i < 4; ++i) gload_lds16(bsrc[i], lds + bdst[i]);
#pragma unroll
    for (int i = 0; i < 2; ++i) asrc[i] += 128;
#pragma unroll
    for (int i = 0; i < 4; ++i) bsrc[i] += 128;
    __syncthreads();

    int bufo = 0;
    for (int kt = 0; kt < 16; ++kt) {
        const int nbuf = bufo ^ 49152;
        if (kt + 1 < 16) {
#pragma unroll
            for (int i = 0; i < 2; ++i) { gload_lds16(asrc[i], lds + nbuf + adst[i]); asrc[i] += 128; }
#pragma unroll
            for (int i = 0; i < 4; ++i) { gload_lds16(bsrc[i], lds + nbuf + bdst[i]); bsrc[i] += 128; }
        }
#pragma unroll
        for (int ks = 0; ks < 2; ++ks) {
            f16x8 a[4], b[4];
#pragma unroll
            for (int m = 0; m < 4; ++m) a[m] = *(const f16x8*)(lds + bufo + aoff[m][ks]);
#pragma unroll
            for (int n = 0; n < 4; ++n) b[n] = *(const f16x8*)(lds + bufo + boff[n][ks]);
#pragma unroll
            for (int m = 0; m < 4; ++m)
#pragma unroll
                for (int n = 0; n < 4; ++n)
                    acc[m][n] = __builtin_amdgcn_mfma_f32_16x16x32_f16(a[m], b[n], acc[m][n], 0, 0, 0);
        }
        if (kt + 1 < 16) { __syncthreads(); bufo = nbuf; }
    }

#pragma unroll
    for (int m = 0; m < 4; ++m) {
        size_t row_b = arow0 + wm * 64 + m * 16 + (lane >> 4) * 4;
#pragma unroll
        for (int n = 0; n < 4; ++n) {
            int col = brow0 + wn * 64 + n * 16 + (lane & 15);
#pragma unroll
            for (int i = 0; i < 4; ++i)
                corr[(row_b + i) * NATOMS + col] = (f16)acc[m][n][i];
        }
    }
}

// ------- phase 1: sorted top-8 keys + values (f16 corr, cache-hot) ----------
__global__ __launch_bounds__(512) void topred_kernel(const f16* __restrict__ corr,
                                                     unsigned* __restrict__ topk) {
    const int tid = threadIdx.x;
    const int sl  = tid & 31;
    const int hw  = tid >> 5;                 // half-wave 0..15
    const int np  = blockIdx.x * 16 + hw;     // may run into pad rows (< MPAD)

    const f16* row = corr + (size_t)np * NATOMS;
    const f16* cr = row + sl * 16;
    f16x8 c0 = *(const f16x8*)cr;
    f16x8 c1 = *(const f16x8*)(cr + 8);
    unsigned k[16];
#pragma unroll
    for (int j = 0; j < 8; ++j) {
        k[j]     = mk_key32((float)c0[j], sl * 16 + j);
        k[8 + j] = mk_key32((float)c1[j], sl * 16 + 8 + j);
    }

    unsigned a[8], b8[8];
#pragma unroll
    for (int i = 0; i < 8; ++i) { a[i] = k[i]; b8[i] = k[8 + i]; }
    SORT8(a)
    SORT8(b8)
    unsigned s[8];
    MERGE8(s, a, b8)
#pragma unroll
    for (int off = 16; off; off >>= 1) {
        unsigned p[8];
#pragma unroll
        for (int i = 0; i < 8; ++i) p[i] = (unsigned)__shfl_xor((int)s[i], off);
        MERGE8(s, s, p)
    }

    if (sl == 0 && np < NPATCH) {
        float v0 = (float)row[key32_idx(s[0])], v1 = (float)row[key32_idx(s[1])];
        float v2 = (float)row[key32_idx(s[2])], v3 = (float)row[key32_idx(s[3])];
        float v4 = (float)row[key32_idx(s[4])], v5 = (float)row[key32_idx(s[5])];
        float v6 = (float)row[key32_idx(s[6])], v7 = (float)row[key32_idx(s[7])];
        uint4* dst = (uint4*)(topk + (size_t)np * 16);
        dst[0] = make_uint4(s[0], s[1], s[2], s[3]);
        dst[1] = make_uint4(s[4], s[5], s[6], s[7]);
        dst[2] = make_uint4(__float_as_uint(v0), __float_as_uint(v1),
                            __float_as_uint(v2), __float_as_uint(v3));
        dst[3] = make_uint4(__float_as_uint(v4), __float_as_uint(v5),
                            __float_as_uint(v6), __float_as_uint(v7));
    }
}

// ------- phase 2: 64-thr blocks; parallel gram gather; unrolled arbitration -
__global__ __launch_bounds__(64) void topfin_kernel(const unsigned* __restrict__ topk,
                                                    const f16* __restrict__ corr,
                                                    const float* __restrict__ x,
                                                    const float* __restrict__ D,
                                                    const float* __restrict__ gram,
                                                    int* __restrict__ sup_out,
                                                    float* __restrict__ val_out) {
    const int lane = threadIdx.x & 63;
    const int half = lane >> 5;
    const int sl   = lane & 31;
    const int hw   = threadIdx.x >> 5;        // 0..1
    const int np   = blockIdx.x * 2 + hw;     // grid*2 == NPATCH exactly

    unsigned s[8];
    float    tval[8];
    {
        const uint4* src = (const uint4*)(topk + (size_t)np * 16);
        uint4 s0 = src[0], s1 = src[1], v0 = src[2], v1 = src[3];
        s[0] = s0.x; s[1] = s0.y; s[2] = s0.z; s[3] = s0.w;
        s[4] = s1.x; s[5] = s1.y; s[6] = s1.z; s[7] = s1.w;
        tval[0] = __uint_as_float(v0.x); tval[1] = __uint_as_float(v0.y);
        tval[2] = __uint_as_float(v0.z); tval[3] = __uint_as_float(v0.w);
        tval[4] = __uint_as_float(v1.x); tval[5] = __uint_as_float(v1.y);
        tval[6] = __uint_as_float(v1.z); tval[7] = __uint_as_float(v1.w);
    }
    int tidx[8];
#pragma unroll
    for (int r = 0; r < 8; ++r) tidx[r] = key32_idx(s[r]);

    const float a5 = fabsf(tval[KSP - 1]);
    const float lo = fmaxf(a5 - DELTA, 0.0f);
    const float hi = a5 + DELTA;
    const unsigned lokey = (__float_as_uint(fmaxf(lo - QGUARD, 0.0f)) >> 11) << 11;

    int   nfinal = 0, fidx[KSP];
    float fval[KSP];
    int   nwin = 0, widx[8];
    float wvf[8];
#pragma unroll
    for (int r = 0; r < KSP; ++r) {
        if (fabsf(tval[r]) > hi) { fidx[nfinal] = tidx[r]; fval[nfinal] = tval[r]; ++nfinal; }
        else                     { widx[nwin] = tidx[r]; wvf[nwin] = tval[r]; ++nwin; }
    }
#pragma unroll
    for (int r = KSP; r < 8; ++r) {
        if (fabsf(tval[r]) >= lo && nwin < 8) { widx[nwin] = tidx[r]; wvf[nwin] = tval[r]; ++nwin; }
    }

    // rescan for extras beyond top-8 (only when the 8th key is inside window)
    if (s[7] >= lokey) {
        const f16* cr = corr + (size_t)np * NATOMS + sl * 16;
        f16x8 c0 = *(const f16x8*)cr;
        f16x8 c1 = *(const f16x8*)(cr + 8);
        unsigned k[16];
        float vbuf[16];
#pragma unroll
        for (int j = 0; j < 8; ++j) {
            vbuf[j]     = (float)c0[j];
            vbuf[8 + j] = (float)c1[j];
            k[j]        = mk_key32(vbuf[j], sl * 16 + j);
            k[8 + j]    = mk_key32(vbuf[8 + j], sl * 16 + 8 + j);
        }
#pragma unroll
        for (int i = 0; i < 16; ++i) {
            bool ex = (k[i] < s[7]) && (k[i] >= lokey);
            unsigned m = (unsigned)(__ballot(ex) >> (half * 32));
            while (m && nwin < 8) {
                int l = __ffs(m) - 1; m &= m - 1;
                unsigned kk = (unsigned)__shfl((int)k[i], l + half * 32);
                float vv2 = __shfl(vbuf[i], l + half * 32);
                if (fabsf(vv2) >= lo) { widx[nwin] = key32_idx(kk); wvf[nwin] = vv2; ++nwin; }
            }
        }
    }

    const int need = KSP - nfinal;
    if (nwin == need) {
        for (int w = 0; w < nwin; ++w) { fidx[nfinal] = widx[w]; fval[nfinal] = wvf[w]; ++nfinal; }
    } else {
        // fp64 arbitration of the boundary window (rare), 32-lane dot
        int bb_ = np / (HO_ * WO_);
        int rr  = np - bb_ * (HO_ * WO_);
        int ho2 = rr / WO_;
        int wo2 = rr - ho2 * WO_;
        const float* xb = x + (size_t)bb_ * CHN * HH * WW;
        double wv64[8];
        for (int w = 0; w < nwin; ++w) {
            int at = widx[w];
            double sd = 0.0;
#pragma unroll
            for (int t = 0; t < 32; ++t) {
                int kk = sl + (t << 5);
                int c  = kk >> 4, pr = (kk >> 2) & 3, pc = kk & 3;
                float xv = xb[((size_t)c * HH + (2 * ho2 + pr)) * WW + 2 * wo2 + pc];
                float dv = D[(size_t)kk * NATOMS + at];
                sd = fma((double)xv, (double)dv, sd);
            }
            for (int off = 16; off; off >>= 1) sd += __shfl_xor(sd, off);
            wv64[w] = sd;
        }
        unsigned taken = 0u;
        for (int scnt = 0; scnt < need; ++scnt) {
            int best = -1; double bbv = -1.0;
            for (int w = 0; w < nwin; ++w) {
                if ((taken >> w) & 1u) continue;
                double aw = fabs(wv64[w]);
                if (aw > bbv || (aw == bbv && best >= 0 && widx[w] < widx[best])) { bbv = aw; best = w; }
            }
            taken |= 1u << best;
            fidx[nfinal] = widx[best];
            fval[nfinal] = (float)wv64[best];
            ++nfinal;
        }
    }

    // ---- 5x5 solve (fp32); gram gathered in PARALLEL across lanes ----
    float A[KSP][KSP], bb[KSP];
    {
        float gv = 0.f;
        if (sl < 25) {
            int gi = sl / 5, gj = sl - 5 * gi;
            gv = gram[(size_t)fidx[gi] * NATOMS + fidx[gj]];
        }
#pragma unroll
        for (int i = 0; i < KSP; ++i)
#pragma unroll
            for (int j = 0; j < KSP; ++j)
                A[i][j] = __shfl(gv, i * 5 + j + half * 32);
    }
#pragma unroll
    for (int i = 0; i < KSP; ++i) bb[i] = fval[i];
#pragma unroll
    for (int c = 0; c < KSP; ++c) {
        float inv = 1.0f / A[c][c];
#pragma unroll
        for (int r = 0; r < KSP; ++r) {
            if (r > c) {
                float f = A[r][c] * inv;
#pragma unroll
                for (int cc = 0; cc < KSP; ++cc)
                    if (cc > c) A[r][cc] -= f * A[c][cc];
                bb[r] -= f * bb[c];
            }
        }
    }
#pragma unroll
    for (int r = KSP - 1; r >= 0; --r) {
        float t = bb[r];
#pragma unroll
        for (int cc = 0; cc < KSP; ++cc)
            if (cc > r) t -= A[r][cc] * bb[cc];
        bb[r] = t / A[r][r];
    }
    if (sl == 0) {
#pragma unroll
        for (int i = 0; i < KSP; ++i) {
            sup_out[(size_t)np * KSP + i] = fidx[i];
            val_out[(size_t)np * KSP + i] = bb[i];
        }
    }
}

// ------- fused reconstruction: compact-dict gather + LDS transpose ----------
// Block = 16 consecutive patches. Lane = channel; per atom one f16x4 from
// Dq/Dql (exactly the inner-2x2 h/l values -> bit-identical z to the full
// gather). LDS staging + write phase identical to the 226.7us config.
__global__ __launch_bounds__(256) void reconp_kernel(const float* __restrict__ x,
                                                     const f16* __restrict__ Dq,
                                                     const f16* __restrict__ Dql,
                                                     const int* __restrict__ sup,
                                                     const float* __restrict__ val,
                                                     float* __restrict__ out,
                                                     double* __restrict__ rpart) {
    __shared__ f32x4 zbuf[16][65];
    __shared__ double red[4];
    const int lane = threadIdx.x & 63;
    const int wave = threadIdx.x >> 6;
    const int n0   = blockIdx.x * 16;

#pragma unroll
    for (int it = 0; it < 4; ++it) {
        const int nl = it * 4 + wave;
        const int n  = n0 + nl;
        if (n < NPATCH) {
            const int*   sp = sup + (size_t)n * KSP;
            const float* vp = val + (size_t)n * KSP;
            float z0 = 0.f, z1 = 0.f, z2 = 0.f, z3 = 0.f;
#pragma unroll
            for (int t = 0; t < KSP; ++t) {
                int a = sp[t]; float v = vp[t];
                f16x4 qh = *(const f16x4*)(Dq  + ((size_t)a * CHN + lane) * 4);
                f16x4 ql = *(const f16x4*)(Dql + ((size_t)a * CHN + lane) * 4);
                z0 = fmaf(v, (float)qh[0] + (float)ql[0], z0);
                z1 = fmaf(v, (float)qh[1] + (float)ql[1], z1);
                z2 = fmaf(v, (float)qh[2] + (float)ql[2], z2);
                z3 = fmaf(v, (float)qh[3] + (float)ql[3], z3);
            }
            zbuf[nl][lane] = (f32x4){ z0, z1, z2, z3 };
        }
    }
    __syncthreads();

    double sq = 0.0;
#pragma unroll
    for (int k = 0; k < 4; ++k) {
        int f  = threadIdx.x + 256 * k;       // 0..1023, nl minor -> coalesced
        int c  = f >> 4;
        int nl = f & 15;
        int n  = n0 + nl;
        if (n < NPATCH) {
            int b  = n / (HO_ * WO_);
            int r  = n - b * (HO_ * WO_);
            int ho = r / WO_, wo = r - ho * WO_;
            f32x4 zv = zbuf[nl][c];
            size_t base = ((size_t)(b * CHN + c) * HH + (2 * ho + 1)) * WW + (2 * wo + 1);
            float x0 = x[base],      x1 = x[base + 1];
            float x2 = x[base + WW], x3 = x[base + WW + 1];
            out[base]          = x0 + (zv.x - x0);
            out[base + 1]      = x1 + (zv.y - x1);
            out[base + WW]     = x2 + (zv.z - x2);
            out[base + WW + 1] = x3 + (zv.w - x3);
            float d0 = zv.x - x0, d1 = zv.y - x1, d2 = zv.z - x2, d3 = zv.w - x3;
            sq += (double)d0 * d0 + (double)d1 * d1 + (double)d2 * d2 + (double)d3 * d3;
        }
    }

    for (int off = 32; off; off >>= 1) sq += __shfl_xor(sq, off);
    if (lane == 0) red[wave] = sq;
    __syncthreads();
    if (threadIdx.x == 0) rpart[blockIdx.x] = red[0] + red[1] + red[2] + red[3];
}

// ------- border pixels: z_q = 0 -> out = x + (0 - x), loss += x^2 -----------
__global__ __launch_bounds__(256) void border_kernel(const float* __restrict__ x,
                                                     float* __restrict__ out,
                                                     double* __restrict__ bpart) {
    const int plane = blockIdx.x;             // b*CHN + c, 0..511
    const float* xp = x + (size_t)plane * HH * WW;
    float* op = out + (size_t)plane * HH * WW;
    double sq = 0.0;
    for (int idx = threadIdx.x; idx < 508; idx += 256) {
        int i, j;
        if (idx < 128)      { i = 0;         j = idx;       }
        else if (idx < 256) { i = 127;       j = idx - 128; }
        else if (idx < 382) { i = idx - 255; j = 0;         }   // i = 1..126
        else                { i = idx - 381; j = 127;       }   // i = 1..126
        float xv = xp[i * WW + j];
        op[i * WW + j] = xv + (0.0f - xv);
        sq += (double)xv * xv;
    }
    for (int off = 32; off; off >>= 1) sq += __shfl_xor(sq, off);
    __shared__ double red[4];
    const int lane = threadIdx.x & 63, wv = threadIdx.x >> 6;
    if (lane == 0) red[wv] = sq;
    __syncthreads();
    if (threadIdx.x == 0) bpart[blockIdx.x] = red[0] + red[1] + red[2] + red[3];
}

// ------- loss finalize: sum reconp + border partials ------------------------
__global__ __launch_bounds__(256) void loss2_kernel(const double* __restrict__ rpart,
                                                    const double* __restrict__ bpart,
                                                    float* __restrict__ out) {
    double s = 0.0;
    for (int i = threadIdx.x; i < RPB; i += 256) s += rpart[i];
    for (int i = threadIdx.x; i < 512; i += 256) s += bpart[i];
    for (int off = 32; off; off >>= 1) s += __shfl_xor(s, off);
    __shared__ double red[4];
    const int lane = threadIdx.x & 63, wv = threadIdx.x >> 6;
    if (lane == 0) red[wv] = s;
    __syncthreads();
    if (threadIdx.x == 0) {
        double m = (red[0] + red[1] + red[2] + red[3]) / (double)OUT_N;
        out[OUT_N] = (float)(m + 0.25 * m);
    }
}

// ======================= FALLBACK PATH (small ws) ===========================
__global__ __launch_bounds__(256) void corr_kernel_fb(const float* __restrict__ x,
                                                      const float* __restrict__ D,
                                                      const float* __restrict__ gram,
                                                      int* __restrict__ sup_out,
                                                      float* __restrict__ val_out) {
    __shared__ float pt[256 * MT];
    __shared__ float corrbuf[MT][NATOMS];
    __shared__ int   sup_s[MT][KSP];
    __shared__ float rhs_s[MT][KSP];

    const int tid  = threadIdx.x;
    const int lane = tid & 63;
    const int wave = tid >> 6;
    const int n0   = blockIdx.x * MT;
    const int sp  = lane & 15;
    const int spr = lane >> 4;

    int n = n0 + sp;
    bool pvalid = (n < NPATCH);
    int b = 0, ho = 0, wo = 0;
    if (pvalid) {
        b = n / (HO_ * WO_);
        int r = n - b * (HO_ * WO_);
        ho = r / WO_;
        wo = r - ho * WO_;
    }

    f32x2 accP[2][8];
#pragma unroll
    for (int a = 0; a < 2; ++a)
#pragma unroll
        for (int g = 0; g < 8; ++g) accP[a][g] = (f32x2)(0.f);

    for (int chunk = 0; chunk < 4; ++chunk) {
        __syncthreads();
#pragma unroll
        for (int t = 0; t < 4; ++t) {
            int s = wave + 4 * t;
            int c = chunk * 16 + s;
            float2 va = make_float2(0.f, 0.f), vb = make_float2(0.f, 0.f);
            if (pvalid) {
                const float* px = x + (((size_t)b * CHN + c) * HH + (2 * ho + spr)) * WW + 2 * wo;
                va = *(const float2*)px;
                vb = *(const float2*)(px + 2);
            }
            int kl = (s * 16 + spr * 4) * MT + sp;
            pt[kl]          = va.x;
            pt[kl + MT]     = va.y;
            pt[kl + 2 * MT] = vb.x;
            pt[kl + 3 * MT] = vb.y;
        }
        __syncthreads();
        const float* Dp = D + (size_t)chunk * 256 * NATOMS + 2 * tid;
#pragma unroll 4
        for (int k = 0; k < 256; ++k) {
            float2 dv = *(const float2*)(Dp + (size_t)k * NATOMS);
            f32x2 d00 = {dv.x, dv.x}, d11 = {dv.y, dv.y};
#pragma unroll
            for (int q = 0; q < 4; ++q) {
                const float4 f = *(const float4*)&pt[k * MT + 4 * q];
                f32x2 flo = {f.x, f.y}, fhi = {f.z, f.w};
                accP[0][2 * q]     = fma2(flo, d00, accP[0][2 * q]);
                accP[1][2 * q]     = fma2(flo, d11, accP[1][2 * q]);
                accP[0][2 * q + 1] = fma2(fhi, d00, accP[0][2 * q + 1]);
                accP[1][2 * q + 1] = fma2(fhi, d11, accP[1][2 * q + 1]);
            }
        }
    }
#pragma unroll
    for (int g = 0; g < 8; ++g) {
        *(float2*)&corrbuf[2 * g][2 * tid]     = make_float2(accP[0][g].x, accP[1][g].x);
        *(float2*)&corrbuf[2 * g + 1][2 * tid] = make_float2(accP[0][g].y, accP[1][g].y);
    }
    __syncthreads();

    for (int pi = 0; pi < 4; ++pi) {
        int p  = wave * 4 + pi;
        int np = n0 + p;
        if (np >= NPATCH) continue;
        float v[8], av[8];
#pragma unroll
        for (int i = 0; i < 8; ++i) {
            v[i]  = corrbuf[p][lane + 64 * i];
            av[i] = fabsf(v[i]);
        }
        unsigned usedm = 0u;
        int   top_i[KSP];
        float top_v[KSP];
#pragma unroll
        for (int r = 0; r < KSP; ++r) {
            float ba = -1.0f, bv = 0.0f;
            int   bi = 0x7FFFFFFF;
#pragma unroll
            for (int i = 0; i < 8; ++i) {
                if (!((usedm >> i) & 1u)) {
                    int idx = lane + 64 * i;
                    if (av[i] > ba || (av[i] == ba && idx < bi)) { ba = av[i]; bi = idx; bv = v[i]; }
                }
            }
            for (int off = 32; off; off >>= 1) {
                float oa = __shfl_xor(ba, off);
                int   oi = __shfl_xor(bi, off);
                float ov = __shfl_xor(bv, off);
                if (oa > ba || (oa == ba && oi < bi)) { ba = oa; bi = oi; bv = ov; }
            }
            top_i[r] = bi; top_v[r] = bv;
            if (lane == (bi & 63)) usedm |= (1u << (bi >> 6));
        }
        const float a5 = fabsf(top_v[KSP - 1]);
        const float lo = a5 - DELTA, hi = a5 + DELTA;
        int   nfinal = 0, fidx[KSP];
        float fval[KSP];
        int   nwin = 0, widx[8];
        float wvf[8];
#pragma unroll
        for (int r = 0; r < KSP; ++r) {
            if (fabsf(top_v[r]) > hi) { fidx[nfinal] = top_i[r]; fval[nfinal] = top_v[r]; ++nfinal; }
            else if (nwin < 8)        { widx[nwin] = top_i[r]; wvf[nwin] = top_v[r]; ++nwin; }
        }
#pragma unroll
        for (int i = 0; i < 8; ++i) {
            bool ex = (((usedm >> i) & 1u) == 0u) && (av[i] >= lo);
            unsigned long long m = __ballot(ex);
            while (m && nwin < 8) {
                int l = __ffsll(m) - 1; m &= m - 1;
                widx[nwin] = l + 64 * i;
                wvf[nwin]  = __shfl(v[i], l);
                ++nwin;
            }
        }
        const int need = KSP - nfinal;
        if (nwin == need) {
            for (int w = 0; w < nwin; ++w) { fidx[nfinal] = widx[w]; fval[nfinal] = wvf[w]; ++nfinal; }
        } else {
            int bb_ = np / (HO_ * WO_);
            int rr  = np - bb_ * (HO_ * WO_);
            int ho2 = rr / WO_;
            int wo2 = rr - ho2 * WO_;
            const float* xb = x + (size_t)bb_ * CHN * HH * WW;
            double wv64[8];
            for (int w = 0; w < nwin; ++w) {
                int a = widx[w];
                double s = 0.0;
                for (int t = 0; t < 16; ++t) {
                    int k  = lane + (t << 6);
                    int c  = k >> 4, pr = (k >> 2) & 3, pc = k & 3;
                    float xv = xb[((size_t)c * HH + (2 * ho2 + pr)) * WW + 2 * wo2 + pc];
                    float dv = D[(size_t)k * NATOMS + a];
                    s = fma((double)xv, (double)dv, s);
                }
                for (int off = 32; off; off >>= 1) s += __shfl_xor(s, off);
                wv64[w] = s;
            }
            unsigned taken = 0u;
            for (int scnt = 0; scnt < need; ++scnt) {
                int best = -1; double bbv = -1.0;
                for (int w = 0; w < nwin; ++w) {
                    if ((taken >> w) & 1u) continue;
                    double aw = fabs(wv64[w]);
                    if (aw > bbv || (aw == bbv && best >= 0 && widx[w] < widx[best])) { bbv = aw; best = w; }
                }
                taken |= 1u << best;
                fidx[nfinal] = widx[best];
                fval[nfinal] = (float)wv64[best];
                ++nfinal;
            }
        }
        if (lane == 0) {
#pragma unroll
            for (int r = 0; r < KSP; ++r) { sup_s[p][r] = fidx[r]; rhs_s[p][r] = fval[r]; }
        }
    }
    __syncthreads();

    if (tid < MT) {
        int p = tid, np = n0 + p;
        if (np < NPATCH) {
            int s[KSP];
            double A[KSP][KSP], bb[KSP];
#pragma unroll
            for (int i = 0; i < KSP; ++i) { s[i] = sup_s[p][i]; bb[i] = (double)rhs_s[p][i]; }
#pragma unroll
            for (int i = 0; i < KSP; ++i)
#pragma unroll
                for (int j = 0; j < KSP; ++j)
                    A[i][j] = (double)gram[(size_t)s[i] * NATOMS + s[j]] + (i == j ? 1e-10 : 0.0);
#pragma unroll
            for (int c = 0; c < KSP; ++c) {
                double inv = 1.0 / A[c][c];
#pragma unroll
                for (int r = 0; r < KSP; ++r) {
                    if (r > c) {
                        double f = A[r][c] * inv;
#pragma unroll
                        for (int cc = 0; cc < KSP; ++cc)
                            if (cc > c) A[r][cc] -= f * A[c][cc];
                        bb[r] -= f * bb[c];
                    }
                }
            }
#pragma unroll
            for (int r = KSP - 1; r >= 0; --r) {
                double t = bb[r];
#pragma unroll
                for (int cc = 0; cc < KSP; ++cc)
                    if (cc > r) t -= A[r][cc] * bb[cc];
                bb[r] = t / A[r][r];
            }
#pragma unroll
            for (int i = 0; i < KSP; ++i) {
                sup_out[(size_t)np * KSP + i] = s[i];
                val_out[(size_t)np * KSP + i] = (float)bb[i];
            }
        }
    }
}

__global__ __launch_bounds__(256) void recon_kernel_fb(const float* __restrict__ x,
                                                       const float* __restrict__ D,
                                                       const int* __restrict__ sup,
                                                       const float* __restrict__ val,
                                                       float* __restrict__ out,
                                                       double* __restrict__ partials) {
    double sqacc = 0.0;
    for (size_t o = (size_t)blockIdx.x * 256 + threadIdx.x; o < OUT_N; o += (size_t)FBLK * 256) {
        const int j = (int)(o & 127);
        const int i = (int)((o >> 7) & 127);
        const int c = (int)((o >> 14) & 63);
        const int b = (int)(o >> 20);
        const float xv = x[o];
        float z = 0.0f;
        const int pr = (i & 1) ? 1 : 2;
        const int pc = (j & 1) ? 1 : 2;
        const int ho = (i - pr) >> 1;
        const int wo = (j - pc) >> 1;
        if (ho >= 0 && ho < HO_ && wo >= 0 && wo < WO_) {
            const int n = (b * HO_ + ho) * WO_ + wo;
            const int k = c * 16 + pr * 4 + pc;
            const int*   sp5 = sup + (size_t)n * KSP;
            const float* vp5 = val + (size_t)n * KSP;
            float s = 0.0f;
#pragma unroll
            for (int t = 0; t < KSP; ++t)
                s = fmaf(vp5[t], D[(size_t)k * NATOMS + sp5[t]], s);
            z = s;
        }
        out[o] = xv + (z - xv);
        const float d = z - xv;
        sqacc += (double)d * (double)d;
    }
    for (int off = 32; off; off >>= 1) sqacc += __shfl_xor(sqacc, off);
    __shared__ double red[4];
    const int lane = threadIdx.x & 63, wv = threadIdx.x >> 6;
    if (lane == 0) red[wv] = sqacc;
    __syncthreads();
    if (threadIdx.x == 0) partials[blockIdx.x] = red[0] + red[1] + red[2] + red[3];
}

__global__ __launch_bounds__(256) void loss_kernel(const double* __restrict__ partials,
                                                   float* __restrict__ out) {
    double s = 0.0;
    for (int i = threadIdx.x; i < FBLK; i += 256) s += partials[i];
    for (int off = 32; off; off >>= 1) s += __shfl_xor(s, off);
    __shared__ double red[4];
    const int lane = threadIdx.x & 63, wv = threadIdx.x >> 6;
    if (lane == 0) red[wv] = s;
    __syncthreads();
    if (threadIdx.x == 0) {
        double m = (red[0] + red[1] + red[2] + red[3]) / (double)OUT_N;
        out[OUT_N] = (float)(m + 0.25 * m);
    }
}

// ---------------------------------------------------------------------------
extern "C" void kernel_launch(void* const* d_in, const int* in_sizes, int n_in,
                              void* d_out, int out_size, void* d_ws, size_t ws_size,
                              hipStream_t stream) {
    const float* x = (const float*)d_in[0];
    const float* D = (const float*)d_in[1];
    float* out = (float*)d_out;
    char* ws = (char*)d_ws;

    size_t off = 0;
    auto take = [&](size_t bytes) { char* p = ws + off; off += (bytes + 255) & ~(size_t)255; return p; };
    float*    gram     = (float*)take((size_t)NATOMS * NATOMS * 4);
    int*      sup      = (int*)take((size_t)NPATCH * KSP * 4);
    float*    val      = (float*)take((size_t)NPATCH * KSP * 4);
    double*   partials = (double*)take((size_t)FBLK * 8);
    double*   rpart    = (double*)take((size_t)RPB * 8);
    double*   bpart    = (double*)take((size_t)512 * 8);
    unsigned* topk     = (unsigned*)take((size_t)NPATCH * 16 * 4);
    f16*   Dth  = (f16*)take((size_t)NATOMS * PDIM * 2);
    f16*   Dtl  = (f16*)take((size_t)NATOMS * PDIM * 2);
    f16*   Dq   = (f16*)take((size_t)NATOMS * CHN * 4 * 2);
    f16*   Dql  = (f16*)take((size_t)NATOMS * CHN * 4 * 2);
    f16*   Xh   = (f16*)take((size_t)MPAD * PDIM * 2);
    f16*   corr = (f16*)take((size_t)MPAD * NATOMS * 2);
    const bool big = (off <= ws_size);

    if (big) {
        hipMemsetAsync(Xh + (size_t)NPATCH * PDIM, 0,
                       (size_t)(MPAD - NPATCH) * PDIM * sizeof(f16), stream);
        extract_kernel<<<8 * HO_ * 4, 256, 0, stream>>>(x, Xh);
        dtrans_kernel<<<dim3(16, 8), 256, 0, stream>>>(D, Dth, Dtl, Dq, Dql);
        gram_kernel<<<dim3(16, 16), 256, 0, stream>>>(D, gram);
        border_kernel<<<512, 256, 0, stream>>>(x, out, bpart);
        gemm_kernel<<<dim3(MPAD / 128, NATOMS / 256), 512, 0, stream>>>(Xh, Dth, corr);
        topred_kernel<<<(NPATCH + 15) / 16, 512, 0, stream>>>(corr, topk);
        topfin_kernel<<<NPATCH / 2, 64, 0, stream>>>(topk, corr, x, D, gram, sup, val);
        reconp_kernel<<<RPB, 256, 0, stream>>>(x, Dq, Dql, sup, val, out, rpart);
        loss2_kernel<<<1, 256, 0, stream>>>(rpart, bpart, out);
    } else {
        gram_kernel<<<dim3(16, 16), 256, 0, stream>>>(D, gram);
        corr_kernel_fb<<<(NPATCH + MT - 1) / MT, 256, 0, stream>>>(x, D, gram, sup, val);
        recon_kernel_fb<<<FBLK, 256, 0, stream>>>(x, D, sup, val, out, partials);
        loss_kernel<<<1, 256, 0, stream>>>(partials, out);
    }
}

// Round 26
// 195.989 us; speedup vs baseline: 1.2821x; 1.0290x over previous
//
#include <hip/hip_runtime.h>

#define CHN    64
#define NATOMS 512
#define PDIM   1024
#define KSP    5
#define HO_    63
#define WO_    63
#define NPATCH 31752
#define MPAD   31872          // 249 * 128
#define HH     128
#define WW     128
#define MT     16
#define OUT_N  8388608
#define DELTA  6e-3f
#define QGUARD 2.5e-3f
#define FBLK   2048
#define RPB    ((NPATCH + 15) / 16)   // 1985 reconp blocks

typedef _Float16 f16;
typedef _Float16 f16x8 __attribute__((ext_vector_type(8)));
typedef _Float16 f16x4 __attribute__((ext_vector_type(4)));
typedef float    f32x4 __attribute__((ext_vector_type(4)));
typedef float    f32x2 __attribute__((ext_vector_type(2)));

static __device__ __forceinline__ void gload_lds16(const void* g, void* l) {
    __builtin_amdgcn_global_load_lds(
        (const __attribute__((address_space(1))) unsigned int*)g,
        (__attribute__((address_space(3))) unsigned int*)l, 16, 0, 0);
}

static __device__ inline f32x2 fma2(f32x2 a, f32x2 b, f32x2 c) {
#if __has_builtin(__builtin_elementwise_fma)
    return __builtin_elementwise_fma(a, b, c);
#else
    f32x2 r; r.x = fmaf(a.x, b.x, c.x); r.y = fmaf(a.y, b.y, c.y); return r;
#endif
}

// ---- u32 key: (abs>>11)<<11 | (1023-idx)<<1 | sign ----
static __device__ __forceinline__ unsigned mk_key32(float v, int idx) {
    unsigned vb = __float_as_uint(v);
    unsigned ab = vb & 0x7FFFFFFFu;
    return ((ab >> 11) << 11) | ((unsigned)(1023 - idx) << 1) | (vb >> 31);
}
static __device__ __forceinline__ int key32_idx(unsigned k) {
    return 1023 - (int)((k >> 1) & 1023u);
}

#define CEU(s, i, j) { unsigned _a = s[i], _b = s[j]; \
                       s[i] = _a > _b ? _a : _b; s[j] = _a > _b ? _b : _a; }

#define SORT8(s) \
    CEU(s,0,1) CEU(s,2,3) CEU(s,4,5) CEU(s,6,7) \
    CEU(s,0,2) CEU(s,1,3) CEU(s,4,6) CEU(s,5,7) \
    CEU(s,1,2) CEU(s,5,6) \
    CEU(s,0,4) CEU(s,1,5) CEU(s,2,6) CEU(s,3,7) \
    CEU(s,2,4) CEU(s,3,5) \
    CEU(s,1,2) CEU(s,3,4) CEU(s,5,6)

#define MERGE8(s, a, b) { \
    unsigned L[8]; \
    L[0] = a[0] > b[7] ? a[0] : b[7]; L[1] = a[1] > b[6] ? a[1] : b[6]; \
    L[2] = a[2] > b[5] ? a[2] : b[5]; L[3] = a[3] > b[4] ? a[3] : b[4]; \
    L[4] = a[4] > b[3] ? a[4] : b[3]; L[5] = a[5] > b[2] ? a[5] : b[2]; \
    L[6] = a[6] > b[1] ? a[6] : b[1]; L[7] = a[7] > b[0] ? a[7] : b[0]; \
    CEU(L,0,4) CEU(L,1,5) CEU(L,2,6) CEU(L,3,7) \
    CEU(L,0,2) CEU(L,1,3) CEU(L,4,6) CEU(L,5,7) \
    CEU(L,0,1) CEU(L,2,3) CEU(L,4,5) CEU(L,6,7) \
    for (int _i = 0; _i < 8; ++_i) s[_i] = L[_i]; }

// ---------------- gram = D^T D, 32x32 tiles, fp32 accumulate ----------------
__global__ __launch_bounds__(256) void gram_kernel(const float* __restrict__ D,
                                                   float* __restrict__ gram) {
    __shared__ float Ti[64][32];
    __shared__ float Tj[64][32];
    const int tid = threadIdx.x;
    const int i0 = blockIdx.x * 32, j0 = blockIdx.y * 32;
    const int ri  = tid >> 3;
    const int rj0 = (tid & 7) * 4;
    float acc[4] = {0.f, 0.f, 0.f, 0.f};
    for (int k0 = 0; k0 < PDIM; k0 += 64) {
        __syncthreads();
#pragma unroll
        for (int s = 0; s < 8; ++s) {
            int e = tid + 256 * s;
            int kk = e >> 5, col = e & 31;
            Ti[kk][col] = D[(size_t)(k0 + kk) * NATOMS + i0 + col];
            Tj[kk][col] = D[(size_t)(k0 + kk) * NATOMS + j0 + col];
        }
        __syncthreads();
#pragma unroll 4
        for (int kk = 0; kk < 64; ++kk) {
            float ti = Ti[kk][ri];
#pragma unroll
            for (int q = 0; q < 4; ++q)
                acc[q] = fmaf(ti, Tj[kk][rj0 + q], acc[q]);
        }
    }
#pragma unroll
    for (int q = 0; q < 4; ++q)
        gram[(size_t)(i0 + ri) * NATOMS + j0 + rj0 + q] = acc[q];
}

// ------------- patch extraction (coalesced): x -> Xh [MPAD][1024] f16 -------
__global__ __launch_bounds__(256) void extract_kernel(const float* __restrict__ x,
                                                      f16* __restrict__ Xh) {
    __shared__ float xs[16][4][129];
    const int bid = blockIdx.x;
    const int cg  = bid & 3;
    const int t   = bid >> 2;
    const int ho  = t % HO_;
    const int b   = t / HO_;

    for (int i = threadIdx.x; i < 64 * 32; i += 256) {
        int r = i >> 5;
        int q = i & 31;
        int c = r >> 2, pr = r & 3;
        float4 v = *(const float4*)(x + ((size_t)(b * CHN + cg * 16 + c) * HH
                                         + (2 * ho + pr)) * WW + q * 4);
        xs[c][pr][q * 4 + 0] = v.x;
        xs[c][pr][q * 4 + 1] = v.y;
        xs[c][pr][q * 4 + 2] = v.z;
        xs[c][pr][q * 4 + 3] = v.w;
    }
    __syncthreads();

    for (int p = threadIdx.x; p < WO_ * 16; p += 256) {
        int wo = p >> 4;
        int c  = p & 15;
        f16 h[16];
#pragma unroll
        for (int pr = 0; pr < 4; ++pr)
#pragma unroll
            for (int pc = 0; pc < 4; ++pc)
                h[pr * 4 + pc] = (f16)xs[c][pr][2 * wo + pc];
        int n = (b * HO_ + ho) * WO_ + wo;
        f16x8 v0, v1;
#pragma unroll
        for (int i2 = 0; i2 < 8; ++i2) { v0[i2] = h[i2]; v1[i2] = h[8 + i2]; }
        f16* dh = Xh + (size_t)n * PDIM + (cg * 16 + c) * 16;
        *(f16x8*)dh = v0; *(f16x8*)(dh + 8) = v1;
    }
}

// ------------- D -> Dt transpose via LDS tiles (coalesced both sides) -------
// Also emits the compact interleaved inner-2x2 dictionary Dqi[atom][c][8] f16
// = {h5,h6,h9,h10, l5,l6,l9,l10} for reconp (one 16B load per atom).
__global__ __launch_bounds__(256) void dtrans_kernel(const float* __restrict__ D,
                                                     f16* __restrict__ Dth,
                                                     f16* __restrict__ Dtl,
                                                     f16* __restrict__ Dqi) {
    __shared__ float ts[64][65];
    const int k0 = blockIdx.x * 64;
    const int n0 = blockIdx.y * 64;

    for (int i = threadIdx.x; i < 64 * 16; i += 256) {
        int r = i >> 4;
        int q = i & 15;
        float4 v = *(const float4*)(D + (size_t)(k0 + r) * NATOMS + n0 + q * 4);
        ts[r][q * 4 + 0] = v.x;
        ts[r][q * 4 + 1] = v.y;
        ts[r][q * 4 + 2] = v.z;
        ts[r][q * 4 + 3] = v.w;
    }
    __syncthreads();

    {
        int i = threadIdx.x;
        int nn = i >> 2, q = i & 3;
        f16 h[16], l[16];
#pragma unroll
        for (int j = 0; j < 16; ++j) {
            float v = ts[q * 16 + j][nn];
            f16 hh = (f16)v;
            h[j] = hh;
            l[j] = (f16)(v - (float)hh);
        }
        f16x8 h0, h1, l0, l1;
#pragma unroll
        for (int j = 0; j < 8; ++j) { h0[j] = h[j]; h1[j] = h[8 + j]; l0[j] = l[j]; l1[j] = l[8 + j]; }
        f16* dh = Dth + (size_t)(n0 + nn) * PDIM + k0 + q * 16;
        f16* dl = Dtl + (size_t)(n0 + nn) * PDIM + k0 + q * 16;
        *(f16x8*)dh = h0; *(f16x8*)(dh + 8) = h1;
        *(f16x8*)dl = l0; *(f16x8*)(dl + 8) = l1;

        // compact interleaved inner-2x2: channel c = k0/16 + q
        const int c = (k0 >> 4) + q;
        f16x8 qi = { h[5], h[6], h[9], h[10], l[5], l[6], l[9], l[10] };
        *(f16x8*)(Dqi + ((size_t)(n0 + nn) * CHN + c) * 8) = qi;
    }
}

// ------------- MFMA GEMM: corr[MPAD][512] (f16) = Xh . Dth^T ----------------
// 1D grid, XCD-paired mapping: the two 256-col blocks sharing the same 128
// A-rows are bids (b, b+8) -> same XCD under %8 round-robin -> 2nd A read
// hits that XCD's L2 instead of HBM.
__global__ __launch_bounds__(512) void gemm_kernel(const f16* __restrict__ Xh,
                                                   const f16* __restrict__ Dth,
                                                   f16* __restrict__ corr) {
    __shared__ char lds[98304];
    const int bid = blockIdx.x;
    const int xcd = bid & 7;
    const int jj  = bid >> 3;
    const int m   = (jj >> 1) * 8 + xcd;
    if (m >= MPAD / 128) return;
    const int tid  = threadIdx.x;
    const int lane = tid & 63;
    const int wave = tid >> 6;
    const size_t arow0 = (size_t)m * 128;
    const int    brow0 = (jj & 1) * 256;
    const int wm = wave >> 2;
    const int wn = wave & 3;

    f32x4 acc[4][4];
#pragma unroll
    for (int mm = 0; mm < 4; ++mm)
#pragma unroll
        for (int n = 0; n < 4; ++n) acc[mm][n] = (f32x4){0.f, 0.f, 0.f, 0.f};

    const char* asrc[2]; int adst[2];
#pragma unroll
    for (int i = 0; i < 2; ++i) {
        int p = tid * 16 + i * 8192;
        int row = p >> 7, sc = ((p >> 4) & 7) ^ (row & 7);
        asrc[i] = (const char*)Xh + (arow0 + row) * 2048 + sc * 16;
        adst[i] = p;
    }
    const char* bsrc[4]; int bdst[4];
#pragma unroll
    for (int i = 0; i < 4; ++i) {
        int p = tid * 16 + i * 8192;
        int row = p >> 7, sc = ((p >> 4) & 7) ^ (row & 7);
        bsrc[i] = (const char*)Dth + (size_t)(brow0 + row) * 2048 + sc * 16;
        bdst[i] = 16384 + p;
    }

    int aoff[4][2], boff[4][2];
#pragma unroll
    for (int mm = 0; mm < 4; ++mm)
#pragma unroll
        for (int ks = 0; ks < 2; ++ks) {
            int row = wm * 64 + mm * 16 + (lane & 15);
            int ch  = (ks * 4 + (lane >> 4)) ^ (row & 7);
            aoff[mm][ks] = row * 128 + ch * 16;
        }
#pragma unroll
    for (int n = 0; n < 4; ++n)
#pragma unroll
        for (int ks = 0; ks < 2; ++ks) {
            int row = wn * 64 + n * 16 + (lane & 15);
            int ch  = (ks * 4 + (lane >> 4)) ^ (row & 7);
            boff[n][ks] = 16384 + row * 128 + ch * 16;
        }

#pragma unroll
    for (int i = 0; i < 2; ++i) gload_lds16(asrc[i], lds + adst[i]);
#pragma unroll
    for (int i = 0; i < 4; ++i) gload_lds16(bsrc[i], lds + bdst[i]);
#pragma unroll
    for (int i = 0; i < 2; ++i) asrc[i] += 128;
#pragma unroll
    for (int i = 0; i < 4; ++i) bsrc[i] += 128;
    __syncthreads();

    int bufo = 0;
    for (int kt = 0; kt < 16; ++kt) {
        const int nbuf = bufo ^ 49152;
        if (kt + 1 < 16) {
#pragma unroll
            for (int i = 0; i < 2; ++i) { gload_lds16(asrc[i], lds + nbuf + adst[i]); asrc[i] += 128; }
#pragma unroll
            for (int i = 0; i < 4; ++i) { gload_lds16(bsrc[i], lds + nbuf + bdst[i]); bsrc[i] += 128; }
        }
#pragma unroll
        for (int ks = 0; ks < 2; ++ks) {
            f16x8 a[4], b[4];
#pragma unroll
            for (int mm = 0; mm < 4; ++mm) a[mm] = *(const f16x8*)(lds + bufo + aoff[mm][ks]);
#pragma unroll
            for (int n = 0; n < 4; ++n) b[n] = *(const f16x8*)(lds + bufo + boff[n][ks]);
#pragma unroll
            for (int mm = 0; mm < 4; ++mm)
#pragma unroll
                for (int n = 0; n < 4; ++n)
                    acc[mm][n] = __builtin_amdgcn_mfma_f32_16x16x32_f16(a[mm], b[n], acc[mm][n], 0, 0, 0);
        }
        if (kt + 1 < 16) { __syncthreads(); bufo = nbuf; }
    }

#pragma unroll
    for (int mm = 0; mm < 4; ++mm) {
        size_t row_b = arow0 + wm * 64 + mm * 16 + (lane >> 4) * 4;
#pragma unroll
        for (int n = 0; n < 4; ++n) {
            int col = brow0 + wn * 64 + n * 16 + (lane & 15);
#pragma unroll
            for (int i = 0; i < 4; ++i)
                corr[(row_b + i) * NATOMS + col] = (f16)acc[mm][n][i];
        }
    }
}

// ------- phase 1: sorted top-8 keys + values (f16 corr, cache-hot) ----------
__global__ __launch_bounds__(512) void topred_kernel(const f16* __restrict__ corr,
                                                     unsigned* __restrict__ topk) {
    const int tid = threadIdx.x;
    const int sl  = tid & 31;
    const int hw  = tid >> 5;                 // half-wave 0..15
    const int np  = blockIdx.x * 16 + hw;     // may run into pad rows (< MPAD)

    const f16* row = corr + (size_t)np * NATOMS;
    const f16* cr = row + sl * 16;
    f16x8 c0 = *(const f16x8*)cr;
    f16x8 c1 = *(const f16x8*)(cr + 8);
    unsigned k[16];
#pragma unroll
    for (int j = 0; j < 8; ++j) {
        k[j]     = mk_key32((float)c0[j], sl * 16 + j);
        k[8 + j] = mk_key32((float)c1[j], sl * 16 + 8 + j);
    }

    unsigned a[8], b8[8];
#pragma unroll
    for (int i = 0; i < 8; ++i) { a[i] = k[i]; b8[i] = k[8 + i]; }
    SORT8(a)
    SORT8(b8)
    unsigned s[8];
    MERGE8(s, a, b8)
#pragma unroll
    for (int off = 16; off; off >>= 1) {
        unsigned p[8];
#pragma unroll
        for (int i = 0; i < 8; ++i) p[i] = (unsigned)__shfl_xor((int)s[i], off);
        MERGE8(s, s, p)
    }

    if (sl == 0 && np < NPATCH) {
        float v0 = (float)row[key32_idx(s[0])], v1 = (float)row[key32_idx(s[1])];
        float v2 = (float)row[key32_idx(s[2])], v3 = (float)row[key32_idx(s[3])];
        float v4 = (float)row[key32_idx(s[4])], v5 = (float)row[key32_idx(s[5])];
        float v6 = (float)row[key32_idx(s[6])], v7 = (float)row[key32_idx(s[7])];
        uint4* dst = (uint4*)(topk + (size_t)np * 16);
        dst[0] = make_uint4(s[0], s[1], s[2], s[3]);
        dst[1] = make_uint4(s[4], s[5], s[6], s[7]);
        dst[2] = make_uint4(__float_as_uint(v0), __float_as_uint(v1),
                            __float_as_uint(v2), __float_as_uint(v3));
        dst[3] = make_uint4(__float_as_uint(v4), __float_as_uint(v5),
                            __float_as_uint(v6), __float_as_uint(v7));
    }
}

// ------- phase 2: 64-thr blocks; parallel gram gather; unrolled arbitration -
__global__ __launch_bounds__(64) void topfin_kernel(const unsigned* __restrict__ topk,
                                                    const f16* __restrict__ corr,
                                                    const float* __restrict__ x,
                                                    const float* __restrict__ D,
                                                    const float* __restrict__ gram,
                                                    int* __restrict__ sup_out,
                                                    float* __restrict__ val_out) {
    const int lane = threadIdx.x & 63;
    const int half = lane >> 5;
    const int sl   = lane & 31;
    const int hw   = threadIdx.x >> 5;        // 0..1
    const int np   = blockIdx.x * 2 + hw;     // grid*2 == NPATCH exactly

    unsigned s[8];
    float    tval[8];
    {
        const uint4* src = (const uint4*)(topk + (size_t)np * 16);
        uint4 s0 = src[0], s1 = src[1], v0 = src[2], v1 = src[3];
        s[0] = s0.x; s[1] = s0.y; s[2] = s0.z; s[3] = s0.w;
        s[4] = s1.x; s[5] = s1.y; s[6] = s1.z; s[7] = s1.w;
        tval[0] = __uint_as_float(v0.x); tval[1] = __uint_as_float(v0.y);
        tval[2] = __uint_as_float(v0.z); tval[3] = __uint_as_float(v0.w);
        tval[4] = __uint_as_float(v1.x); tval[5] = __uint_as_float(v1.y);
        tval[6] = __uint_as_float(v1.z); tval[7] = __uint_as_float(v1.w);
    }
    int tidx[8];
#pragma unroll
    for (int r = 0; r < 8; ++r) tidx[r] = key32_idx(s[r]);

    const float a5 = fabsf(tval[KSP - 1]);
    const float lo = fmaxf(a5 - DELTA, 0.0f);
    const float hi = a5 + DELTA;
    const unsigned lokey = (__float_as_uint(fmaxf(lo - QGUARD, 0.0f)) >> 11) << 11;

    int   nfinal = 0, fidx[KSP];
    float fval[KSP];
    int   nwin = 0, widx[8];
    float wvf[8];
#pragma unroll
    for (int r = 0; r < KSP; ++r) {
        if (fabsf(tval[r]) > hi) { fidx[nfinal] = tidx[r]; fval[nfinal] = tval[r]; ++nfinal; }
        else                     { widx[nwin] = tidx[r]; wvf[nwin] = tval[r]; ++nwin; }
    }
#pragma unroll
    for (int r = KSP; r < 8; ++r) {
        if (fabsf(tval[r]) >= lo && nwin < 8) { widx[nwin] = tidx[r]; wvf[nwin] = tval[r]; ++nwin; }
    }

    // rescan for extras beyond top-8 (only when the 8th key is inside window)
    if (s[7] >= lokey) {
        const f16* cr = corr + (size_t)np * NATOMS + sl * 16;
        f16x8 c0 = *(const f16x8*)cr;
        f16x8 c1 = *(const f16x8*)(cr + 8);
        unsigned k[16];
        float vbuf[16];
#pragma unroll
        for (int j = 0; j < 8; ++j) {
            vbuf[j]     = (float)c0[j];
            vbuf[8 + j] = (float)c1[j];
            k[j]        = mk_key32(vbuf[j], sl * 16 + j);
            k[8 + j]    = mk_key32(vbuf[8 + j], sl * 16 + 8 + j);
        }
#pragma unroll
        for (int i = 0; i < 16; ++i) {
            bool ex = (k[i] < s[7]) && (k[i] >= lokey);
            unsigned m = (unsigned)(__ballot(ex) >> (half * 32));
            while (m && nwin < 8) {
                int l = __ffs(m) - 1; m &= m - 1;
                unsigned kk = (unsigned)__shfl((int)k[i], l + half * 32);
                float vv2 = __shfl(vbuf[i], l + half * 32);
                if (fabsf(vv2) >= lo) { widx[nwin] = key32_idx(kk); wvf[nwin] = vv2; ++nwin; }
            }
        }
    }

    const int need = KSP - nfinal;
    if (nwin == need) {
        for (int w = 0; w < nwin; ++w) { fidx[nfinal] = widx[w]; fval[nfinal] = wvf[w]; ++nfinal; }
    } else {
        // fp64 arbitration of the boundary window (rare), 32-lane dot
        int bb_ = np / (HO_ * WO_);
        int rr  = np - bb_ * (HO_ * WO_);
        int ho2 = rr / WO_;
        int wo2 = rr - ho2 * WO_;
        const float* xb = x + (size_t)bb_ * CHN * HH * WW;
        double wv64[8];
        for (int w = 0; w < nwin; ++w) {
            int at = widx[w];
            double sd = 0.0;
#pragma unroll
            for (int t = 0; t < 32; ++t) {
                int kk = sl + (t << 5);
                int c  = kk >> 4, pr = (kk >> 2) & 3, pc = kk & 3;
                float xv = xb[((size_t)c * HH + (2 * ho2 + pr)) * WW + 2 * wo2 + pc];
                float dv = D[(size_t)kk * NATOMS + at];
                sd = fma((double)xv, (double)dv, sd);
            }
            for (int off = 16; off; off >>= 1) sd += __shfl_xor(sd, off);
            wv64[w] = sd;
        }
        unsigned taken = 0u;
        for (int scnt = 0; scnt < need; ++scnt) {
            int best = -1; double bbv = -1.0;
            for (int w = 0; w < nwin; ++w) {
                if ((taken >> w) & 1u) continue;
                double aw = fabs(wv64[w]);
                if (aw > bbv || (aw == bbv && best >= 0 && widx[w] < widx[best])) { bbv = aw; best = w; }
            }
            taken |= 1u << best;
            fidx[nfinal] = widx[best];
            fval[nfinal] = (float)wv64[best];
            ++nfinal;
        }
    }

    // ---- 5x5 solve (fp32); gram gathered in PARALLEL across lanes ----
    float A[KSP][KSP], bb[KSP];
    {
        float gv = 0.f;
        if (sl < 25) {
            int gi = sl / 5, gj = sl - 5 * gi;
            gv = gram[(size_t)fidx[gi] * NATOMS + fidx[gj]];
        }
#pragma unroll
        for (int i = 0; i < KSP; ++i)
#pragma unroll
            for (int j = 0; j < KSP; ++j)
                A[i][j] = __shfl(gv, i * 5 + j + half * 32);
    }
#pragma unroll
    for (int i = 0; i < KSP; ++i) bb[i] = fval[i];
#pragma unroll
    for (int c = 0; c < KSP; ++c) {
        float inv = 1.0f / A[c][c];
#pragma unroll
        for (int r = 0; r < KSP; ++r) {
            if (r > c) {
                float f = A[r][c] * inv;
#pragma unroll
                for (int cc = 0; cc < KSP; ++cc)
                    if (cc > c) A[r][cc] -= f * A[c][cc];
                bb[r] -= f * bb[c];
            }
        }
    }
#pragma unroll
    for (int r = KSP - 1; r >= 0; --r) {
        float t = bb[r];
#pragma unroll
        for (int cc = 0; cc < KSP; ++cc)
            if (cc > r) t -= A[r][cc] * bb[cc];
        bb[r] = t / A[r][r];
    }
    if (sl == 0) {
#pragma unroll
        for (int i = 0; i < KSP; ++i) {
            sup_out[(size_t)np * KSP + i] = fidx[i];
            val_out[(size_t)np * KSP + i] = bb[i];
        }
    }
}

// ------- fused reconstruction: compact-dict gather + LDS transpose ----------
// Block = 16 consecutive patches. Lane = channel; per atom one 16B f16x8
// load from Dqi = {h5,h6,h9,h10,l5,l6,l9,l10} -> bit-identical z. LDS
// staging + write phase identical to the 201.7us config.
__global__ __launch_bounds__(256) void reconp_kernel(const float* __restrict__ x,
                                                     const f16* __restrict__ Dqi,
                                                     const int* __restrict__ sup,
                                                     const float* __restrict__ val,
                                                     float* __restrict__ out,
                                                     double* __restrict__ rpart) {
    __shared__ f32x4 zbuf[16][65];
    __shared__ double red[4];
    const int lane = threadIdx.x & 63;
    const int wave = threadIdx.x >> 6;
    const int n0   = blockIdx.x * 16;

#pragma unroll
    for (int it = 0; it < 4; ++it) {
        const int nl = it * 4 + wave;
        const int n  = n0 + nl;
        if (n < NPATCH) {
            const int*   sp = sup + (size_t)n * KSP;
            const float* vp = val + (size_t)n * KSP;
            float z0 = 0.f, z1 = 0.f, z2 = 0.f, z3 = 0.f;
#pragma unroll
            for (int t = 0; t < KSP; ++t) {
                int a = sp[t]; float v = vp[t];
                f16x8 q = *(const f16x8*)(Dqi + ((size_t)a * CHN + lane) * 8);
                z0 = fmaf(v, (float)q[0] + (float)q[4], z0);
                z1 = fmaf(v, (float)q[1] + (float)q[5], z1);
                z2 = fmaf(v, (float)q[2] + (float)q[6], z2);
                z3 = fmaf(v, (float)q[3] + (float)q[7], z3);
            }
            zbuf[nl][lane] = (f32x4){ z0, z1, z2, z3 };
        }
    }
    __syncthreads();

    double sq = 0.0;
#pragma unroll
    for (int k = 0; k < 4; ++k) {
        int f  = threadIdx.x + 256 * k;       // 0..1023, nl minor -> coalesced
        int c  = f >> 4;
        int nl = f & 15;
        int n  = n0 + nl;
        if (n < NPATCH) {
            int b  = n / (HO_ * WO_);
            int r  = n - b * (HO_ * WO_);
            int ho = r / WO_, wo = r - ho * WO_;
            f32x4 zv = zbuf[nl][c];
            size_t base = ((size_t)(b * CHN + c) * HH + (2 * ho + 1)) * WW + (2 * wo + 1);
            float x0 = x[base],      x1 = x[base + 1];
            float x2 = x[base + WW], x3 = x[base + WW + 1];
            out[base]          = x0 + (zv.x - x0);
            out[base + 1]      = x1 + (zv.y - x1);
            out[base + WW]     = x2 + (zv.z - x2);
            out[base + WW + 1] = x3 + (zv.w - x3);
            float d0 = zv.x - x0, d1 = zv.y - x1, d2 = zv.z - x2, d3 = zv.w - x3;
            sq += (double)d0 * d0 + (double)d1 * d1 + (double)d2 * d2 + (double)d3 * d3;
        }
    }

    for (int off = 32; off; off >>= 1) sq += __shfl_xor(sq, off);
    if (lane == 0) red[wave] = sq;
    __syncthreads();
    if (threadIdx.x == 0) rpart[blockIdx.x] = red[0] + red[1] + red[2] + red[3];
}

// ------- border pixels: z_q = 0 -> out = x + (0 - x), loss += x^2 -----------
__global__ __launch_bounds__(256) void border_kernel(const float* __restrict__ x,
                                                     float* __restrict__ out,
                                                     double* __restrict__ bpart) {
    const int plane = blockIdx.x;             // b*CHN + c, 0..511
    const float* xp = x + (size_t)plane * HH * WW;
    float* op = out + (size_t)plane * HH * WW;
    double sq = 0.0;
    for (int idx = threadIdx.x; idx < 508; idx += 256) {
        int i, j;
        if (idx < 128)      { i = 0;         j = idx;       }
        else if (idx < 256) { i = 127;       j = idx - 128; }
        else if (idx < 382) { i = idx - 255; j = 0;         }   // i = 1..126
        else                { i = idx - 381; j = 127;       }   // i = 1..126
        float xv = xp[i * WW + j];
        op[i * WW + j] = xv + (0.0f - xv);
        sq += (double)xv * xv;
    }
    for (int off = 32; off; off >>= 1) sq += __shfl_xor(sq, off);
    __shared__ double red[4];
    const int lane = threadIdx.x & 63, wv = threadIdx.x >> 6;
    if (lane == 0) red[wv] = sq;
    __syncthreads();
    if (threadIdx.x == 0) bpart[blockIdx.x] = red[0] + red[1] + red[2] + red[3];
}

// ------- loss finalize: sum reconp + border partials ------------------------
__global__ __launch_bounds__(256) void loss2_kernel(const double* __restrict__ rpart,
                                                    const double* __restrict__ bpart,
                                                    float* __restrict__ out) {
    double s = 0.0;
    for (int i = threadIdx.x; i < RPB; i += 256) s += rpart[i];
    for (int i = threadIdx.x; i < 512; i += 256) s += bpart[i];
    for (int off = 32; off; off >>= 1) s += __shfl_xor(s, off);
    __shared__ double red[4];
    const int lane = threadIdx.x & 63, wv = threadIdx.x >> 6;
    if (lane == 0) red[wv] = s;
    __syncthreads();
    if (threadIdx.x == 0) {
        double m = (red[0] + red[1] + red[2] + red[3]) / (double)OUT_N;
        out[OUT_N] = (float)(m + 0.25 * m);
    }
}

// ======================= FALLBACK PATH (small ws) ===========================
__global__ __launch_bounds__(256) void corr_kernel_fb(const float* __restrict__ x,
                                                      const float* __restrict__ D,
                                                      const float* __restrict__ gram,
                                                      int* __restrict__ sup_out,
                                                      float* __restrict__ val_out) {
    __shared__ float pt[256 * MT];
    __shared__ float corrbuf[MT][NATOMS];
    __shared__ int   sup_s[MT][KSP];
    __shared__ float rhs_s[MT][KSP];

    const int tid  = threadIdx.x;
    const int lane = tid & 63;
    const int wave = tid >> 6;
    const int n0   = blockIdx.x * MT;
    const int sp  = lane & 15;
    const int spr = lane >> 4;

    int n = n0 + sp;
    bool pvalid = (n < NPATCH);
    int b = 0, ho = 0, wo = 0;
    if (pvalid) {
        b = n / (HO_ * WO_);
        int r = n - b * (HO_ * WO_);
        ho = r / WO_;
        wo = r - ho * WO_;
    }

    f32x2 accP[2][8];
#pragma unroll
    for (int a = 0; a < 2; ++a)
#pragma unroll
        for (int g = 0; g < 8; ++g) accP[a][g] = (f32x2)(0.f);

    for (int chunk = 0; chunk < 4; ++chunk) {
        __syncthreads();
#pragma unroll
        for (int t = 0; t < 4; ++t) {
            int s = wave + 4 * t;
            int c = chunk * 16 + s;
            float2 va = make_float2(0.f, 0.f), vb = make_float2(0.f, 0.f);
            if (pvalid) {
                const float* px = x + (((size_t)b * CHN + c) * HH + (2 * ho + spr)) * WW + 2 * wo;
                va = *(const float2*)px;
                vb = *(const float2*)(px + 2);
            }
            int kl = (s * 16 + spr * 4) * MT + sp;
            pt[kl]          = va.x;
            pt[kl + MT]     = va.y;
            pt[kl + 2 * MT] = vb.x;
            pt[kl + 3 * MT] = vb.y;
        }
        __syncthreads();
        const float* Dp = D + (size_t)chunk * 256 * NATOMS + 2 * tid;
#pragma unroll 4
        for (int k = 0; k < 256; ++k) {
            float2 dv = *(const float2*)(Dp + (size_t)k * NATOMS);
            f32x2 d00 = {dv.x, dv.x}, d11 = {dv.y, dv.y};
#pragma unroll
            for (int q = 0; q < 4; ++q) {
                const float4 f = *(const float4*)&pt[k * MT + 4 * q];
                f32x2 flo = {f.x, f.y}, fhi = {f.z, f.w};
                accP[0][2 * q]     = fma2(flo, d00, accP[0][2 * q]);
                accP[1][2 * q]     = fma2(flo, d11, accP[1][2 * q]);
                accP[0][2 * q + 1] = fma2(fhi, d00, accP[0][2 * q + 1]);
                accP[1][2 * q + 1] = fma2(fhi, d11, accP[1][2 * q + 1]);
            }
        }
    }
#pragma unroll
    for (int g = 0; g < 8; ++g) {
        *(float2*)&corrbuf[2 * g][2 * tid]     = make_float2(accP[0][g].x, accP[1][g].x);
        *(float2*)&corrbuf[2 * g + 1][2 * tid] = make_float2(accP[0][g].y, accP[1][g].y);
    }
    __syncthreads();

    for (int pi = 0; pi < 4; ++pi) {
        int p  = wave * 4 + pi;
        int np = n0 + p;
        if (np >= NPATCH) continue;
        float v[8], av[8];
#pragma unroll
        for (int i = 0; i < 8; ++i) {
            v[i]  = corrbuf[p][lane + 64 * i];
            av[i] = fabsf(v[i]);
        }
        unsigned usedm = 0u;
        int   top_i[KSP];
        float top_v[KSP];
#pragma unroll
        for (int r = 0; r < KSP; ++r) {
            float ba = -1.0f, bv = 0.0f;
            int   bi = 0x7FFFFFFF;
#pragma unroll
            for (int i = 0; i < 8; ++i) {
                if (!((usedm >> i) & 1u)) {
                    int idx = lane + 64 * i;
                    if (av[i] > ba || (av[i] == ba && idx < bi)) { ba = av[i]; bi = idx; bv = v[i]; }
                }
            }
            for (int off = 32; off; off >>= 1) {
                float oa = __shfl_xor(ba, off);
                int   oi = __shfl_xor(bi, off);
                float ov = __shfl_xor(bv, off);
                if (oa > ba || (oa == ba && oi < bi)) { ba = oa; bi = oi; bv = ov; }
            }
            top_i[r] = bi; top_v[r] = bv;
            if (lane == (bi & 63)) usedm |= (1u << (bi >> 6));
        }
        const float a5 = fabsf(top_v[KSP - 1]);
        const float lo = a5 - DELTA, hi = a5 + DELTA;
        int   nfinal = 0, fidx[KSP];
        float fval[KSP];
        int   nwin = 0, widx[8];
        float wvf[8];
#pragma unroll
        for (int r = 0; r < KSP; ++r) {
            if (fabsf(top_v[r]) > hi) { fidx[nfinal] = top_i[r]; fval[nfinal] = top_v[r]; ++nfinal; }
            else if (nwin < 8)        { widx[nwin] = top_i[r]; wvf[nwin] = top_v[r]; ++nwin; }
        }
#pragma unroll
        for (int i = 0; i < 8; ++i) {
            bool ex = (((usedm >> i) & 1u) == 0u) && (av[i] >= lo);
            unsigned long long m = __ballot(ex);
            while (m && nwin < 8) {
                int l = __ffsll(m) - 1; m &= m - 1;
                widx[nwin] = l + 64 * i;
                wvf[nwin]  = __shfl(v[i], l);
                ++nwin;
            }
        }
        const int need = KSP - nfinal;
        if (nwin == need) {
            for (int w = 0; w < nwin; ++w) { fidx[nfinal] = widx[w]; fval[nfinal] = wvf[w]; ++nfinal; }
        } else {
            int bb_ = np / (HO_ * WO_);
            int rr  = np - bb_ * (HO_ * WO_);
            int ho2 = rr / WO_;
            int wo2 = rr - ho2 * WO_;
            const float* xb = x + (size_t)bb_ * CHN * HH * WW;
            double wv64[8];
            for (int w = 0; w < nwin; ++w) {
                int a = widx[w];
                double s = 0.0;
                for (int t = 0; t < 16; ++t) {
                    int k  = lane + (t << 6);
                    int c  = k >> 4, pr = (k >> 2) & 3, pc = k & 3;
                    float xv = xb[((size_t)c * HH + (2 * ho2 + pr)) * WW + 2 * wo2 + pc];
                    float dv = D[(size_t)k * NATOMS + a];
                    s = fma((double)xv, (double)dv, s);
                }
                for (int off = 32; off; off >>= 1) s += __shfl_xor(s, off);
                wv64[w] = s;
            }
            unsigned taken = 0u;
            for (int scnt = 0; scnt < need; ++scnt) {
                int best = -1; double bbv = -1.0;
                for (int w = 0; w < nwin; ++w) {
                    if ((taken >> w) & 1u) continue;
                    double aw = fabs(wv64[w]);
                    if (aw > bbv || (aw == bbv && best >= 0 && widx[w] < widx[best])) { bbv = aw; best = w; }
                }
                taken |= 1u << best;
                fidx[nfinal] = widx[best];
                fval[nfinal] = (float)wv64[best];
                ++nfinal;
            }
        }
        if (lane == 0) {
#pragma unroll
            for (int r = 0; r < KSP; ++r) { sup_s[p][r] = fidx[r]; rhs_s[p][r] = fval[r]; }
        }
    }
    __syncthreads();

    if (tid < MT) {
        int p = tid, np = n0 + p;
        if (np < NPATCH) {
            int s[KSP];
            double A[KSP][KSP], bb[KSP];
#pragma unroll
            for (int i = 0; i < KSP; ++i) { s[i] = sup_s[p][i]; bb[i] = (double)rhs_s[p][i]; }
#pragma unroll
            for (int i = 0; i < KSP; ++i)
#pragma unroll
                for (int j = 0; j < KSP; ++j)
                    A[i][j] = (double)gram[(size_t)s[i] * NATOMS + s[j]] + (i == j ? 1e-10 : 0.0);
#pragma unroll
            for (int c = 0; c < KSP; ++c) {
                double inv = 1.0 / A[c][c];
#pragma unroll
                for (int r = 0; r < KSP; ++r) {
                    if (r > c) {
                        double f = A[r][c] * inv;
#pragma unroll
                        for (int cc = 0; cc < KSP; ++cc)
                            if (cc > c) A[r][cc] -= f * A[c][cc];
                        bb[r] -= f * bb[c];
                    }
                }
            }
#pragma unroll
            for (int r = KSP - 1; r >= 0; --r) {
                double t = bb[r];
#pragma unroll
                for (int cc = 0; cc < KSP; ++cc)
                    if (cc > r) t -= A[r][cc] * bb[cc];
                bb[r] = t / A[r][r];
            }
#pragma unroll
            for (int i = 0; i < KSP; ++i) {
                sup_out[(size_t)np * KSP + i] = s[i];
                val_out[(size_t)np * KSP + i] = (float)bb[i];
            }
        }
    }
}

__global__ __launch_bounds__(256) void recon_kernel_fb(const float* __restrict__ x,
                                                       const float* __restrict__ D,
                                                       const int* __restrict__ sup,
                                                       const float* __restrict__ val,
                                                       float* __restrict__ out,
                                                       double* __restrict__ partials) {
    double sqacc = 0.0;
    for (size_t o = (size_t)blockIdx.x * 256 + threadIdx.x; o < OUT_N; o += (size_t)FBLK * 256) {
        const int j = (int)(o & 127);
        const int i = (int)((o >> 7) & 127);
        const int c = (int)((o >> 14) & 63);
        const int b = (int)(o >> 20);
        const float xv = x[o];
        float z = 0.0f;
        const int pr = (i & 1) ? 1 : 2;
        const int pc = (j & 1) ? 1 : 2;
        const int ho = (i - pr) >> 1;
        const int wo = (j - pc) >> 1;
        if (ho >= 0 && ho < HO_ && wo >= 0 && wo < WO_) {
            const int n = (b * HO_ + ho) * WO_ + wo;
            const int k = c * 16 + pr * 4 + pc;
            const int*   sp5 = sup + (size_t)n * KSP;
            const float* vp5 = val + (size_t)n * KSP;
            float s = 0.0f;
#pragma unroll
            for (int t = 0; t < KSP; ++t)
                s = fmaf(vp5[t], D[(size_t)k * NATOMS + sp5[t]], s);
            z = s;
        }
        out[o] = xv + (z - xv);
        const float d = z - xv;
        sqacc += (double)d * (double)d;
    }
    for (int off = 32; off; off >>= 1) sqacc += __shfl_xor(sqacc, off);
    __shared__ double red[4];
    const int lane = threadIdx.x & 63, wv = threadIdx.x >> 6;
    if (lane == 0) red[wv] = sqacc;
    __syncthreads();
    if (threadIdx.x == 0) partials[blockIdx.x] = red[0] + red[1] + red[2] + red[3];
}

__global__ __launch_bounds__(256) void loss_kernel(const double* __restrict__ partials,
                                                   float* __restrict__ out) {
    double s = 0.0;
    for (int i = threadIdx.x; i < FBLK; i += 256) s += partials[i];
    for (int off = 32; off; off >>= 1) s += __shfl_xor(s, off);
    __shared__ double red[4];
    const int lane = threadIdx.x & 63, wv = threadIdx.x >> 6;
    if (lane == 0) red[wv] = s;
    __syncthreads();
    if (threadIdx.x == 0) {
        double m = (red[0] + red[1] + red[2] + red[3]) / (double)OUT_N;
        out[OUT_N] = (float)(m + 0.25 * m);
    }
}

// ---------------------------------------------------------------------------
extern "C" void kernel_launch(void* const* d_in, const int* in_sizes, int n_in,
                              void* d_out, int out_size, void* d_ws, size_t ws_size,
                              hipStream_t stream) {
    const float* x = (const float*)d_in[0];
    const float* D = (const float*)d_in[1];
    float* out = (float*)d_out;
    char* ws = (char*)d_ws;

    size_t off = 0;
    auto take = [&](size_t bytes) { char* p = ws + off; off += (bytes + 255) & ~(size_t)255; return p; };
    float*    gram     = (float*)take((size_t)NATOMS * NATOMS * 4);
    int*      sup      = (int*)take((size_t)NPATCH * KSP * 4);
    float*    val      = (float*)take((size_t)NPATCH * KSP * 4);
    double*   partials = (double*)take((size_t)FBLK * 8);
    double*   rpart    = (double*)take((size_t)RPB * 8);
    double*   bpart    = (double*)take((size_t)512 * 8);
    unsigned* topk     = (unsigned*)take((size_t)NPATCH * 16 * 4);
    f16*   Dth  = (f16*)take((size_t)NATOMS * PDIM * 2);
    f16*   Dtl  = (f16*)take((size_t)NATOMS * PDIM * 2);
    f16*   Dqi  = (f16*)take((size_t)NATOMS * CHN * 8 * 2);
    f16*   Xh   = (f16*)take((size_t)MPAD * PDIM * 2);
    f16*   corr = (f16*)take((size_t)MPAD * NATOMS * 2);
    const bool big = (off <= ws_size);

    if (big) {
        hipMemsetAsync(Xh + (size_t)NPATCH * PDIM, 0,
                       (size_t)(MPAD - NPATCH) * PDIM * sizeof(f16), stream);
        extract_kernel<<<8 * HO_ * 4, 256, 0, stream>>>(x, Xh);
        dtrans_kernel<<<dim3(16, 8), 256, 0, stream>>>(D, Dth, Dtl, Dqi);
        gram_kernel<<<dim3(16, 16), 256, 0, stream>>>(D, gram);
        border_kernel<<<512, 256, 0, stream>>>(x, out, bpart);
        gemm_kernel<<<512, 512, 0, stream>>>(Xh, Dth, corr);
        topred_kernel<<<(NPATCH + 15) / 16, 512, 0, stream>>>(corr, topk);
        topfin_kernel<<<NPATCH / 2, 64, 0, stream>>>(topk, corr, x, D, gram, sup, val);
        reconp_kernel<<<RPB, 256, 0, stream>>>(x, Dqi, sup, val, out, rpart);
        loss2_kernel<<<1, 256, 0, stream>>>(rpart, bpart, out);
    } else {
        gram_kernel<<<dim3(16, 16), 256, 0, stream>>>(D, gram);
        corr_kernel_fb<<<(NPATCH + MT - 1) / MT, 256, 0, stream>>>(x, D, gram, sup, val);
        recon_kernel_fb<<<FBLK, 256, 0, stream>>>(x, D, sup, val, out, partials);
        loss_kernel<<<1, 256, 0, stream>>>(partials, out);
    }
}

// Round 27
// 190.897 us; speedup vs baseline: 1.3163x; 1.0267x over previous
//
#include <hip/hip_runtime.h>

#define CHN    64
#define NATOMS 512
#define PDIM   1024
#define KSP    5
#define HO_    63
#define WO_    63
#define NPATCH 31752
#define MPAD   31872          // 249 * 128
#define HH     128
#define WW     128
#define MT     16
#define OUT_N  8388608
#define DELTA  6e-3f
#define QGUARD 2.5e-3f
#define FBLK   2048
#define RPB    (8 * HO_ * 4)  // 2016 reconp blocks: (b, ho, channel-group)

typedef _Float16 f16;
typedef _Float16 f16x8 __attribute__((ext_vector_type(8)));
typedef _Float16 f16x4 __attribute__((ext_vector_type(4)));
typedef float    f32x4 __attribute__((ext_vector_type(4)));
typedef float    f32x2 __attribute__((ext_vector_type(2)));

static __device__ __forceinline__ void gload_lds16(const void* g, void* l) {
    __builtin_amdgcn_global_load_lds(
        (const __attribute__((address_space(1))) unsigned int*)g,
        (__attribute__((address_space(3))) unsigned int*)l, 16, 0, 0);
}

static __device__ inline f32x2 fma2(f32x2 a, f32x2 b, f32x2 c) {
#if __has_builtin(__builtin_elementwise_fma)
    return __builtin_elementwise_fma(a, b, c);
#else
    f32x2 r; r.x = fmaf(a.x, b.x, c.x); r.y = fmaf(a.y, b.y, c.y); return r;
#endif
}

// ---- u32 key: (abs>>11)<<11 | (1023-idx)<<1 | sign ----
static __device__ __forceinline__ unsigned mk_key32(float v, int idx) {
    unsigned vb = __float_as_uint(v);
    unsigned ab = vb & 0x7FFFFFFFu;
    return ((ab >> 11) << 11) | ((unsigned)(1023 - idx) << 1) | (vb >> 31);
}
static __device__ __forceinline__ int key32_idx(unsigned k) {
    return 1023 - (int)((k >> 1) & 1023u);
}

#define CEU(s, i, j) { unsigned _a = s[i], _b = s[j]; \
                       s[i] = _a > _b ? _a : _b; s[j] = _a > _b ? _b : _a; }

#define SORT8(s) \
    CEU(s,0,1) CEU(s,2,3) CEU(s,4,5) CEU(s,6,7) \
    CEU(s,0,2) CEU(s,1,3) CEU(s,4,6) CEU(s,5,7) \
    CEU(s,1,2) CEU(s,5,6) \
    CEU(s,0,4) CEU(s,1,5) CEU(s,2,6) CEU(s,3,7) \
    CEU(s,2,4) CEU(s,3,5) \
    CEU(s,1,2) CEU(s,3,4) CEU(s,5,6)

#define MERGE8(s, a, b) { \
    unsigned L[8]; \
    L[0] = a[0] > b[7] ? a[0] : b[7]; L[1] = a[1] > b[6] ? a[1] : b[6]; \
    L[2] = a[2] > b[5] ? a[2] : b[5]; L[3] = a[3] > b[4] ? a[3] : b[4]; \
    L[4] = a[4] > b[3] ? a[4] : b[3]; L[5] = a[5] > b[2] ? a[5] : b[2]; \
    L[6] = a[6] > b[1] ? a[6] : b[1]; L[7] = a[7] > b[0] ? a[7] : b[0]; \
    CEU(L,0,4) CEU(L,1,5) CEU(L,2,6) CEU(L,3,7) \
    CEU(L,0,2) CEU(L,1,3) CEU(L,4,6) CEU(L,5,7) \
    CEU(L,0,1) CEU(L,2,3) CEU(L,4,5) CEU(L,6,7) \
    for (int _i = 0; _i < 8; ++_i) s[_i] = L[_i]; }

// ---------------- gram = D^T D, 32x32 tiles, fp32 accumulate ----------------
__global__ __launch_bounds__(256) void gram_kernel(const float* __restrict__ D,
                                                   float* __restrict__ gram) {
    __shared__ float Ti[64][32];
    __shared__ float Tj[64][32];
    const int tid = threadIdx.x;
    const int i0 = blockIdx.x * 32, j0 = blockIdx.y * 32;
    const int ri  = tid >> 3;
    const int rj0 = (tid & 7) * 4;
    float acc[4] = {0.f, 0.f, 0.f, 0.f};
    for (int k0 = 0; k0 < PDIM; k0 += 64) {
        __syncthreads();
#pragma unroll
        for (int s = 0; s < 8; ++s) {
            int e = tid + 256 * s;
            int kk = e >> 5, col = e & 31;
            Ti[kk][col] = D[(size_t)(k0 + kk) * NATOMS + i0 + col];
            Tj[kk][col] = D[(size_t)(k0 + kk) * NATOMS + j0 + col];
        }
        __syncthreads();
#pragma unroll 4
        for (int kk = 0; kk < 64; ++kk) {
            float ti = Ti[kk][ri];
#pragma unroll
            for (int q = 0; q < 4; ++q)
                acc[q] = fmaf(ti, Tj[kk][rj0 + q], acc[q]);
        }
    }
#pragma unroll
    for (int q = 0; q < 4; ++q)
        gram[(size_t)(i0 + ri) * NATOMS + j0 + rj0 + q] = acc[q];
}

// ------------- patch extraction (coalesced): x -> Xh [MPAD][1024] f16 -------
__global__ __launch_bounds__(256) void extract_kernel(const float* __restrict__ x,
                                                      f16* __restrict__ Xh) {
    __shared__ float xs[16][4][129];
    const int bid = blockIdx.x;
    const int cg  = bid & 3;
    const int t   = bid >> 2;
    const int ho  = t % HO_;
    const int b   = t / HO_;

    for (int i = threadIdx.x; i < 64 * 32; i += 256) {
        int r = i >> 5;
        int q = i & 31;
        int c = r >> 2, pr = r & 3;
        float4 v = *(const float4*)(x + ((size_t)(b * CHN + cg * 16 + c) * HH
                                         + (2 * ho + pr)) * WW + q * 4);
        xs[c][pr][q * 4 + 0] = v.x;
        xs[c][pr][q * 4 + 1] = v.y;
        xs[c][pr][q * 4 + 2] = v.z;
        xs[c][pr][q * 4 + 3] = v.w;
    }
    __syncthreads();

    for (int p = threadIdx.x; p < WO_ * 16; p += 256) {
        int wo = p >> 4;
        int c  = p & 15;
        f16 h[16];
#pragma unroll
        for (int pr = 0; pr < 4; ++pr)
#pragma unroll
            for (int pc = 0; pc < 4; ++pc)
                h[pr * 4 + pc] = (f16)xs[c][pr][2 * wo + pc];
        int n = (b * HO_ + ho) * WO_ + wo;
        f16x8 v0, v1;
#pragma unroll
        for (int i2 = 0; i2 < 8; ++i2) { v0[i2] = h[i2]; v1[i2] = h[8 + i2]; }
        f16* dh = Xh + (size_t)n * PDIM + (cg * 16 + c) * 16;
        *(f16x8*)dh = v0; *(f16x8*)(dh + 8) = v1;
    }
}

// ------------- D -> Dt transpose via LDS tiles (coalesced both sides) -------
// Also emits the compact interleaved inner-2x2 dictionary Dqi[atom][c][8] f16
// = {h5,h6,h9,h10, l5,l6,l9,l10} for reconp (one 16B load per atom).
__global__ __launch_bounds__(256) void dtrans_kernel(const float* __restrict__ D,
                                                     f16* __restrict__ Dth,
                                                     f16* __restrict__ Dtl,
                                                     f16* __restrict__ Dqi) {
    __shared__ float ts[64][65];
    const int k0 = blockIdx.x * 64;
    const int n0 = blockIdx.y * 64;

    for (int i = threadIdx.x; i < 64 * 16; i += 256) {
        int r = i >> 4;
        int q = i & 15;
        float4 v = *(const float4*)(D + (size_t)(k0 + r) * NATOMS + n0 + q * 4);
        ts[r][q * 4 + 0] = v.x;
        ts[r][q * 4 + 1] = v.y;
        ts[r][q * 4 + 2] = v.z;
        ts[r][q * 4 + 3] = v.w;
    }
    __syncthreads();

    {
        int i = threadIdx.x;
        int nn = i >> 2, q = i & 3;
        f16 h[16], l[16];
#pragma unroll
        for (int j = 0; j < 16; ++j) {
            float v = ts[q * 16 + j][nn];
            f16 hh = (f16)v;
            h[j] = hh;
            l[j] = (f16)(v - (float)hh);
        }
        f16x8 h0, h1, l0, l1;
#pragma unroll
        for (int j = 0; j < 8; ++j) { h0[j] = h[j]; h1[j] = h[8 + j]; l0[j] = l[j]; l1[j] = l[8 + j]; }
        f16* dh = Dth + (size_t)(n0 + nn) * PDIM + k0 + q * 16;
        f16* dl = Dtl + (size_t)(n0 + nn) * PDIM + k0 + q * 16;
        *(f16x8*)dh = h0; *(f16x8*)(dh + 8) = h1;
        *(f16x8*)dl = l0; *(f16x8*)(dl + 8) = l1;

        // compact interleaved inner-2x2: channel c = k0/16 + q
        const int c = (k0 >> 4) + q;
        f16x8 qi = { h[5], h[6], h[9], h[10], l[5], l[6], l[9], l[10] };
        *(f16x8*)(Dqi + ((size_t)(n0 + nn) * CHN + c) * 8) = qi;
    }
}

// ------------- MFMA GEMM: corr[MPAD][512] (f16) = Xh . Dth^T ----------------
// 1D grid, XCD-paired mapping: the two 256-col blocks sharing the same 128
// A-rows are bids (b, b+8) -> same XCD under %8 round-robin -> 2nd A read
// hits that XCD's L2 instead of HBM.
__global__ __launch_bounds__(512) void gemm_kernel(const f16* __restrict__ Xh,
                                                   const f16* __restrict__ Dth,
                                                   f16* __restrict__ corr) {
    __shared__ char lds[98304];
    const int bid = blockIdx.x;
    const int xcd = bid & 7;
    const int jj  = bid >> 3;
    const int m   = (jj >> 1) * 8 + xcd;
    if (m >= MPAD / 128) return;
    const int tid  = threadIdx.x;
    const int lane = tid & 63;
    const int wave = tid >> 6;
    const size_t arow0 = (size_t)m * 128;
    const int    brow0 = (jj & 1) * 256;
    const int wm = wave >> 2;
    const int wn = wave & 3;

    f32x4 acc[4][4];
#pragma unroll
    for (int mm = 0; mm < 4; ++mm)
#pragma unroll
        for (int n = 0; n < 4; ++n) acc[mm][n] = (f32x4){0.f, 0.f, 0.f, 0.f};

    const char* asrc[2]; int adst[2];
#pragma unroll
    for (int i = 0; i < 2; ++i) {
        int p = tid * 16 + i * 8192;
        int row = p >> 7, sc = ((p >> 4) & 7) ^ (row & 7);
        asrc[i] = (const char*)Xh + (arow0 + row) * 2048 + sc * 16;
        adst[i] = p;
    }
    const char* bsrc[4]; int bdst[4];
#pragma unroll
    for (int i = 0; i < 4; ++i) {
        int p = tid * 16 + i * 8192;
        int row = p >> 7, sc = ((p >> 4) & 7) ^ (row & 7);
        bsrc[i] = (const char*)Dth + (size_t)(brow0 + row) * 2048 + sc * 16;
        bdst[i] = 16384 + p;
    }

    int aoff[4][2], boff[4][2];
#pragma unroll
    for (int mm = 0; mm < 4; ++mm)
#pragma unroll
        for (int ks = 0; ks < 2; ++ks) {
            int row = wm * 64 + mm * 16 + (lane & 15);
            int ch  = (ks * 4 + (lane >> 4)) ^ (row & 7);
            aoff[mm][ks] = row * 128 + ch * 16;
        }
#pragma unroll
    for (int n = 0; n < 4; ++n)
#pragma unroll
        for (int ks = 0; ks < 2; ++ks) {
            int row = wn * 64 + n * 16 + (lane & 15);
            int ch  = (ks * 4 + (lane >> 4)) ^ (row & 7);
            boff[n][ks] = 16384 + row * 128 + ch * 16;
        }

#pragma unroll
    for (int i = 0; i < 2; ++i) gload_lds16(asrc[i], lds + adst[i]);
#pragma unroll
    for (int i = 0; i < 4; ++i) gload_lds16(bsrc[i], lds + bdst[i]);
#pragma unroll
    for (int i = 0; i < 2; ++i) asrc[i] += 128;
#pragma unroll
    for (int i = 0; i < 4; ++i) bsrc[i] += 128;
    __syncthreads();

    int bufo = 0;
    for (int kt = 0; kt < 16; ++kt) {
        const int nbuf = bufo ^ 49152;
        if (kt + 1 < 16) {
#pragma unroll
            for (int i = 0; i < 2; ++i) { gload_lds16(asrc[i], lds + nbuf + adst[i]); asrc[i] += 128; }
#pragma unroll
            for (int i = 0; i < 4; ++i) { gload_lds16(bsrc[i], lds + nbuf + bdst[i]); bsrc[i] += 128; }
        }
#pragma unroll
        for (int ks = 0; ks < 2; ++ks) {
            f16x8 a[4], b[4];
#pragma unroll
            for (int mm = 0; mm < 4; ++mm) a[mm] = *(const f16x8*)(lds + bufo + aoff[mm][ks]);
#pragma unroll
            for (int n = 0; n < 4; ++n) b[n] = *(const f16x8*)(lds + bufo + boff[n][ks]);
#pragma unroll
            for (int mm = 0; mm < 4; ++mm)
#pragma unroll
                for (int n = 0; n < 4; ++n)
                    acc[mm][n] = __builtin_amdgcn_mfma_f32_16x16x32_f16(a[mm], b[n], acc[mm][n], 0, 0, 0);
        }
        if (kt + 1 < 16) { __syncthreads(); bufo = nbuf; }
    }

#pragma unroll
    for (int mm = 0; mm < 4; ++mm) {
        size_t row_b = arow0 + wm * 64 + mm * 16 + (lane >> 4) * 4;
#pragma unroll
        for (int n = 0; n < 4; ++n) {
            int col = brow0 + wn * 64 + n * 16 + (lane & 15);
#pragma unroll
            for (int i = 0; i < 4; ++i)
                corr[(row_b + i) * NATOMS + col] = (f16)acc[mm][n][i];
        }
    }
}

// ------- phase 1: sorted top-8 keys + values (f16 corr, cache-hot) ----------
__global__ __launch_bounds__(512) void topred_kernel(const f16* __restrict__ corr,
                                                     unsigned* __restrict__ topk) {
    const int tid = threadIdx.x;
    const int sl  = tid & 31;
    const int hw  = tid >> 5;                 // half-wave 0..15
    const int np  = blockIdx.x * 16 + hw;     // may run into pad rows (< MPAD)

    const f16* row = corr + (size_t)np * NATOMS;
    const f16* cr = row + sl * 16;
    f16x8 c0 = *(const f16x8*)cr;
    f16x8 c1 = *(const f16x8*)(cr + 8);
    unsigned k[16];
#pragma unroll
    for (int j = 0; j < 8; ++j) {
        k[j]     = mk_key32((float)c0[j], sl * 16 + j);
        k[8 + j] = mk_key32((float)c1[j], sl * 16 + 8 + j);
    }

    unsigned a[8], b8[8];
#pragma unroll
    for (int i = 0; i < 8; ++i) { a[i] = k[i]; b8[i] = k[8 + i]; }
    SORT8(a)
    SORT8(b8)
    unsigned s[8];
    MERGE8(s, a, b8)
#pragma unroll
    for (int off = 16; off; off >>= 1) {
        unsigned p[8];
#pragma unroll
        for (int i = 0; i < 8; ++i) p[i] = (unsigned)__shfl_xor((int)s[i], off);
        MERGE8(s, s, p)
    }

    if (sl == 0 && np < NPATCH) {
        float v0 = (float)row[key32_idx(s[0])], v1 = (float)row[key32_idx(s[1])];
        float v2 = (float)row[key32_idx(s[2])], v3 = (float)row[key32_idx(s[3])];
        float v4 = (float)row[key32_idx(s[4])], v5 = (float)row[key32_idx(s[5])];
        float v6 = (float)row[key32_idx(s[6])], v7 = (float)row[key32_idx(s[7])];
        uint4* dst = (uint4*)(topk + (size_t)np * 16);
        dst[0] = make_uint4(s[0], s[1], s[2], s[3]);
        dst[1] = make_uint4(s[4], s[5], s[6], s[7]);
        dst[2] = make_uint4(__float_as_uint(v0), __float_as_uint(v1),
                            __float_as_uint(v2), __float_as_uint(v3));
        dst[3] = make_uint4(__float_as_uint(v4), __float_as_uint(v5),
                            __float_as_uint(v6), __float_as_uint(v7));
    }
}

// ------- phase 2: 64-thr blocks; parallel gram gather; unrolled arbitration -
__global__ __launch_bounds__(64) void topfin_kernel(const unsigned* __restrict__ topk,
                                                    const f16* __restrict__ corr,
                                                    const float* __restrict__ x,
                                                    const float* __restrict__ D,
                                                    const float* __restrict__ gram,
                                                    int* __restrict__ sup_out,
                                                    float* __restrict__ val_out) {
    const int lane = threadIdx.x & 63;
    const int half = lane >> 5;
    const int sl   = lane & 31;
    const int hw   = threadIdx.x >> 5;        // 0..1
    const int np   = blockIdx.x * 2 + hw;     // grid*2 == NPATCH exactly

    unsigned s[8];
    float    tval[8];
    {
        const uint4* src = (const uint4*)(topk + (size_t)np * 16);
        uint4 s0 = src[0], s1 = src[1], v0 = src[2], v1 = src[3];
        s[0] = s0.x; s[1] = s0.y; s[2] = s0.z; s[3] = s0.w;
        s[4] = s1.x; s[5] = s1.y; s[6] = s1.z; s[7] = s1.w;
        tval[0] = __uint_as_float(v0.x); tval[1] = __uint_as_float(v0.y);
        tval[2] = __uint_as_float(v0.z); tval[3] = __uint_as_float(v0.w);
        tval[4] = __uint_as_float(v1.x); tval[5] = __uint_as_float(v1.y);
        tval[6] = __uint_as_float(v1.z); tval[7] = __uint_as_float(v1.w);
    }
    int tidx[8];
#pragma unroll
    for (int r = 0; r < 8; ++r) tidx[r] = key32_idx(s[r]);

    const float a5 = fabsf(tval[KSP - 1]);
    const float lo = fmaxf(a5 - DELTA, 0.0f);
    const float hi = a5 + DELTA;
    const unsigned lokey = (__float_as_uint(fmaxf(lo - QGUARD, 0.0f)) >> 11) << 11;

    int   nfinal = 0, fidx[KSP];
    float fval[KSP];
    int   nwin = 0, widx[8];
    float wvf[8];
#pragma unroll
    for (int r = 0; r < KSP; ++r) {
        if (fabsf(tval[r]) > hi) { fidx[nfinal] = tidx[r]; fval[nfinal] = tval[r]; ++nfinal; }
        else                     { widx[nwin] = tidx[r]; wvf[nwin] = tval[r]; ++nwin; }
    }
#pragma unroll
    for (int r = KSP; r < 8; ++r) {
        if (fabsf(tval[r]) >= lo && nwin < 8) { widx[nwin] = tidx[r]; wvf[nwin] = tval[r]; ++nwin; }
    }

    // rescan for extras beyond top-8 (only when the 8th key is inside window)
    if (s[7] >= lokey) {
        const f16* cr = corr + (size_t)np * NATOMS + sl * 16;
        f16x8 c0 = *(const f16x8*)cr;
        f16x8 c1 = *(const f16x8*)(cr + 8);
        unsigned k[16];
        float vbuf[16];
#pragma unroll
        for (int j = 0; j < 8; ++j) {
            vbuf[j]     = (float)c0[j];
            vbuf[8 + j] = (float)c1[j];
            k[j]        = mk_key32(vbuf[j], sl * 16 + j);
            k[8 + j]    = mk_key32(vbuf[8 + j], sl * 16 + 8 + j);
        }
#pragma unroll
        for (int i = 0; i < 16; ++i) {
            bool ex = (k[i] < s[7]) && (k[i] >= lokey);
            unsigned m = (unsigned)(__ballot(ex) >> (half * 32));
            while (m && nwin < 8) {
                int l = __ffs(m) - 1; m &= m - 1;
                unsigned kk = (unsigned)__shfl((int)k[i], l + half * 32);
                float vv2 = __shfl(vbuf[i], l + half * 32);
                if (fabsf(vv2) >= lo) { widx[nwin] = key32_idx(kk); wvf[nwin] = vv2; ++nwin; }
            }
        }
    }

    const int need = KSP - nfinal;
    if (nwin == need) {
        for (int w = 0; w < nwin; ++w) { fidx[nfinal] = widx[w]; fval[nfinal] = wvf[w]; ++nfinal; }
    } else {
        // fp64 arbitration of the boundary window (rare), 32-lane dot
        int bb_ = np / (HO_ * WO_);
        int rr  = np - bb_ * (HO_ * WO_);
        int ho2 = rr / WO_;
        int wo2 = rr - ho2 * WO_;
        const float* xb = x + (size_t)bb_ * CHN * HH * WW;
        double wv64[8];
        for (int w = 0; w < nwin; ++w) {
            int at = widx[w];
            double sd = 0.0;
#pragma unroll
            for (int t = 0; t < 32; ++t) {
                int kk = sl + (t << 5);
                int c  = kk >> 4, pr = (kk >> 2) & 3, pc = kk & 3;
                float xv = xb[((size_t)c * HH + (2 * ho2 + pr)) * WW + 2 * wo2 + pc];
                float dv = D[(size_t)kk * NATOMS + at];
                sd = fma((double)xv, (double)dv, sd);
            }
            for (int off = 16; off; off >>= 1) sd += __shfl_xor(sd, off);
            wv64[w] = sd;
        }
        unsigned taken = 0u;
        for (int scnt = 0; scnt < need; ++scnt) {
            int best = -1; double bbv = -1.0;
            for (int w = 0; w < nwin; ++w) {
                if ((taken >> w) & 1u) continue;
                double aw = fabs(wv64[w]);
                if (aw > bbv || (aw == bbv && best >= 0 && widx[w] < widx[best])) { bbv = aw; best = w; }
            }
            taken |= 1u << best;
            fidx[nfinal] = widx[best];
            fval[nfinal] = (float)wv64[best];
            ++nfinal;
        }
    }

    // ---- 5x5 solve (fp32); gram gathered in PARALLEL across lanes ----
    float A[KSP][KSP], bb[KSP];
    {
        float gv = 0.f;
        if (sl < 25) {
            int gi = sl / 5, gj = sl - 5 * gi;
            gv = gram[(size_t)fidx[gi] * NATOMS + fidx[gj]];
        }
#pragma unroll
        for (int i = 0; i < KSP; ++i)
#pragma unroll
            for (int j = 0; j < KSP; ++j)
                A[i][j] = __shfl(gv, i * 5 + j + half * 32);
    }
#pragma unroll
    for (int i = 0; i < KSP; ++i) bb[i] = fval[i];
#pragma unroll
    for (int c = 0; c < KSP; ++c) {
        float inv = 1.0f / A[c][c];
#pragma unroll
        for (int r = 0; r < KSP; ++r) {
            if (r > c) {
                float f = A[r][c] * inv;
#pragma unroll
                for (int cc = 0; cc < KSP; ++cc)
                    if (cc > c) A[r][cc] -= f * A[c][cc];
                bb[r] -= f * bb[c];
            }
        }
    }
#pragma unroll
    for (int r = KSP - 1; r >= 0; --r) {
        float t = bb[r];
#pragma unroll
        for (int cc = 0; cc < KSP; ++cc)
            if (cc > r) t -= A[r][cc] * bb[cc];
        bb[r] = t / A[r][r];
    }
    if (sl == 0) {
#pragma unroll
        for (int i = 0; i < KSP; ++i) {
            sup_out[(size_t)np * KSP + i] = fidx[i];
            val_out[(size_t)np * KSP + i] = bb[i];
        }
    }
}

// ------- fused reconstruction: (b,ho,cg) blocks, Dqi gather, float4 IO ------
// Thread = (patch p_local, channel c_local); each (patch,channel) computed
// once (no cross-block redundancy). z via one 16B Dqi load per atom (bit-
// identical to the full gather). Write phase = round-23's verified float4
// mapping: two complete image rows for this block's 16 channels.
__global__ __launch_bounds__(256) void reconp_kernel(const float* __restrict__ x,
                                                     const f16* __restrict__ Dqi,
                                                     const int* __restrict__ sup,
                                                     const float* __restrict__ val,
                                                     float* __restrict__ out,
                                                     double* __restrict__ rpart) {
    __shared__ float zplane[4][WO_][17];      // [pos][wo][c_local], 17 KB
    __shared__ double red[4];
    const int tid  = threadIdx.x;
    const int lane = tid & 63;
    const int wave = tid >> 6;
    const int cg = blockIdx.x & 3;
    const int t2 = blockIdx.x >> 2;
    const int ho = t2 % HO_;
    const int b  = t2 / HO_;
    const int nbase = (b * HO_ + ho) * WO_;
    const int p_local = tid >> 4;             // 0..15
    const int c_local = tid & 15;
    const int c = cg * 16 + c_local;

#pragma unroll
    for (int it = 0; it < 4; ++it) {
        const int wo = it * 16 + p_local;
        if (wo < WO_) {
            const int n = nbase + wo;
            const int*   sp = sup + (size_t)n * KSP;
            const float* vp = val + (size_t)n * KSP;
            float z0 = 0.f, z1 = 0.f, z2 = 0.f, z3 = 0.f;
#pragma unroll
            for (int t = 0; t < KSP; ++t) {
                int a = sp[t]; float v = vp[t];
                f16x8 q = *(const f16x8*)(Dqi + ((size_t)a * CHN + c) * 8);
                z0 = fmaf(v, (float)q[0] + (float)q[4], z0);
                z1 = fmaf(v, (float)q[1] + (float)q[5], z1);
                z2 = fmaf(v, (float)q[2] + (float)q[6], z2);
                z3 = fmaf(v, (float)q[3] + (float)q[7], z3);
            }
            zplane[0][wo][c_local] = z0;      // (pr=1,pc=1)
            zplane[1][wo][c_local] = z1;      // (pr=1,pc=2)
            zplane[2][wo][c_local] = z2;      // (pr=2,pc=1)
            zplane[3][wo][c_local] = z3;      // (pr=2,pc=2)
        }
    }
    __syncthreads();

    double sq = 0.0;
#pragma unroll
    for (int k = 0; k < 4; ++k) {
        int f  = tid + 256 * k;               // 0..1023
        int q  = f & 31;                       // float4 col group 0..31
        int cl = (f >> 5) & 15;
        int r  = f >> 9;                       // 0..1
        const int prof = r * 2;                // row 2ho+1 -> pr=1; 2ho+2 -> pr=2
        float4 zv;
        zv.x = (q == 0)  ? 0.f : zplane[prof + 1][2 * q - 1][cl];
        zv.y = zplane[prof][2 * q][cl];
        zv.z = zplane[prof + 1][2 * q][cl];
        zv.w = (q == 31) ? 0.f : zplane[prof][2 * q + 1][cl];
        size_t base = ((size_t)(b * CHN + cg * 16 + cl) * HH + (2 * ho + 1 + r)) * WW + 4 * q;
        float4 xv = *(const float4*)(x + base);
        float4 ov;
        ov.x = xv.x + (zv.x - xv.x);
        ov.y = xv.y + (zv.y - xv.y);
        ov.z = xv.z + (zv.z - xv.z);
        ov.w = xv.w + (zv.w - xv.w);
        *(float4*)(out + base) = ov;
        float d0 = zv.x - xv.x, d1 = zv.y - xv.y, d2 = zv.z - xv.z, d3 = zv.w - xv.w;
        sq += (double)d0 * d0 + (double)d1 * d1 + (double)d2 * d2 + (double)d3 * d3;
    }

    for (int off = 32; off; off >>= 1) sq += __shfl_xor(sq, off);
    if (lane == 0) red[wave] = sq;
    __syncthreads();
    if (threadIdx.x == 0) rpart[blockIdx.x] = red[0] + red[1] + red[2] + red[3];
}

// ------- border rows 0 and 127: out = x + (0 - x), loss += x^2 (float4) -----
__global__ __launch_bounds__(64) void border_kernel(const float* __restrict__ x,
                                                    float* __restrict__ out,
                                                    double* __restrict__ bpart) {
    const int plane = blockIdx.x;             // b*CHN + c, 0..511
    const int t = threadIdx.x;                // 0..63: r = t>>5 (row 0/127), q = t&31
    const int r = (t >> 5) ? 127 : 0;
    const int q = t & 31;
    size_t base = (size_t)plane * HH * WW + (size_t)r * WW + 4 * q;
    float4 xv = *(const float4*)(x + base);
    float4 ov;
    ov.x = xv.x + (0.0f - xv.x);
    ov.y = xv.y + (0.0f - xv.y);
    ov.z = xv.z + (0.0f - xv.z);
    ov.w = xv.w + (0.0f - xv.w);
    *(float4*)(out + base) = ov;
    double sq = (double)xv.x * xv.x + (double)xv.y * xv.y
              + (double)xv.z * xv.z + (double)xv.w * xv.w;
    for (int off = 32; off; off >>= 1) sq += __shfl_xor(sq, off);
    if (threadIdx.x == 0) bpart[blockIdx.x] = sq;
}

// ------- left/right border columns (rows 1..126): same semantics ------------
__global__ __launch_bounds__(256) void border2_kernel(const float* __restrict__ x,
                                                      float* __restrict__ out,
                                                      double* __restrict__ bpart2) {
    const int plane = blockIdx.x;             // b*CHN + c, 0..511
    const float* xp = x + (size_t)plane * HH * WW;
    float* op = out + (size_t)plane * HH * WW;
    double sq = 0.0;
    for (int idx = threadIdx.x; idx < 252; idx += 256) {
        int i = 1 + (idx >> 1);               // 1..126
        int j = (idx & 1) ? 127 : 0;
        float xv = xp[i * WW + j];
        op[i * WW + j] = xv + (0.0f - xv);
        sq += (double)xv * xv;
    }
    for (int off = 32; off; off >>= 1) sq += __shfl_xor(sq, off);
    __shared__ double red[4];
    const int lane = threadIdx.x & 63, wv = threadIdx.x >> 6;
    if (lane == 0) red[wv] = sq;
    __syncthreads();
    if (threadIdx.x == 0) bpart2[blockIdx.x] = red[0] + red[1] + red[2] + red[3];
}

// ------- loss finalize: sum reconp + border partials ------------------------
__global__ __launch_bounds__(256) void loss2_kernel(const double* __restrict__ rpart,
                                                    const double* __restrict__ bpart,
                                                    const double* __restrict__ bpart2,
                                                    float* __restrict__ out) {
    double s = 0.0;
    for (int i = threadIdx.x; i < RPB; i += 256) s += rpart[i];
    for (int i = threadIdx.x; i < 512; i += 256) s += bpart[i] + bpart2[i];
    for (int off = 32; off; off >>= 1) s += __shfl_xor(s, off);
    __shared__ double red[4];
    const int lane = threadIdx.x & 63, wv = threadIdx.x >> 6;
    if (lane == 0) red[wv] = s;
    __syncthreads();
    if (threadIdx.x == 0) {
        double m = (red[0] + red[1] + red[2] + red[3]) / (double)OUT_N;
        out[OUT_N] = (float)(m + 0.25 * m);
    }
}

// ======================= FALLBACK PATH (small ws) ===========================
__global__ __launch_bounds__(256) void corr_kernel_fb(const float* __restrict__ x,
                                                      const float* __restrict__ D,
                                                      const float* __restrict__ gram,
                                                      int* __restrict__ sup_out,
                                                      float* __restrict__ val_out) {
    __shared__ float pt[256 * MT];
    __shared__ float corrbuf[MT][NATOMS];
    __shared__ int   sup_s[MT][KSP];
    __shared__ float rhs_s[MT][KSP];

    const int tid  = threadIdx.x;
    const int lane = tid & 63;
    const int wave = tid >> 6;
    const int n0   = blockIdx.x * MT;
    const int sp  = lane & 15;
    const int spr = lane >> 4;

    int n = n0 + sp;
    bool pvalid = (n < NPATCH);
    int b = 0, ho = 0, wo = 0;
    if (pvalid) {
        b = n / (HO_ * WO_);
        int r = n - b * (HO_ * WO_);
        ho = r / WO_;
        wo = r - ho * WO_;
    }

    f32x2 accP[2][8];
#pragma unroll
    for (int a = 0; a < 2; ++a)
#pragma unroll
        for (int g = 0; g < 8; ++g) accP[a][g] = (f32x2)(0.f);

    for (int chunk = 0; chunk < 4; ++chunk) {
        __syncthreads();
#pragma unroll
        for (int t = 0; t < 4; ++t) {
            int s = wave + 4 * t;
            int c = chunk * 16 + s;
            float2 va = make_float2(0.f, 0.f), vb = make_float2(0.f, 0.f);
            if (pvalid) {
                const float* px = x + (((size_t)b * CHN + c) * HH + (2 * ho + spr)) * WW + 2 * wo;
                va = *(const float2*)px;
                vb = *(const float2*)(px + 2);
            }
            int kl = (s * 16 + spr * 4) * MT + sp;
            pt[kl]          = va.x;
            pt[kl + MT]     = va.y;
            pt[kl + 2 * MT] = vb.x;
            pt[kl + 3 * MT] = vb.y;
        }
        __syncthreads();
        const float* Dp = D + (size_t)chunk * 256 * NATOMS + 2 * tid;
#pragma unroll 4
        for (int k = 0; k < 256; ++k) {
            float2 dv = *(const float2*)(Dp + (size_t)k * NATOMS);
            f32x2 d00 = {dv.x, dv.x}, d11 = {dv.y, dv.y};
#pragma unroll
            for (int q = 0; q < 4; ++q) {
                const float4 f = *(const float4*)&pt[k * MT + 4 * q];
                f32x2 flo = {f.x, f.y}, fhi = {f.z, f.w};
                accP[0][2 * q]     = fma2(flo, d00, accP[0][2 * q]);
                accP[1][2 * q]     = fma2(flo, d11, accP[1][2 * q]);
                accP[0][2 * q + 1] = fma2(fhi, d00, accP[0][2 * q + 1]);
                accP[1][2 * q + 1] = fma2(fhi, d11, accP[1][2 * q + 1]);
            }
        }
    }
#pragma unroll
    for (int g = 0; g < 8; ++g) {
        *(float2*)&corrbuf[2 * g][2 * tid]     = make_float2(accP[0][g].x, accP[1][g].x);
        *(float2*)&corrbuf[2 * g + 1][2 * tid] = make_float2(accP[0][g].y, accP[1][g].y);
    }
    __syncthreads();

    for (int pi = 0; pi < 4; ++pi) {
        int p  = wave * 4 + pi;
        int np = n0 + p;
        if (np >= NPATCH) continue;
        float v[8], av[8];
#pragma unroll
        for (int i = 0; i < 8; ++i) {
            v[i]  = corrbuf[p][lane + 64 * i];
            av[i] = fabsf(v[i]);
        }
        unsigned usedm = 0u;
        int   top_i[KSP];
        float top_v[KSP];
#pragma unroll
        for (int r = 0; r < KSP; ++r) {
            float ba = -1.0f, bv = 0.0f;
            int   bi = 0x7FFFFFFF;
#pragma unroll
            for (int i = 0; i < 8; ++i) {
                if (!((usedm >> i) & 1u)) {
                    int idx = lane + 64 * i;
                    if (av[i] > ba || (av[i] == ba && idx < bi)) { ba = av[i]; bi = idx; bv = v[i]; }
                }
            }
            for (int off = 32; off; off >>= 1) {
                float oa = __shfl_xor(ba, off);
                int   oi = __shfl_xor(bi, off);
                float ov = __shfl_xor(bv, off);
                if (oa > ba || (oa == ba && oi < bi)) { ba = oa; bi = oi; bv = ov; }
            }
            top_i[r] = bi; top_v[r] = bv;
            if (lane == (bi & 63)) usedm |= (1u << (bi >> 6));
        }
        const float a5 = fabsf(top_v[KSP - 1]);
        const float lo = a5 - DELTA, hi = a5 + DELTA;
        int   nfinal = 0, fidx[KSP];
        float fval[KSP];
        int   nwin = 0, widx[8];
        float wvf[8];
#pragma unroll
        for (int r = 0; r < KSP; ++r) {
            if (fabsf(top_v[r]) > hi) { fidx[nfinal] = top_i[r]; fval[nfinal] = top_v[r]; ++nfinal; }
            else if (nwin < 8)        { widx[nwin] = top_i[r]; wvf[nwin] = top_v[r]; ++nwin; }
        }
#pragma unroll
        for (int i = 0; i < 8; ++i) {
            bool ex = (((usedm >> i) & 1u) == 0u) && (av[i] >= lo);
            unsigned long long m = __ballot(ex);
            while (m && nwin < 8) {
                int l = __ffsll(m) - 1; m &= m - 1;
                widx[nwin] = l + 64 * i;
                wvf[nwin]  = __shfl(v[i], l);
                ++nwin;
            }
        }
        const int need = KSP - nfinal;
        if (nwin == need) {
            for (int w = 0; w < nwin; ++w) { fidx[nfinal] = widx[w]; fval[nfinal] = wvf[w]; ++nfinal; }
        } else {
            int bb_ = np / (HO_ * WO_);
            int rr  = np - bb_ * (HO_ * WO_);
            int ho2 = rr / WO_;
            int wo2 = rr - ho2 * WO_;
            const float* xb = x + (size_t)bb_ * CHN * HH * WW;
            double wv64[8];
            for (int w = 0; w < nwin; ++w) {
                int a = widx[w];
                double s = 0.0;
                for (int t = 0; t < 16; ++t) {
                    int k  = lane + (t << 6);
                    int c  = k >> 4, pr = (k >> 2) & 3, pc = k & 3;
                    float xv = xb[((size_t)c * HH + (2 * ho2 + pr)) * WW + 2 * wo2 + pc];
                    float dv = D[(size_t)k * NATOMS + a];
                    s = fma((double)xv, (double)dv, s);
                }
                for (int off = 32; off; off >>= 1) s += __shfl_xor(s, off);
                wv64[w] = s;
            }
            unsigned taken = 0u;
            for (int scnt = 0; scnt < need; ++scnt) {
                int best = -1; double bbv = -1.0;
                for (int w = 0; w < nwin; ++w) {
                    if ((taken >> w) & 1u) continue;
                    double aw = fabs(wv64[w]);
                    if (aw > bbv || (aw == bbv && best >= 0 && widx[w] < widx[best])) { bbv = aw; best = w; }
                }
                taken |= 1u << best;
                fidx[nfinal] = widx[best];
                fval[nfinal] = (float)wv64[best];
                ++nfinal;
            }
        }
        if (lane == 0) {
#pragma unroll
            for (int r = 0; r < KSP; ++r) { sup_s[p][r] = fidx[r]; rhs_s[p][r] = fval[r]; }
        }
    }
    __syncthreads();

    if (tid < MT) {
        int p = tid, np = n0 + p;
        if (np < NPATCH) {
            int s[KSP];
            double A[KSP][KSP], bb[KSP];
#pragma unroll
            for (int i = 0; i < KSP; ++i) { s[i] = sup_s[p][i]; bb[i] = (double)rhs_s[p][i]; }
#pragma unroll
            for (int i = 0; i < KSP; ++i)
#pragma unroll
                for (int j = 0; j < KSP; ++j)
                    A[i][j] = (double)gram[(size_t)s[i] * NATOMS + s[j]] + (i == j ? 1e-10 : 0.0);
#pragma unroll
            for (int c = 0; c < KSP; ++c) {
                double inv = 1.0 / A[c][c];
#pragma unroll
                for (int r = 0; r < KSP; ++r) {
                    if (r > c) {
                        double f = A[r][c] * inv;
#pragma unroll
                        for (int cc = 0; cc < KSP; ++cc)
                            if (cc > c) A[r][cc] -= f * A[c][cc];
                        bb[r] -= f * bb[c];
                    }
                }
            }
#pragma unroll
            for (int r = KSP - 1; r >= 0; --r) {
                double t = bb[r];
#pragma unroll
                for (int cc = 0; cc < KSP; ++cc)
                    if (cc > r) t -= A[r][cc] * bb[cc];
                bb[r] = t / A[r][r];
            }
#pragma unroll
            for (int i = 0; i < KSP; ++i) {
                sup_out[(size_t)np * KSP + i] = s[i];
                val_out[(size_t)np * KSP + i] = (float)bb[i];
            }
        }
    }
}

__global__ __launch_bounds__(256) void recon_kernel_fb(const float* __restrict__ x,
                                                       const float* __restrict__ D,
                                                       const int* __restrict__ sup,
                                                       const float* __restrict__ val,
                                                       float* __restrict__ out,
                                                       double* __restrict__ partials) {
    double sqacc = 0.0;
    for (size_t o = (size_t)blockIdx.x * 256 + threadIdx.x; o < OUT_N; o += (size_t)FBLK * 256) {
        const int j = (int)(o & 127);
        const int i = (int)((o >> 7) & 127);
        const int c = (int)((o >> 14) & 63);
        const int b = (int)(o >> 20);
        const float xv = x[o];
        float z = 0.0f;
        const int pr = (i & 1) ? 1 : 2;
        const int pc = (j & 1) ? 1 : 2;
        const int ho = (i - pr) >> 1;
        const int wo = (j - pc) >> 1;
        if (ho >= 0 && ho < HO_ && wo >= 0 && wo < WO_) {
            const int n = (b * HO_ + ho) * WO_ + wo;
            const int k = c * 16 + pr * 4 + pc;
            const int*   sp5 = sup + (size_t)n * KSP;
            const float* vp5 = val + (size_t)n * KSP;
            float s = 0.0f;
#pragma unroll
            for (int t = 0; t < KSP; ++t)
                s = fmaf(vp5[t], D[(size_t)k * NATOMS + sp5[t]], s);
            z = s;
        }
        out[o] = xv + (z - xv);
        const float d = z - xv;
        sqacc += (double)d * (double)d;
    }
    for (int off = 32; off; off >>= 1) sqacc += __shfl_xor(sqacc, off);
    __shared__ double red[4];
    const int lane = threadIdx.x & 63, wv = threadIdx.x >> 6;
    if (lane == 0) red[wv] = sqacc;
    __syncthreads();
    if (threadIdx.x == 0) partials[blockIdx.x] = red[0] + red[1] + red[2] + red[3];
}

__global__ __launch_bounds__(256) void loss_kernel(const double* __restrict__ partials,
                                                   float* __restrict__ out) {
    double s = 0.0;
    for (int i = threadIdx.x; i < FBLK; i += 256) s += partials[i];
    for (int off = 32; off; off >>= 1) s += __shfl_xor(s, off);
    __shared__ double red[4];
    const int lane = threadIdx.x & 63, wv = threadIdx.x >> 6;
    if (lane == 0) red[wv] = s;
    __syncthreads();
    if (threadIdx.x == 0) {
        double m = (red[0] + red[1] + red[2] + red[3]) / (double)OUT_N;
        out[OUT_N] = (float)(m + 0.25 * m);
    }
}

// ---------------------------------------------------------------------------
extern "C" void kernel_launch(void* const* d_in, const int* in_sizes, int n_in,
                              void* d_out, int out_size, void* d_ws, size_t ws_size,
                              hipStream_t stream) {
    const float* x = (const float*)d_in[0];
    const float* D = (const float*)d_in[1];
    float* out = (float*)d_out;
    char* ws = (char*)d_ws;

    size_t off = 0;
    auto take = [&](size_t bytes) { char* p = ws + off; off += (bytes + 255) & ~(size_t)255; return p; };
    float*    gram     = (float*)take((size_t)NATOMS * NATOMS * 4);
    int*      sup      = (int*)take((size_t)NPATCH * KSP * 4);
    float*    val      = (float*)take((size_t)NPATCH * KSP * 4);
    double*   partials = (double*)take((size_t)FBLK * 8);
    double*   rpart    = (double*)take((size_t)RPB * 8);
    double*   bpart    = (double*)take((size_t)512 * 8);
    double*   bpart2   = (double*)take((size_t)512 * 8);
    unsigned* topk     = (unsigned*)take((size_t)NPATCH * 16 * 4);
    f16*   Dth  = (f16*)take((size_t)NATOMS * PDIM * 2);
    f16*   Dtl  = (f16*)take((size_t)NATOMS * PDIM * 2);
    f16*   Dqi  = (f16*)take((size_t)NATOMS * CHN * 8 * 2);
    f16*   Xh   = (f16*)take((size_t)MPAD * PDIM * 2);
    f16*   corr = (f16*)take((size_t)MPAD * NATOMS * 2);
    const bool big = (off <= ws_size);

    if (big) {
        hipMemsetAsync(Xh + (size_t)NPATCH * PDIM, 0,
                       (size_t)(MPAD - NPATCH) * PDIM * sizeof(f16), stream);
        extract_kernel<<<8 * HO_ * 4, 256, 0, stream>>>(x, Xh);
        dtrans_kernel<<<dim3(16, 8), 256, 0, stream>>>(D, Dth, Dtl, Dqi);
        gram_kernel<<<dim3(16, 16), 256, 0, stream>>>(D, gram);
        border_kernel<<<512, 64, 0, stream>>>(x, out, bpart);
        border2_kernel<<<512, 256, 0, stream>>>(x, out, bpart2);
        gemm_kernel<<<512, 512, 0, stream>>>(Xh, Dth, corr);
        topred_kernel<<<(NPATCH + 15) / 16, 512, 0, stream>>>(corr, topk);
        topfin_kernel<<<NPATCH / 2, 64, 0, stream>>>(topk, corr, x, D, gram, sup, val);
        reconp_kernel<<<RPB, 256, 0, stream>>>(x, Dqi, sup, val, out, rpart);
        loss2_kernel<<<1, 256, 0, stream>>>(rpart, bpart, bpart2, out);
    } else {
        gram_kernel<<<dim3(16, 16), 256, 0, stream>>>(D, gram);
        corr_kernel_fb<<<(NPATCH + MT - 1) / MT, 256, 0, stream>>>(x, D, gram, sup, val);
        recon_kernel_fb<<<FBLK, 256, 0, stream>>>(x, D, sup, val, out, partials);
        loss_kernel<<<1, 256, 0, stream>>>(partials, out);
    }
}

// Round 28
// 185.638 us; speedup vs baseline: 1.3536x; 1.0283x over previous
//
#include <hip/hip_runtime.h>

#define CHN    64
#define NATOMS 512
#define PDIM   1024
#define KSP    5
#define HO_    63
#define WO_    63
#define NPATCH 31752
#define MPAD   31872          // 249 * 128
#define HH     128
#define WW     128
#define MT     16
#define OUT_N  8388608
#define DELTA  6e-3f
#define QGUARD 2.5e-3f
#define FBLK   2048
#define RPB    (8 * HO_ * 4)  // 2016 reconp blocks: (b, ho, channel-group)

typedef _Float16 f16;
typedef _Float16 f16x8 __attribute__((ext_vector_type(8)));
typedef _Float16 f16x4 __attribute__((ext_vector_type(4)));
typedef float    f32x4 __attribute__((ext_vector_type(4)));
typedef float    f32x2 __attribute__((ext_vector_type(2)));

static __device__ __forceinline__ void gload_lds16(const void* g, void* l) {
    __builtin_amdgcn_global_load_lds(
        (const __attribute__((address_space(1))) unsigned int*)g,
        (__attribute__((address_space(3))) unsigned int*)l, 16, 0, 0);
}

static __device__ inline f32x2 fma2(f32x2 a, f32x2 b, f32x2 c) {
#if __has_builtin(__builtin_elementwise_fma)
    return __builtin_elementwise_fma(a, b, c);
#else
    f32x2 r; r.x = fmaf(a.x, b.x, c.x); r.y = fmaf(a.y, b.y, c.y); return r;
#endif
}

// ---- u32 key: (abs>>11)<<11 | (1023-idx)<<1 | sign ----
static __device__ __forceinline__ unsigned mk_key32(float v, int idx) {
    unsigned vb = __float_as_uint(v);
    unsigned ab = vb & 0x7FFFFFFFu;
    return ((ab >> 11) << 11) | ((unsigned)(1023 - idx) << 1) | (vb >> 31);
}
static __device__ __forceinline__ int key32_idx(unsigned k) {
    return 1023 - (int)((k >> 1) & 1023u);
}

#define CEU(s, i, j) { unsigned _a = s[i], _b = s[j]; \
                       s[i] = _a > _b ? _a : _b; s[j] = _a > _b ? _b : _a; }

#define SORT8(s) \
    CEU(s,0,1) CEU(s,2,3) CEU(s,4,5) CEU(s,6,7) \
    CEU(s,0,2) CEU(s,1,3) CEU(s,4,6) CEU(s,5,7) \
    CEU(s,1,2) CEU(s,5,6) \
    CEU(s,0,4) CEU(s,1,5) CEU(s,2,6) CEU(s,3,7) \
    CEU(s,2,4) CEU(s,3,5) \
    CEU(s,1,2) CEU(s,3,4) CEU(s,5,6)

#define MERGE8(s, a, b) { \
    unsigned L[8]; \
    L[0] = a[0] > b[7] ? a[0] : b[7]; L[1] = a[1] > b[6] ? a[1] : b[6]; \
    L[2] = a[2] > b[5] ? a[2] : b[5]; L[3] = a[3] > b[4] ? a[3] : b[4]; \
    L[4] = a[4] > b[3] ? a[4] : b[3]; L[5] = a[5] > b[2] ? a[5] : b[2]; \
    L[6] = a[6] > b[1] ? a[6] : b[1]; L[7] = a[7] > b[0] ? a[7] : b[0]; \
    CEU(L,0,4) CEU(L,1,5) CEU(L,2,6) CEU(L,3,7) \
    CEU(L,0,2) CEU(L,1,3) CEU(L,4,6) CEU(L,5,7) \
    CEU(L,0,1) CEU(L,2,3) CEU(L,4,5) CEU(L,6,7) \
    for (int _i = 0; _i < 8; ++_i) s[_i] = L[_i]; }

// ---------------- gram = D^T D, 32x32 tiles, fp32 accumulate ----------------
__global__ __launch_bounds__(256) void gram_kernel(const float* __restrict__ D,
                                                   float* __restrict__ gram) {
    __shared__ float Ti[64][32];
    __shared__ float Tj[64][32];
    const int tid = threadIdx.x;
    const int i0 = blockIdx.x * 32, j0 = blockIdx.y * 32;
    const int ri  = tid >> 3;
    const int rj0 = (tid & 7) * 4;
    float acc[4] = {0.f, 0.f, 0.f, 0.f};
    for (int k0 = 0; k0 < PDIM; k0 += 64) {
        __syncthreads();
#pragma unroll
        for (int s = 0; s < 8; ++s) {
            int e = tid + 256 * s;
            int kk = e >> 5, col = e & 31;
            Ti[kk][col] = D[(size_t)(k0 + kk) * NATOMS + i0 + col];
            Tj[kk][col] = D[(size_t)(k0 + kk) * NATOMS + j0 + col];
        }
        __syncthreads();
#pragma unroll 4
        for (int kk = 0; kk < 64; ++kk) {
            float ti = Ti[kk][ri];
#pragma unroll
            for (int q = 0; q < 4; ++q)
                acc[q] = fmaf(ti, Tj[kk][rj0 + q], acc[q]);
        }
    }
#pragma unroll
    for (int q = 0; q < 4; ++q)
        gram[(size_t)(i0 + ri) * NATOMS + j0 + rj0 + q] = acc[q];
}

// ------------- patch extraction (coalesced): x -> Xh [MPAD][1024] f16 -------
__global__ __launch_bounds__(256) void extract_kernel(const float* __restrict__ x,
                                                      f16* __restrict__ Xh) {
    __shared__ float xs[16][4][129];
    const int bid = blockIdx.x;
    const int cg  = bid & 3;
    const int t   = bid >> 2;
    const int ho  = t % HO_;
    const int b   = t / HO_;

    for (int i = threadIdx.x; i < 64 * 32; i += 256) {
        int r = i >> 5;
        int q = i & 31;
        int c = r >> 2, pr = r & 3;
        float4 v = *(const float4*)(x + ((size_t)(b * CHN + cg * 16 + c) * HH
                                         + (2 * ho + pr)) * WW + q * 4);
        xs[c][pr][q * 4 + 0] = v.x;
        xs[c][pr][q * 4 + 1] = v.y;
        xs[c][pr][q * 4 + 2] = v.z;
        xs[c][pr][q * 4 + 3] = v.w;
    }
    __syncthreads();

    for (int p = threadIdx.x; p < WO_ * 16; p += 256) {
        int wo = p >> 4;
        int c  = p & 15;
        f16 h[16];
#pragma unroll
        for (int pr = 0; pr < 4; ++pr)
#pragma unroll
            for (int pc = 0; pc < 4; ++pc)
                h[pr * 4 + pc] = (f16)xs[c][pr][2 * wo + pc];
        int n = (b * HO_ + ho) * WO_ + wo;
        f16x8 v0, v1;
#pragma unroll
        for (int i2 = 0; i2 < 8; ++i2) { v0[i2] = h[i2]; v1[i2] = h[8 + i2]; }
        f16* dh = Xh + (size_t)n * PDIM + (cg * 16 + c) * 16;
        *(f16x8*)dh = v0; *(f16x8*)(dh + 8) = v1;
    }
}

// ------------- D -> Dt transpose via LDS tiles (coalesced both sides) -------
// Also emits the compact interleaved inner-2x2 dictionary Dqi[atom][c][8] f16
// = {h5,h6,h9,h10, l5,l6,l9,l10} for reconp (one 16B load per atom).
__global__ __launch_bounds__(256) void dtrans_kernel(const float* __restrict__ D,
                                                     f16* __restrict__ Dth,
                                                     f16* __restrict__ Dtl,
                                                     f16* __restrict__ Dqi) {
    __shared__ float ts[64][65];
    const int k0 = blockIdx.x * 64;
    const int n0 = blockIdx.y * 64;

    for (int i = threadIdx.x; i < 64 * 16; i += 256) {
        int r = i >> 4;
        int q = i & 15;
        float4 v = *(const float4*)(D + (size_t)(k0 + r) * NATOMS + n0 + q * 4);
        ts[r][q * 4 + 0] = v.x;
        ts[r][q * 4 + 1] = v.y;
        ts[r][q * 4 + 2] = v.z;
        ts[r][q * 4 + 3] = v.w;
    }
    __syncthreads();

    {
        int i = threadIdx.x;
        int nn = i >> 2, q = i & 3;
        f16 h[16], l[16];
#pragma unroll
        for (int j = 0; j < 16; ++j) {
            float v = ts[q * 16 + j][nn];
            f16 hh = (f16)v;
            h[j] = hh;
            l[j] = (f16)(v - (float)hh);
        }
        f16x8 h0, h1, l0, l1;
#pragma unroll
        for (int j = 0; j < 8; ++j) { h0[j] = h[j]; h1[j] = h[8 + j]; l0[j] = l[j]; l1[j] = l[8 + j]; }
        f16* dh = Dth + (size_t)(n0 + nn) * PDIM + k0 + q * 16;
        f16* dl = Dtl + (size_t)(n0 + nn) * PDIM + k0 + q * 16;
        *(f16x8*)dh = h0; *(f16x8*)(dh + 8) = h1;
        *(f16x8*)dl = l0; *(f16x8*)(dl + 8) = l1;

        // compact interleaved inner-2x2: channel c = k0/16 + q
        const int c = (k0 >> 4) + q;
        f16x8 qi = { h[5], h[6], h[9], h[10], l[5], l[6], l[9], l[10] };
        *(f16x8*)(Dqi + ((size_t)(n0 + nn) * CHN + c) * 8) = qi;
    }
}

// ------------- MFMA GEMM: corr[MPAD][512] (f16) = Xh . Dth^T ----------------
// 1D grid, XCD-paired mapping: the two 256-col blocks sharing the same 128
// A-rows are bids (b, b+8) -> same XCD under %8 round-robin -> 2nd A read
// hits that XCD's L2 instead of HBM.
__global__ __launch_bounds__(512) void gemm_kernel(const f16* __restrict__ Xh,
                                                   const f16* __restrict__ Dth,
                                                   f16* __restrict__ corr) {
    __shared__ char lds[98304];
    const int bid = blockIdx.x;
    const int xcd = bid & 7;
    const int jj  = bid >> 3;
    const int m   = (jj >> 1) * 8 + xcd;
    if (m >= MPAD / 128) return;
    const int tid  = threadIdx.x;
    const int lane = tid & 63;
    const int wave = tid >> 6;
    const size_t arow0 = (size_t)m * 128;
    const int    brow0 = (jj & 1) * 256;
    const int wm = wave >> 2;
    const int wn = wave & 3;

    f32x4 acc[4][4];
#pragma unroll
    for (int mm = 0; mm < 4; ++mm)
#pragma unroll
        for (int n = 0; n < 4; ++n) acc[mm][n] = (f32x4){0.f, 0.f, 0.f, 0.f};

    const char* asrc[2]; int adst[2];
#pragma unroll
    for (int i = 0; i < 2; ++i) {
        int p = tid * 16 + i * 8192;
        int row = p >> 7, sc = ((p >> 4) & 7) ^ (row & 7);
        asrc[i] = (const char*)Xh + (arow0 + row) * 2048 + sc * 16;
        adst[i] = p;
    }
    const char* bsrc[4]; int bdst[4];
#pragma unroll
    for (int i = 0; i < 4; ++i) {
        int p = tid * 16 + i * 8192;
        int row = p >> 7, sc = ((p >> 4) & 7) ^ (row & 7);
        bsrc[i] = (const char*)Dth + (size_t)(brow0 + row) * 2048 + sc * 16;
        bdst[i] = 16384 + p;
    }

    int aoff[4][2], boff[4][2];
#pragma unroll
    for (int mm = 0; mm < 4; ++mm)
#pragma unroll
        for (int ks = 0; ks < 2; ++ks) {
            int row = wm * 64 + mm * 16 + (lane & 15);
            int ch  = (ks * 4 + (lane >> 4)) ^ (row & 7);
            aoff[mm][ks] = row * 128 + ch * 16;
        }
#pragma unroll
    for (int n = 0; n < 4; ++n)
#pragma unroll
        for (int ks = 0; ks < 2; ++ks) {
            int row = wn * 64 + n * 16 + (lane & 15);
            int ch  = (ks * 4 + (lane >> 4)) ^ (row & 7);
            boff[n][ks] = 16384 + row * 128 + ch * 16;
        }

#pragma unroll
    for (int i = 0; i < 2; ++i) gload_lds16(asrc[i], lds + adst[i]);
#pragma unroll
    for (int i = 0; i < 4; ++i) gload_lds16(bsrc[i], lds + bdst[i]);
#pragma unroll
    for (int i = 0; i < 2; ++i) asrc[i] += 128;
#pragma unroll
    for (int i = 0; i < 4; ++i) bsrc[i] += 128;
    __syncthreads();

    int bufo = 0;
    for (int kt = 0; kt < 16; ++kt) {
        const int nbuf = bufo ^ 49152;
        if (kt + 1 < 16) {
#pragma unroll
            for (int i = 0; i < 2; ++i) { gload_lds16(asrc[i], lds + nbuf + adst[i]); asrc[i] += 128; }
#pragma unroll
            for (int i = 0; i < 4; ++i) { gload_lds16(bsrc[i], lds + nbuf + bdst[i]); bsrc[i] += 128; }
        }
#pragma unroll
        for (int ks = 0; ks < 2; ++ks) {
            f16x8 a[4], b[4];
#pragma unroll
            for (int mm = 0; mm < 4; ++mm) a[mm] = *(const f16x8*)(lds + bufo + aoff[mm][ks]);
#pragma unroll
            for (int n = 0; n < 4; ++n) b[n] = *(const f16x8*)(lds + bufo + boff[n][ks]);
#pragma unroll
            for (int mm = 0; mm < 4; ++mm)
#pragma unroll
                for (int n = 0; n < 4; ++n)
                    acc[mm][n] = __builtin_amdgcn_mfma_f32_16x16x32_f16(a[mm], b[n], acc[mm][n], 0, 0, 0);
        }
        if (kt + 1 < 16) { __syncthreads(); bufo = nbuf; }
    }

#pragma unroll
    for (int mm = 0; mm < 4; ++mm) {
        size_t row_b = arow0 + wm * 64 + mm * 16 + (lane >> 4) * 4;
#pragma unroll
        for (int n = 0; n < 4; ++n) {
            int col = brow0 + wn * 64 + n * 16 + (lane & 15);
#pragma unroll
            for (int i = 0; i < 4; ++i)
                corr[(row_b + i) * NATOMS + col] = (f16)acc[mm][n][i];
        }
    }
}

// ------- phase 1: sorted top-8 keys + values (f16 corr, cache-hot) ----------
__global__ __launch_bounds__(512) void topred_kernel(const f16* __restrict__ corr,
                                                     unsigned* __restrict__ topk) {
    const int tid = threadIdx.x;
    const int sl  = tid & 31;
    const int hw  = tid >> 5;                 // half-wave 0..15
    const int np  = blockIdx.x * 16 + hw;     // may run into pad rows (< MPAD)

    const f16* row = corr + (size_t)np * NATOMS;
    const f16* cr = row + sl * 16;
    f16x8 c0 = *(const f16x8*)cr;
    f16x8 c1 = *(const f16x8*)(cr + 8);
    unsigned k[16];
#pragma unroll
    for (int j = 0; j < 8; ++j) {
        k[j]     = mk_key32((float)c0[j], sl * 16 + j);
        k[8 + j] = mk_key32((float)c1[j], sl * 16 + 8 + j);
    }

    unsigned a[8], b8[8];
#pragma unroll
    for (int i = 0; i < 8; ++i) { a[i] = k[i]; b8[i] = k[8 + i]; }
    SORT8(a)
    SORT8(b8)
    unsigned s[8];
    MERGE8(s, a, b8)
#pragma unroll
    for (int off = 16; off; off >>= 1) {
        unsigned p[8];
#pragma unroll
        for (int i = 0; i < 8; ++i) p[i] = (unsigned)__shfl_xor((int)s[i], off);
        MERGE8(s, s, p)
    }

    if (sl == 0 && np < NPATCH) {
        float v0 = (float)row[key32_idx(s[0])], v1 = (float)row[key32_idx(s[1])];
        float v2 = (float)row[key32_idx(s[2])], v3 = (float)row[key32_idx(s[3])];
        float v4 = (float)row[key32_idx(s[4])], v5 = (float)row[key32_idx(s[5])];
        float v6 = (float)row[key32_idx(s[6])], v7 = (float)row[key32_idx(s[7])];
        uint4* dst = (uint4*)(topk + (size_t)np * 16);
        dst[0] = make_uint4(s[0], s[1], s[2], s[3]);
        dst[1] = make_uint4(s[4], s[5], s[6], s[7]);
        dst[2] = make_uint4(__float_as_uint(v0), __float_as_uint(v1),
                            __float_as_uint(v2), __float_as_uint(v3));
        dst[3] = make_uint4(__float_as_uint(v4), __float_as_uint(v5),
                            __float_as_uint(v6), __float_as_uint(v7));
    }
}

// ------- phase 2: 64-thr blocks; parallel gram gather; unrolled arbitration -
__global__ __launch_bounds__(64) void topfin_kernel(const unsigned* __restrict__ topk,
                                                    const f16* __restrict__ corr,
                                                    const float* __restrict__ x,
                                                    const float* __restrict__ D,
                                                    const float* __restrict__ gram,
                                                    int* __restrict__ sup_out,
                                                    float* __restrict__ val_out) {
    const int lane = threadIdx.x & 63;
    const int half = lane >> 5;
    const int sl   = lane & 31;
    const int hw   = threadIdx.x >> 5;        // 0..1
    const int np   = blockIdx.x * 2 + hw;     // grid*2 == NPATCH exactly

    unsigned s[8];
    float    tval[8];
    {
        const uint4* src = (const uint4*)(topk + (size_t)np * 16);
        uint4 s0 = src[0], s1 = src[1], v0 = src[2], v1 = src[3];
        s[0] = s0.x; s[1] = s0.y; s[2] = s0.z; s[3] = s0.w;
        s[4] = s1.x; s[5] = s1.y; s[6] = s1.z; s[7] = s1.w;
        tval[0] = __uint_as_float(v0.x); tval[1] = __uint_as_float(v0.y);
        tval[2] = __uint_as_float(v0.z); tval[3] = __uint_as_float(v0.w);
        tval[4] = __uint_as_float(v1.x); tval[5] = __uint_as_float(v1.y);
        tval[6] = __uint_as_float(v1.z); tval[7] = __uint_as_float(v1.w);
    }
    int tidx[8];
#pragma unroll
    for (int r = 0; r < 8; ++r) tidx[r] = key32_idx(s[r]);

    const float a5 = fabsf(tval[KSP - 1]);
    const float lo = fmaxf(a5 - DELTA, 0.0f);
    const float hi = a5 + DELTA;
    const unsigned lokey = (__float_as_uint(fmaxf(lo - QGUARD, 0.0f)) >> 11) << 11;

    int   nfinal = 0, fidx[KSP];
    float fval[KSP];
    int   nwin = 0, widx[8];
    float wvf[8];
#pragma unroll
    for (int r = 0; r < KSP; ++r) {
        if (fabsf(tval[r]) > hi) { fidx[nfinal] = tidx[r]; fval[nfinal] = tval[r]; ++nfinal; }
        else                     { widx[nwin] = tidx[r]; wvf[nwin] = tval[r]; ++nwin; }
    }
#pragma unroll
    for (int r = KSP; r < 8; ++r) {
        if (fabsf(tval[r]) >= lo && nwin < 8) { widx[nwin] = tidx[r]; wvf[nwin] = tval[r]; ++nwin; }
    }

    // rescan for extras beyond top-8 (only when the 8th key is inside window)
    if (s[7] >= lokey) {
        const f16* cr = corr + (size_t)np * NATOMS + sl * 16;
        f16x8 c0 = *(const f16x8*)cr;
        f16x8 c1 = *(const f16x8*)(cr + 8);
        unsigned k[16];
        float vbuf[16];
#pragma unroll
        for (int j = 0; j < 8; ++j) {
            vbuf[j]     = (float)c0[j];
            vbuf[8 + j] = (float)c1[j];
            k[j]        = mk_key32(vbuf[j], sl * 16 + j);
            k[8 + j]    = mk_key32(vbuf[8 + j], sl * 16 + 8 + j);
        }
#pragma unroll
        for (int i = 0; i < 16; ++i) {
            bool ex = (k[i] < s[7]) && (k[i] >= lokey);
            unsigned m = (unsigned)(__ballot(ex) >> (half * 32));
            while (m && nwin < 8) {
                int l = __ffs(m) - 1; m &= m - 1;
                unsigned kk = (unsigned)__shfl((int)k[i], l + half * 32);
                float vv2 = __shfl(vbuf[i], l + half * 32);
                if (fabsf(vv2) >= lo) { widx[nwin] = key32_idx(kk); wvf[nwin] = vv2; ++nwin; }
            }
        }
    }

    const int need = KSP - nfinal;
    if (nwin == need) {
        for (int w = 0; w < nwin; ++w) { fidx[nfinal] = widx[w]; fval[nfinal] = wvf[w]; ++nfinal; }
    } else {
        // fp64 arbitration of the boundary window (rare), 32-lane dot
        int bb_ = np / (HO_ * WO_);
        int rr  = np - bb_ * (HO_ * WO_);
        int ho2 = rr / WO_;
        int wo2 = rr - ho2 * WO_;
        const float* xb = x + (size_t)bb_ * CHN * HH * WW;
        double wv64[8];
        for (int w = 0; w < nwin; ++w) {
            int at = widx[w];
            double sd = 0.0;
#pragma unroll
            for (int t = 0; t < 32; ++t) {
                int kk = sl + (t << 5);
                int c  = kk >> 4, pr = (kk >> 2) & 3, pc = kk & 3;
                float xv = xb[((size_t)c * HH + (2 * ho2 + pr)) * WW + 2 * wo2 + pc];
                float dv = D[(size_t)kk * NATOMS + at];
                sd = fma((double)xv, (double)dv, sd);
            }
            for (int off = 16; off; off >>= 1) sd += __shfl_xor(sd, off);
            wv64[w] = sd;
        }
        unsigned taken = 0u;
        for (int scnt = 0; scnt < need; ++scnt) {
            int best = -1; double bbv = -1.0;
            for (int w = 0; w < nwin; ++w) {
                if ((taken >> w) & 1u) continue;
                double aw = fabs(wv64[w]);
                if (aw > bbv || (aw == bbv && best >= 0 && widx[w] < widx[best])) { bbv = aw; best = w; }
            }
            taken |= 1u << best;
            fidx[nfinal] = widx[best];
            fval[nfinal] = (float)wv64[best];
            ++nfinal;
        }
    }

    // ---- 5x5 solve (fp32); gram gathered in PARALLEL across lanes ----
    float A[KSP][KSP], bb[KSP];
    {
        float gv = 0.f;
        if (sl < 25) {
            int gi = sl / 5, gj = sl - 5 * gi;
            gv = gram[(size_t)fidx[gi] * NATOMS + fidx[gj]];
        }
#pragma unroll
        for (int i = 0; i < KSP; ++i)
#pragma unroll
            for (int j = 0; j < KSP; ++j)
                A[i][j] = __shfl(gv, i * 5 + j + half * 32);
    }
#pragma unroll
    for (int i = 0; i < KSP; ++i) bb[i] = fval[i];
#pragma unroll
    for (int c = 0; c < KSP; ++c) {
        float inv = 1.0f / A[c][c];
#pragma unroll
        for (int r = 0; r < KSP; ++r) {
            if (r > c) {
                float f = A[r][c] * inv;
#pragma unroll
                for (int cc = 0; cc < KSP; ++cc)
                    if (cc > c) A[r][cc] -= f * A[c][cc];
                bb[r] -= f * bb[c];
            }
        }
    }
#pragma unroll
    for (int r = KSP - 1; r >= 0; --r) {
        float t = bb[r];
#pragma unroll
        for (int cc = 0; cc < KSP; ++cc)
            if (cc > r) t -= A[r][cc] * bb[cc];
        bb[r] = t / A[r][r];
    }
    if (sl == 0) {
#pragma unroll
        for (int i = 0; i < KSP; ++i) {
            sup_out[(size_t)np * KSP + i] = fidx[i];
            val_out[(size_t)np * KSP + i] = bb[i];
        }
    }
}

// ------- fused reconstruction: (b,ho,cg) blocks, Dqi gather, float4 IO ------
// Thread = (patch p_local, channel c_local); each (patch,channel) computed
// once. z via one 16B Dqi load per atom (bit-identical to the full gather).
// Write phase: two complete image rows (2ho+1, 2ho+2) for this block's 16
// channels, ALL columns (cols 0/127 get z=0 and ARE loss-counted here) --
// pairs exactly with the rows-0/127-only border kernel. No overlap.
__global__ __launch_bounds__(256) void reconp_kernel(const float* __restrict__ x,
                                                     const f16* __restrict__ Dqi,
                                                     const int* __restrict__ sup,
                                                     const float* __restrict__ val,
                                                     float* __restrict__ out,
                                                     double* __restrict__ rpart) {
    __shared__ float zplane[4][WO_][17];      // [pos][wo][c_local], 17 KB
    __shared__ double red[4];
    const int tid  = threadIdx.x;
    const int lane = tid & 63;
    const int wave = tid >> 6;
    const int cg = blockIdx.x & 3;
    const int t2 = blockIdx.x >> 2;
    const int ho = t2 % HO_;
    const int b  = t2 / HO_;
    const int nbase = (b * HO_ + ho) * WO_;
    const int p_local = tid >> 4;             // 0..15
    const int c_local = tid & 15;
    const int c = cg * 16 + c_local;

#pragma unroll
    for (int it = 0; it < 4; ++it) {
        const int wo = it * 16 + p_local;
        if (wo < WO_) {
            const int n = nbase + wo;
            const int*   sp = sup + (size_t)n * KSP;
            const float* vp = val + (size_t)n * KSP;
            float z0 = 0.f, z1 = 0.f, z2 = 0.f, z3 = 0.f;
#pragma unroll
            for (int t = 0; t < KSP; ++t) {
                int a = sp[t]; float v = vp[t];
                f16x8 q = *(const f16x8*)(Dqi + ((size_t)a * CHN + c) * 8);
                z0 = fmaf(v, (float)q[0] + (float)q[4], z0);
                z1 = fmaf(v, (float)q[1] + (float)q[5], z1);
                z2 = fmaf(v, (float)q[2] + (float)q[6], z2);
                z3 = fmaf(v, (float)q[3] + (float)q[7], z3);
            }
            zplane[0][wo][c_local] = z0;      // (pr=1,pc=1)
            zplane[1][wo][c_local] = z1;      // (pr=1,pc=2)
            zplane[2][wo][c_local] = z2;      // (pr=2,pc=1)
            zplane[3][wo][c_local] = z3;      // (pr=2,pc=2)
        }
    }
    __syncthreads();

    double sq = 0.0;
#pragma unroll
    for (int k = 0; k < 4; ++k) {
        int f  = tid + 256 * k;               // 0..1023
        int q  = f & 31;                       // float4 col group 0..31
        int cl = (f >> 5) & 15;
        int r  = f >> 9;                       // 0..1
        const int prof = r * 2;                // row 2ho+1 -> pr=1; 2ho+2 -> pr=2
        float4 zv;
        zv.x = (q == 0)  ? 0.f : zplane[prof + 1][2 * q - 1][cl];
        zv.y = zplane[prof][2 * q][cl];
        zv.z = zplane[prof + 1][2 * q][cl];
        zv.w = (q == 31) ? 0.f : zplane[prof][2 * q + 1][cl];
        size_t base = ((size_t)(b * CHN + cg * 16 + cl) * HH + (2 * ho + 1 + r)) * WW + 4 * q;
        float4 xv = *(const float4*)(x + base);
        float4 ov;
        ov.x = xv.x + (zv.x - xv.x);
        ov.y = xv.y + (zv.y - xv.y);
        ov.z = xv.z + (zv.z - xv.z);
        ov.w = xv.w + (zv.w - xv.w);
        *(float4*)(out + base) = ov;
        float d0 = zv.x - xv.x, d1 = zv.y - xv.y, d2 = zv.z - xv.z, d3 = zv.w - xv.w;
        sq += (double)d0 * d0 + (double)d1 * d1 + (double)d2 * d2 + (double)d3 * d3;
    }

    for (int off = 32; off; off >>= 1) sq += __shfl_xor(sq, off);
    if (lane == 0) red[wave] = sq;
    __syncthreads();
    if (threadIdx.x == 0) rpart[blockIdx.x] = red[0] + red[1] + red[2] + red[3];
}

// ------- border rows 0 and 127 ONLY: out = x + (0 - x), loss += x^2 ---------
// (interior rows' edge columns are fully handled inside reconp)
__global__ __launch_bounds__(64) void border_kernel(const float* __restrict__ x,
                                                    float* __restrict__ out,
                                                    double* __restrict__ bpart) {
    const int plane = blockIdx.x;             // b*CHN + c, 0..511
    const int t = threadIdx.x;                // 0..63: r = t>>5 (row 0/127), q = t&31
    const int r = (t >> 5) ? 127 : 0;
    const int q = t & 31;
    size_t base = (size_t)plane * HH * WW + (size_t)r * WW + 4 * q;
    float4 xv = *(const float4*)(x + base);
    float4 ov;
    ov.x = xv.x + (0.0f - xv.x);
    ov.y = xv.y + (0.0f - xv.y);
    ov.z = xv.z + (0.0f - xv.z);
    ov.w = xv.w + (0.0f - xv.w);
    *(float4*)(out + base) = ov;
    double sq = (double)xv.x * xv.x + (double)xv.y * xv.y
              + (double)xv.z * xv.z + (double)xv.w * xv.w;
    for (int off = 32; off; off >>= 1) sq += __shfl_xor(sq, off);
    if (threadIdx.x == 0) bpart[blockIdx.x] = sq;
}

// ------- loss finalize: sum reconp + border partials ------------------------
__global__ __launch_bounds__(256) void loss2_kernel(const double* __restrict__ rpart,
                                                    const double* __restrict__ bpart,
                                                    float* __restrict__ out) {
    double s = 0.0;
    for (int i = threadIdx.x; i < RPB; i += 256) s += rpart[i];
    for (int i = threadIdx.x; i < 512; i += 256) s += bpart[i];
    for (int off = 32; off; off >>= 1) s += __shfl_xor(s, off);
    __shared__ double red[4];
    const int lane = threadIdx.x & 63, wv = threadIdx.x >> 6;
    if (lane == 0) red[wv] = s;
    __syncthreads();
    if (threadIdx.x == 0) {
        double m = (red[0] + red[1] + red[2] + red[3]) / (double)OUT_N;
        out[OUT_N] = (float)(m + 0.25 * m);
    }
}

// ======================= FALLBACK PATH (small ws) ===========================
__global__ __launch_bounds__(256) void corr_kernel_fb(const float* __restrict__ x,
                                                      const float* __restrict__ D,
                                                      const float* __restrict__ gram,
                                                      int* __restrict__ sup_out,
                                                      float* __restrict__ val_out) {
    __shared__ float pt[256 * MT];
    __shared__ float corrbuf[MT][NATOMS];
    __shared__ int   sup_s[MT][KSP];
    __shared__ float rhs_s[MT][KSP];

    const int tid  = threadIdx.x;
    const int lane = tid & 63;
    const int wave = tid >> 6;
    const int n0   = blockIdx.x * MT;
    const int sp  = lane & 15;
    const int spr = lane >> 4;

    int n = n0 + sp;
    bool pvalid = (n < NPATCH);
    int b = 0, ho = 0, wo = 0;
    if (pvalid) {
        b = n / (HO_ * WO_);
        int r = n - b * (HO_ * WO_);
        ho = r / WO_;
        wo = r - ho * WO_;
    }

    f32x2 accP[2][8];
#pragma unroll
    for (int a = 0; a < 2; ++a)
#pragma unroll
        for (int g = 0; g < 8; ++g) accP[a][g] = (f32x2)(0.f);

    for (int chunk = 0; chunk < 4; ++chunk) {
        __syncthreads();
#pragma unroll
        for (int t = 0; t < 4; ++t) {
            int s = wave + 4 * t;
            int c = chunk * 16 + s;
            float2 va = make_float2(0.f, 0.f), vb = make_float2(0.f, 0.f);
            if (pvalid) {
                const float* px = x + (((size_t)b * CHN + c) * HH + (2 * ho + spr)) * WW + 2 * wo;
                va = *(const float2*)px;
                vb = *(const float2*)(px + 2);
            }
            int kl = (s * 16 + spr * 4) * MT + sp;
            pt[kl]          = va.x;
            pt[kl + MT]     = va.y;
            pt[kl + 2 * MT] = vb.x;
            pt[kl + 3 * MT] = vb.y;
        }
        __syncthreads();
        const float* Dp = D + (size_t)chunk * 256 * NATOMS + 2 * tid;
#pragma unroll 4
        for (int k = 0; k < 256; ++k) {
            float2 dv = *(const float2*)(Dp + (size_t)k * NATOMS);
            f32x2 d00 = {dv.x, dv.x}, d11 = {dv.y, dv.y};
#pragma unroll
            for (int q = 0; q < 4; ++q) {
                const float4 f = *(const float4*)&pt[k * MT + 4 * q];
                f32x2 flo = {f.x, f.y}, fhi = {f.z, f.w};
                accP[0][2 * q]     = fma2(flo, d00, accP[0][2 * q]);
                accP[1][2 * q]     = fma2(flo, d11, accP[1][2 * q]);
                accP[0][2 * q + 1] = fma2(fhi, d00, accP[0][2 * q + 1]);
                accP[1][2 * q + 1] = fma2(fhi, d11, accP[1][2 * q + 1]);
            }
        }
    }
#pragma unroll
    for (int g = 0; g < 8; ++g) {
        *(float2*)&corrbuf[2 * g][2 * tid]     = make_float2(accP[0][g].x, accP[1][g].x);
        *(float2*)&corrbuf[2 * g + 1][2 * tid] = make_float2(accP[0][g].y, accP[1][g].y);
    }
    __syncthreads();

    for (int pi = 0; pi < 4; ++pi) {
        int p  = wave * 4 + pi;
        int np = n0 + p;
        if (np >= NPATCH) continue;
        float v[8], av[8];
#pragma unroll
        for (int i = 0; i < 8; ++i) {
            v[i]  = corrbuf[p][lane + 64 * i];
            av[i] = fabsf(v[i]);
        }
        unsigned usedm = 0u;
        int   top_i[KSP];
        float top_v[KSP];
#pragma unroll
        for (int r = 0; r < KSP; ++r) {
            float ba = -1.0f, bv = 0.0f;
            int   bi = 0x7FFFFFFF;
#pragma unroll
            for (int i = 0; i < 8; ++i) {
                if (!((usedm >> i) & 1u)) {
                    int idx = lane + 64 * i;
                    if (av[i] > ba || (av[i] == ba && idx < bi)) { ba = av[i]; bi = idx; bv = v[i]; }
                }
            }
            for (int off = 32; off; off >>= 1) {
                float oa = __shfl_xor(ba, off);
                int   oi = __shfl_xor(bi, off);
                float ov = __shfl_xor(bv, off);
                if (oa > ba || (oa == ba && oi < bi)) { ba = oa; bi = oi; bv = ov; }
            }
            top_i[r] = bi; top_v[r] = bv;
            if (lane == (bi & 63)) usedm |= (1u << (bi >> 6));
        }
        const float a5 = fabsf(top_v[KSP - 1]);
        const float lo = a5 - DELTA, hi = a5 + DELTA;
        int   nfinal = 0, fidx[KSP];
        float fval[KSP];
        int   nwin = 0, widx[8];
        float wvf[8];
#pragma unroll
        for (int r = 0; r < KSP; ++r) {
            if (fabsf(top_v[r]) > hi) { fidx[nfinal] = top_i[r]; fval[nfinal] = top_v[r]; ++nfinal; }
            else if (nwin < 8)        { widx[nwin] = top_i[r]; wvf[nwin] = top_v[r]; ++nwin; }
        }
#pragma unroll
        for (int i = 0; i < 8; ++i) {
            bool ex = (((usedm >> i) & 1u) == 0u) && (av[i] >= lo);
            unsigned long long m = __ballot(ex);
            while (m && nwin < 8) {
                int l = __ffsll(m) - 1; m &= m - 1;
                widx[nwin] = l + 64 * i;
                wvf[nwin]  = __shfl(v[i], l);
                ++nwin;
            }
        }
        const int need = KSP - nfinal;
        if (nwin == need) {
            for (int w = 0; w < nwin; ++w) { fidx[nfinal] = widx[w]; fval[nfinal] = wvf[w]; ++nfinal; }
        } else {
            int bb_ = np / (HO_ * WO_);
            int rr  = np - bb_ * (HO_ * WO_);
            int ho2 = rr / WO_;
            int wo2 = rr - ho2 * WO_;
            const float* xb = x + (size_t)bb_ * CHN * HH * WW;
            double wv64[8];
            for (int w = 0; w < nwin; ++w) {
                int a = widx[w];
                double s = 0.0;
                for (int t = 0; t < 16; ++t) {
                    int k  = lane + (t << 6);
                    int c  = k >> 4, pr = (k >> 2) & 3, pc = k & 3;
                    float xv = xb[((size_t)c * HH + (2 * ho2 + pr)) * WW + 2 * wo2 + pc];
                    float dv = D[(size_t)k * NATOMS + a];
                    s = fma((double)xv, (double)dv, s);
                }
                for (int off = 32; off; off >>= 1) s += __shfl_xor(s, off);
                wv64[w] = s;
            }
            unsigned taken = 0u;
            for (int scnt = 0; scnt < need; ++scnt) {
                int best = -1; double bbv = -1.0;
                for (int w = 0; w < nwin; ++w) {
                    if ((taken >> w) & 1u) continue;
                    double aw = fabs(wv64[w]);
                    if (aw > bbv || (aw == bbv && best >= 0 && widx[w] < widx[best])) { bbv = aw; best = w; }
                }
                taken |= 1u << best;
                fidx[nfinal] = widx[best];
                fval[nfinal] = (float)wv64[best];
                ++nfinal;
            }
        }
        if (lane == 0) {
#pragma unroll
            for (int r = 0; r < KSP; ++r) { sup_s[p][r] = fidx[r]; rhs_s[p][r] = fval[r]; }
        }
    }
    __syncthreads();

    if (tid < MT) {
        int p = tid, np = n0 + p;
        if (np < NPATCH) {
            int s[KSP];
            double A[KSP][KSP], bb[KSP];
#pragma unroll
            for (int i = 0; i < KSP; ++i) { s[i] = sup_s[p][i]; bb[i] = (double)rhs_s[p][i]; }
#pragma unroll
            for (int i = 0; i < KSP; ++i)
#pragma unroll
                for (int j = 0; j < KSP; ++j)
                    A[i][j] = (double)gram[(size_t)s[i] * NATOMS + s[j]] + (i == j ? 1e-10 : 0.0);
#pragma unroll
            for (int c = 0; c < KSP; ++c) {
                double inv = 1.0 / A[c][c];
#pragma unroll
                for (int r = 0; r < KSP; ++r) {
                    if (r > c) {
                        double f = A[r][c] * inv;
#pragma unroll
                        for (int cc = 0; cc < KSP; ++cc)
                            if (cc > c) A[r][cc] -= f * A[c][cc];
                        bb[r] -= f * bb[c];
                    }
                }
            }
#pragma unroll
            for (int r = KSP - 1; r >= 0; --r) {
                double t = bb[r];
#pragma unroll
                for (int cc = 0; cc < KSP; ++cc)
                    if (cc > r) t -= A[r][cc] * bb[cc];
                bb[r] = t / A[r][r];
            }
#pragma unroll
            for (int i = 0; i < KSP; ++i) {
                sup_out[(size_t)np * KSP + i] = s[i];
                val_out[(size_t)np * KSP + i] = (float)bb[i];
            }
        }
    }
}

__global__ __launch_bounds__(256) void recon_kernel_fb(const float* __restrict__ x,
                                                       const float* __restrict__ D,
                                                       const int* __restrict__ sup,
                                                       const float* __restrict__ val,
                                                       float* __restrict__ out,
                                                       double* __restrict__ partials) {
    double sqacc = 0.0;
    for (size_t o = (size_t)blockIdx.x * 256 + threadIdx.x; o < OUT_N; o += (size_t)FBLK * 256) {
        const int j = (int)(o & 127);
        const int i = (int)((o >> 7) & 127);
        const int c = (int)((o >> 14) & 63);
        const int b = (int)(o >> 20);
        const float xv = x[o];
        float z = 0.0f;
        const int pr = (i & 1) ? 1 : 2;
        const int pc = (j & 1) ? 1 : 2;
        const int ho = (i - pr) >> 1;
        const int wo = (j - pc) >> 1;
        if (ho >= 0 && ho < HO_ && wo >= 0 && wo < WO_) {
            const int n = (b * HO_ + ho) * WO_ + wo;
            const int k = c * 16 + pr * 4 + pc;
            const int*   sp5 = sup + (size_t)n * KSP;
            const float* vp5 = val + (size_t)n * KSP;
            float s = 0.0f;
#pragma unroll
            for (int t = 0; t < KSP; ++t)
                s = fmaf(vp5[t], D[(size_t)k * NATOMS + sp5[t]], s);
            z = s;
        }
        out[o] = xv + (z - xv);
        const float d = z - xv;
        sqacc += (double)d * (double)d;
    }
    for (int off = 32; off; off >>= 1) sqacc += __shfl_xor(sqacc, off);
    __shared__ double red[4];
    const int lane = threadIdx.x & 63, wv = threadIdx.x >> 6;
    if (lane == 0) red[wv] = sqacc;
    __syncthreads();
    if (threadIdx.x == 0) partials[blockIdx.x] = red[0] + red[1] + red[2] + red[3];
}

__global__ __launch_bounds__(256) void loss_kernel(const double* __restrict__ partials,
                                                   float* __restrict__ out) {
    double s = 0.0;
    for (int i = threadIdx.x; i < FBLK; i += 256) s += partials[i];
    for (int off = 32; off; off >>= 1) s += __shfl_xor(s, off);
    __shared__ double red[4];
    const int lane = threadIdx.x & 63, wv = threadIdx.x >> 6;
    if (lane == 0) red[wv] = s;
    __syncthreads();
    if (threadIdx.x == 0) {
        double m = (red[0] + red[1] + red[2] + red[3]) / (double)OUT_N;
        out[OUT_N] = (float)(m + 0.25 * m);
    }
}

// ---------------------------------------------------------------------------
extern "C" void kernel_launch(void* const* d_in, const int* in_sizes, int n_in,
                              void* d_out, int out_size, void* d_ws, size_t ws_size,
                              hipStream_t stream) {
    const float* x = (const float*)d_in[0];
    const float* D = (const float*)d_in[1];
    float* out = (float*)d_out;
    char* ws = (char*)d_ws;

    size_t off = 0;
    auto take = [&](size_t bytes) { char* p = ws + off; off += (bytes + 255) & ~(size_t)255; return p; };
    float*    gram     = (float*)take((size_t)NATOMS * NATOMS * 4);
    int*      sup      = (int*)take((size_t)NPATCH * KSP * 4);
    float*    val      = (float*)take((size_t)NPATCH * KSP * 4);
    double*   partials = (double*)take((size_t)FBLK * 8);
    double*   rpart    = (double*)take((size_t)RPB * 8);
    double*   bpart    = (double*)take((size_t)512 * 8);
    unsigned* topk     = (unsigned*)take((size_t)NPATCH * 16 * 4);
    f16*   Dth  = (f16*)take((size_t)NATOMS * PDIM * 2);
    f16*   Dtl  = (f16*)take((size_t)NATOMS * PDIM * 2);
    f16*   Dqi  = (f16*)take((size_t)NATOMS * CHN * 8 * 2);
    f16*   Xh   = (f16*)take((size_t)MPAD * PDIM * 2);
    f16*   corr = (f16*)take((size_t)MPAD * NATOMS * 2);
    const bool big = (off <= ws_size);

    if (big) {
        hipMemsetAsync(Xh + (size_t)NPATCH * PDIM, 0,
                       (size_t)(MPAD - NPATCH) * PDIM * sizeof(f16), stream);
        extract_kernel<<<8 * HO_ * 4, 256, 0, stream>>>(x, Xh);
        dtrans_kernel<<<dim3(16, 8), 256, 0, stream>>>(D, Dth, Dtl, Dqi);
        gram_kernel<<<dim3(16, 16), 256, 0, stream>>>(D, gram);
        border_kernel<<<512, 64, 0, stream>>>(x, out, bpart);
        gemm_kernel<<<512, 512, 0, stream>>>(Xh, Dth, corr);
        topred_kernel<<<(NPATCH + 15) / 16, 512, 0, stream>>>(corr, topk);
        topfin_kernel<<<NPATCH / 2, 64, 0, stream>>>(topk, corr, x, D, gram, sup, val);
        reconp_kernel<<<RPB, 256, 0, stream>>>(x, Dqi, sup, val, out, rpart);
        loss2_kernel<<<1, 256, 0, stream>>>(rpart, bpart, out);
    } else {
        gram_kernel<<<dim3(16, 16), 256, 0, stream>>>(D, gram);
        corr_kernel_fb<<<(NPATCH + MT - 1) / MT, 256, 0, stream>>>(x, D, gram, sup, val);
        recon_kernel_fb<<<FBLK, 256, 0, stream>>>(x, D, sup, val, out, partials);
        loss_kernel<<<1, 256, 0, stream>>>(partials, out);
    }
}